// Round 1
// baseline (1542.126 us; speedup 1.0000x reference)
//
#include <hip/hip_runtime.h>
#include <math.h>

#define DIM 768
#define HEADS 12
#define HD 64
#define GATE_HID 192
#define BATCH 2
#define SEQ 2048
#define BN_TOT (BATCH*SEQ)          // 4096
#define ATT_SCALE 0.125f            // 64^-0.5

// ---------------------------------------------------------------------------
// Kernel 1: coverage gate MLP.  g[b][h][n] = sigmoid(silu(c*Wg1+bg1)@Wg2+bg2)
// ---------------------------------------------------------------------------
__global__ __launch_bounds__(256) void gate_kernel(
    const float* __restrict__ cov, const float* __restrict__ Wg1,
    const float* __restrict__ bg1, const float* __restrict__ Wg2,
    const float* __restrict__ bg2, float* __restrict__ g)
{
  int idx = blockIdx.x * 256 + threadIdx.x;   // b*SEQ + n
  if (idx >= BN_TOT) return;
  float c = cov[idx];
  float acc[HEADS];
  #pragma unroll
  for (int t = 0; t < HEADS; ++t) acc[t] = bg2[t];
  for (int j = 0; j < GATE_HID; ++j) {
    float hpre = c * Wg1[j] + bg1[j];
    float s = hpre / (1.f + __expf(-hpre));   // silu
    #pragma unroll
    for (int t = 0; t < HEADS; ++t) acc[t] += s * Wg2[j * HEADS + t];
  }
  int b = idx / SEQ, n = idx % SEQ;
  #pragma unroll
  for (int t = 0; t < HEADS; ++t) {
    float val = 1.f / (1.f + __expf(-acc[t]));
    g[(size_t)(b * HEADS + t) * SEQ + n] = val;
  }
}

// ---------------------------------------------------------------------------
// Kernel 2: qkv = x @ Wqkv, scattered into Q/K/V with (B,H,N,64) layout.
// fp32 tiled GEMM: 64x64 block tile, BK=16, 256 threads, 4x4 microtile.
// ---------------------------------------------------------------------------
__global__ __launch_bounds__(256) void qkv_gemm(
    const float* __restrict__ X, const float* __restrict__ W,
    float* __restrict__ Q, float* __restrict__ Kt, float* __restrict__ Vt)
{
  __shared__ float As[16][64];   // As[k][m]
  __shared__ float Bs[16][64];   // Bs[k][n]
  const int t  = threadIdx.x;
  const int tx = t & 15, ty = t >> 4;
  const int row0 = blockIdx.y * 64;
  const int col0 = blockIdx.x * 64;
  const int m  = t >> 2;           // 0..63  (A-load row)
  const int k4 = (t & 3) << 2;     // 0,4,8,12 (A-load k)
  const int bk = t >> 6;           // 0..3   (B-load k base)
  const int bn = t & 63;           // 0..63  (B-load col)

  float acc[4][4];
  #pragma unroll
  for (int i = 0; i < 4; ++i)
    #pragma unroll
    for (int j = 0; j < 4; ++j) acc[i][j] = 0.f;

  for (int kb = 0; kb < DIM; kb += 16) {
    float4 av = *reinterpret_cast<const float4*>(
        &X[(size_t)(row0 + m) * DIM + kb + k4]);
    As[k4 + 0][m] = av.x; As[k4 + 1][m] = av.y;
    As[k4 + 2][m] = av.z; As[k4 + 3][m] = av.w;
    #pragma unroll
    for (int i = 0; i < 4; ++i)
      Bs[bk + i * 4][bn] =
          W[(size_t)(kb + bk + i * 4) * (3 * DIM) + col0 + bn];
    __syncthreads();
    #pragma unroll
    for (int kk = 0; kk < 16; ++kk) {
      float a[4], bb[4];
      #pragma unroll
      for (int i = 0; i < 4; ++i) a[i] = As[kk][ty * 4 + i];
      #pragma unroll
      for (int j = 0; j < 4; ++j) bb[j] = Bs[kk][tx * 4 + j];
      #pragma unroll
      for (int i = 0; i < 4; ++i)
        #pragma unroll
        for (int j = 0; j < 4; ++j) acc[i][j] += a[i] * bb[j];
    }
    __syncthreads();
  }

  // epilogue: scatter to Q/K/V head layout. 64-col tile = exactly one head.
  const int c0    = col0 + tx * 4;
  const int which = c0 / DIM;
  const int cc0   = c0 % DIM;
  const int h     = cc0 / HD;
  const int d0    = cc0 % HD;          // = tx*4 within the head
  float* dst = (which == 0) ? Q : ((which == 1) ? Kt : Vt);
  #pragma unroll
  for (int i = 0; i < 4; ++i) {
    int rr = row0 + ty * 4 + i;
    int b = rr / SEQ, n = rr % SEQ;
    #pragma unroll
    for (int j = 0; j < 4; ++j)
      dst[((size_t)(b * HEADS + h) * SEQ + n) * HD + d0 + j] = acc[i][j];
  }
}

// ---------------------------------------------------------------------------
// Kernel 3: flash-style attention with multiplicative key-side coverage gate.
// One block per (b,h, 64-row q tile).  scores = (q.k * SCALE) * g[key], then
// online softmax, o = p @ v.  All fp32.
// ---------------------------------------------------------------------------
__global__ __launch_bounds__(256) void attn_kernel(
    const float* __restrict__ Q, const float* __restrict__ K,
    const float* __restrict__ V, const float* __restrict__ G,
    float* __restrict__ AO)
{
  __shared__ float qs[64][65];
  __shared__ float ks[64][65];
  __shared__ float vs[64][65];
  __shared__ float ss[64][65];
  __shared__ float gsh[64];

  const int t  = threadIdx.x;
  const int qt = blockIdx.x;            // 0..31
  const int bh = blockIdx.y;            // 0..23
  const int b  = bh / HEADS;
  const int h  = bh % HEADS;
  const float* qp = Q + (size_t)bh * SEQ * HD;
  const float* kp = K + (size_t)bh * SEQ * HD;
  const float* vp = V + (size_t)bh * SEQ * HD;
  const float* gp = G + (size_t)bh * SEQ;

  #pragma unroll
  for (int i = 0; i < 16; ++i) {
    int e = i * 256 + t;
    int r = e >> 6, d = e & 63;
    qs[r][d] = qp[(size_t)(qt * 64 + r) * HD + d];
  }

  const int r     = t >> 2;             // 0..63 : my q row
  const int cbase = (t & 3) * 16;       // my 16-col slice
  float o[16];
  #pragma unroll
  for (int i = 0; i < 16; ++i) o[i] = 0.f;
  float m = -INFINITY, l = 0.f;

  for (int kt = 0; kt < SEQ / 64; ++kt) {
    #pragma unroll
    for (int i = 0; i < 16; ++i) {
      int e = i * 256 + t;
      int rr = e >> 6, d = e & 63;
      ks[rr][d] = kp[(size_t)(kt * 64 + rr) * HD + d];
      vs[rr][d] = vp[(size_t)(kt * 64 + rr) * HD + d];
    }
    if (t < 64) gsh[t] = gp[kt * 64 + t];
    __syncthreads();

    // QK^T for my 16 scores (row r, cols cbase..cbase+15)
    float dot[16];
    #pragma unroll
    for (int i = 0; i < 16; ++i) dot[i] = 0.f;
    for (int d = 0; d < 64; ++d) {
      float qv = qs[r][d];
      #pragma unroll
      for (int i = 0; i < 16; ++i) dot[i] += qv * ks[cbase + i][d];
    }
    #pragma unroll
    for (int i = 0; i < 16; ++i)
      ss[r][cbase + i] = dot[i] * ATT_SCALE * gsh[cbase + i];
    __syncthreads();

    // online softmax (each of the 4 threads of a row redundantly)
    float tmax = -INFINITY;
    for (int k2 = 0; k2 < 64; ++k2) tmax = fmaxf(tmax, ss[r][k2]);
    float m_new = fmaxf(m, tmax);
    float f = __expf(m - m_new);
    #pragma unroll
    for (int i = 0; i < 16; ++i) o[i] *= f;
    float sum_p = 0.f;
    for (int k2 = 0; k2 < 64; ++k2) {
      float p = __expf(ss[r][k2] - m_new);
      sum_p += p;
      #pragma unroll
      for (int i = 0; i < 16; ++i) o[i] += p * vs[k2][cbase + i];
    }
    l = l * f + sum_p;
    m = m_new;
    __syncthreads();
  }

  float inv = 1.f / l;
  #pragma unroll
  for (int i = 0; i < 16; ++i)
    AO[(size_t)(b * SEQ + qt * 64 + r) * DIM + h * HD + cbase + i] = o[i] * inv;
}

// ---------------------------------------------------------------------------
// Kernel 4: out = AO @ Wo + bo   (4096x768 @ 768x768), same fp32 tiling.
// ---------------------------------------------------------------------------
__global__ __launch_bounds__(256) void outproj_gemm(
    const float* __restrict__ A, const float* __restrict__ W,
    const float* __restrict__ bo, float* __restrict__ out)
{
  __shared__ float As[16][64];
  __shared__ float Bs[16][64];
  const int t  = threadIdx.x;
  const int tx = t & 15, ty = t >> 4;
  const int row0 = blockIdx.y * 64;
  const int col0 = blockIdx.x * 64;
  const int m  = t >> 2;
  const int k4 = (t & 3) << 2;
  const int bk = t >> 6;
  const int bn = t & 63;

  float acc[4][4];
  #pragma unroll
  for (int i = 0; i < 4; ++i)
    #pragma unroll
    for (int j = 0; j < 4; ++j) acc[i][j] = 0.f;

  for (int kb = 0; kb < DIM; kb += 16) {
    float4 av = *reinterpret_cast<const float4*>(
        &A[(size_t)(row0 + m) * DIM + kb + k4]);
    As[k4 + 0][m] = av.x; As[k4 + 1][m] = av.y;
    As[k4 + 2][m] = av.z; As[k4 + 3][m] = av.w;
    #pragma unroll
    for (int i = 0; i < 4; ++i)
      Bs[bk + i * 4][bn] = W[(size_t)(kb + bk + i * 4) * DIM + col0 + bn];
    __syncthreads();
    #pragma unroll
    for (int kk = 0; kk < 16; ++kk) {
      float a[4], bb[4];
      #pragma unroll
      for (int i = 0; i < 4; ++i) a[i] = As[kk][ty * 4 + i];
      #pragma unroll
      for (int j = 0; j < 4; ++j) bb[j] = Bs[kk][tx * 4 + j];
      #pragma unroll
      for (int i = 0; i < 4; ++i)
        #pragma unroll
        for (int j = 0; j < 4; ++j) acc[i][j] += a[i] * bb[j];
    }
    __syncthreads();
  }
  #pragma unroll
  for (int i = 0; i < 4; ++i) {
    int rr = row0 + ty * 4 + i;
    #pragma unroll
    for (int j = 0; j < 4; ++j) {
      int c = col0 + tx * 4 + j;
      out[(size_t)rr * DIM + c] = acc[i][j] + bo[c];
    }
  }
}

// ---------------------------------------------------------------------------
extern "C" void kernel_launch(void* const* d_in, const int* in_sizes, int n_in,
                              void* d_out, int out_size, void* d_ws, size_t ws_size,
                              hipStream_t stream) {
  const float* x    = (const float*)d_in[0];
  const float* cov  = (const float*)d_in[1];
  const float* Wqkv = (const float*)d_in[2];
  const float* Wo   = (const float*)d_in[3];
  const float* bo   = (const float*)d_in[4];
  const float* Wg1  = (const float*)d_in[5];
  const float* bg1  = (const float*)d_in[6];
  const float* Wg2  = (const float*)d_in[7];
  const float* bg2  = (const float*)d_in[8];
  float* out = (float*)d_out;

  float* ws = (float*)d_ws;
  float* g  = ws;                                   // B*H*N          = 49152
  float* Q  = g + (size_t)BATCH * HEADS * SEQ;      // B*H*N*64
  float* K  = Q + (size_t)BATCH * HEADS * SEQ * HD;
  float* V  = K + (size_t)BATCH * HEADS * SEQ * HD;
  float* AO = V + (size_t)BATCH * HEADS * SEQ * HD; // B*N*DIM

  gate_kernel<<<BN_TOT / 256, 256, 0, stream>>>(cov, Wg1, bg1, Wg2, bg2, g);
  qkv_gemm<<<dim3(3 * DIM / 64, BN_TOT / 64), 256, 0, stream>>>(x, Wqkv, Q, K, V);
  attn_kernel<<<dim3(SEQ / 64, BATCH * HEADS), 256, 0, stream>>>(Q, K, V, g, AO);
  outproj_gemm<<<dim3(DIM / 64, BN_TOT / 64), 256, 0, stream>>>(AO, Wo, bo, out);
}

// Round 2
// 543.340 us; speedup vs baseline: 2.8382x; 2.8382x over previous
//
#include <hip/hip_runtime.h>
#include <math.h>

#define DIM 768
#define HEADS 12
#define HD 64
#define GATE_HID 192
#define BATCH 2
#define SEQ 2048
#define BN_TOT (BATCH*SEQ)          // 4096
#define ATT_SCALE 0.125f            // 64^-0.5

typedef __attribute__((ext_vector_type(8))) short bf16x8;
typedef __attribute__((ext_vector_type(4))) float f32x4;

#define MFMA16(a, b, c) __builtin_amdgcn_mfma_f32_16x16x32_bf16(a, b, c, 0, 0, 0)

__device__ inline unsigned short f2bf(float x) {
  union { float f; unsigned int u; } un; un.f = x;
  unsigned int r = un.u + 0x7FFFu + ((un.u >> 16) & 1u);  // RNE
  return (unsigned short)(r >> 16);
}
__device__ inline float bf2f(unsigned short h) {
  union { float f; unsigned int u; } un; un.u = ((unsigned int)h) << 16;
  return un.f;
}

// ---------------------------------------------------------------------------
// Kernel 1: coverage gate MLP.  g[b][h][n] = sigmoid(silu(c*Wg1+bg1)@Wg2+bg2)
// ---------------------------------------------------------------------------
__global__ __launch_bounds__(256) void gate_kernel(
    const float* __restrict__ cov, const float* __restrict__ Wg1,
    const float* __restrict__ bg1, const float* __restrict__ Wg2,
    const float* __restrict__ bg2, float* __restrict__ g)
{
  int idx = blockIdx.x * 256 + threadIdx.x;   // b*SEQ + n
  if (idx >= BN_TOT) return;
  float c = cov[idx];
  float acc[HEADS];
  #pragma unroll
  for (int t = 0; t < HEADS; ++t) acc[t] = bg2[t];
  for (int j = 0; j < GATE_HID; ++j) {
    float hpre = c * Wg1[j] + bg1[j];
    float s = hpre / (1.f + __expf(-hpre));   // silu
    #pragma unroll
    for (int t = 0; t < HEADS; ++t) acc[t] += s * Wg2[j * HEADS + t];
  }
  int b = idx / SEQ, n = idx % SEQ;
  #pragma unroll
  for (int t = 0; t < HEADS; ++t) {
    float val = 1.f / (1.f + __expf(-acc[t]));
    g[(size_t)(b * HEADS + t) * SEQ + n] = val;
  }
}

// ---------------------------------------------------------------------------
// Kernel 2: qkv = x @ Wqkv, scattered into Q/K/V with (B,H,N,64) layout.
// fp32 tiled GEMM: 64x64 block tile, BK=16, 256 threads, 4x4 microtile.
// ---------------------------------------------------------------------------
__global__ __launch_bounds__(256) void qkv_gemm(
    const float* __restrict__ X, const float* __restrict__ W,
    float* __restrict__ Q, float* __restrict__ Kt, float* __restrict__ Vt)
{
  __shared__ float As[16][64];   // As[k][m]
  __shared__ float Bs[16][64];   // Bs[k][n]
  const int t  = threadIdx.x;
  const int tx = t & 15, ty = t >> 4;
  const int row0 = blockIdx.y * 64;
  const int col0 = blockIdx.x * 64;
  const int m  = t >> 2;           // 0..63  (A-load row)
  const int k4 = (t & 3) << 2;     // 0,4,8,12 (A-load k)
  const int bk = t >> 6;           // 0..3   (B-load k base)
  const int bn = t & 63;           // 0..63  (B-load col)

  float acc[4][4];
  #pragma unroll
  for (int i = 0; i < 4; ++i)
    #pragma unroll
    for (int j = 0; j < 4; ++j) acc[i][j] = 0.f;

  for (int kb = 0; kb < DIM; kb += 16) {
    float4 av = *reinterpret_cast<const float4*>(
        &X[(size_t)(row0 + m) * DIM + kb + k4]);
    As[k4 + 0][m] = av.x; As[k4 + 1][m] = av.y;
    As[k4 + 2][m] = av.z; As[k4 + 3][m] = av.w;
    #pragma unroll
    for (int i = 0; i < 4; ++i)
      Bs[bk + i * 4][bn] =
          W[(size_t)(kb + bk + i * 4) * (3 * DIM) + col0 + bn];
    __syncthreads();
    #pragma unroll
    for (int kk = 0; kk < 16; ++kk) {
      float a[4], bb[4];
      #pragma unroll
      for (int i = 0; i < 4; ++i) a[i] = As[kk][ty * 4 + i];
      #pragma unroll
      for (int j = 0; j < 4; ++j) bb[j] = Bs[kk][tx * 4 + j];
      #pragma unroll
      for (int i = 0; i < 4; ++i)
        #pragma unroll
        for (int j = 0; j < 4; ++j) acc[i][j] += a[i] * bb[j];
    }
    __syncthreads();
  }

  // epilogue: scatter to Q/K/V head layout. 64-col tile = exactly one head.
  const int c0    = col0 + tx * 4;
  const int which = c0 / DIM;
  const int cc0   = c0 % DIM;
  const int h     = cc0 / HD;
  const int d0    = cc0 % HD;          // = tx*4 within the head
  float* dst = (which == 0) ? Q : ((which == 1) ? Kt : Vt);
  #pragma unroll
  for (int i = 0; i < 4; ++i) {
    int rr = row0 + ty * 4 + i;
    int b = rr / SEQ, n = rr % SEQ;
    #pragma unroll
    for (int j = 0; j < 4; ++j)
      dst[((size_t)(b * HEADS + h) * SEQ + n) * HD + d0 + j] = acc[i][j];
  }
}

// ---------------------------------------------------------------------------
// Kernel 3: flash attention on MFMA with split-bf16 (hi+lo) precision.
// Block = 256 thr (4 waves). Q-tile 64 rows (16/wave), K-tile 64 keys.
// Q in registers; K, V^T, P in swizzled LDS as hi/lo bf16.
// S = Qh*Kh + Qh*Kl + Ql*Kh (fp32 acc), gated, online softmax in regs,
// P round-trip through LDS, O += Ph*Vh + Ph*Vl + Pl*Vh.
// ---------------------------------------------------------------------------
__global__ __launch_bounds__(256) void attn_mfma(
    const float* __restrict__ Q, const float* __restrict__ K,
    const float* __restrict__ V, const float* __restrict__ G,
    float* __restrict__ AO)
{
  __shared__ unsigned short KhS[64 * 64];
  __shared__ unsigned short KlS[64 * 64];
  __shared__ unsigned short VthS[64 * 64];   // [d][key]
  __shared__ unsigned short VtlS[64 * 64];
  __shared__ unsigned short PhS[64 * 64];    // [q][key]
  __shared__ unsigned short PlS[64 * 64];

  const int t     = threadIdx.x;
  const int w     = t >> 6;         // wave 0..3
  const int lan15 = t & 15;
  const int lgrp  = (t >> 4) & 3;   // lane group within wave
  const int qt    = blockIdx.x;     // 0..31
  const int bh    = blockIdx.y;     // 0..23
  const int b     = bh / HEADS;
  const int h     = bh % HEADS;
  const float* qp = Q + (size_t)bh * SEQ * HD;
  const float* kp = K + (size_t)bh * SEQ * HD;
  const float* vp = V + (size_t)bh * SEQ * HD;
  const float* gp = G + (size_t)bh * SEQ;

  // ---- Q fragments into registers (A-operand layout, hi/lo) ----
  bf16x8 qh[2], ql[2];
  {
    const float* qrow = qp + (size_t)(qt * 64 + w * 16 + lan15) * HD;
    #pragma unroll
    for (int s = 0; s < 2; ++s) {
      const int d0 = s * 32 + 8 * lgrp;
      #pragma unroll
      for (int j = 0; j < 8; ++j) {
        float x = qrow[d0 + j];
        unsigned short hh = f2bf(x);
        qh[s][j] = (short)hh;
        ql[s][j] = (short)f2bf(x - bf2f(hh));
      }
    }
  }

  f32x4 o[4];
  #pragma unroll
  for (int dt = 0; dt < 4; ++dt) o[dt] = (f32x4){0.f, 0.f, 0.f, 0.f};
  float mrun[4] = {-INFINITY, -INFINITY, -INFINITY, -INFINITY};
  float lrun[4] = {0.f, 0.f, 0.f, 0.f};

  // staging index precompute
  const int sr  = t >> 2;           // K-stage: row 0..63
  const int scb = (t & 3) * 16;     // K-stage: col base
  const int vk0 = (t >> 4) * 4;     // V-stage: key base
  const int vd0 = (t & 15) * 4;     // V-stage: d base

  for (int kt = 0; kt < SEQ / 64; ++kt) {
    __syncthreads();   // previous iteration's LDS reads complete

    // ---- stage K (hi/lo, swizzled rows [key][d]) ----
    {
      const float* krow = kp + (size_t)(kt * 64 + sr) * HD;
      #pragma unroll
      for (int i = 0; i < 4; ++i) {
        float4 kv = *reinterpret_cast<const float4*>(&krow[scb + 4 * i]);
        float xs[4] = {kv.x, kv.y, kv.z, kv.w};
        ushort4 h4, l4;
        unsigned short hh;
        hh = f2bf(xs[0]); h4.x = hh; l4.x = f2bf(xs[0] - bf2f(hh));
        hh = f2bf(xs[1]); h4.y = hh; l4.y = f2bf(xs[1] - bf2f(hh));
        hh = f2bf(xs[2]); h4.z = hh; l4.z = f2bf(xs[2] - bf2f(hh));
        hh = f2bf(xs[3]); h4.w = hh; l4.w = f2bf(xs[3] - bf2f(hh));
        int idx = (sr * 64 + scb + 4 * i) ^ ((sr & 7) << 3);
        *reinterpret_cast<ushort4*>(&KhS[idx]) = h4;
        *reinterpret_cast<ushort4*>(&KlS[idx]) = l4;
      }
    }
    // ---- stage V transposed (hi/lo, swizzled rows [d][key]) ----
    {
      float vv[4][4];
      #pragma unroll
      for (int i = 0; i < 4; ++i) {
        float4 r4 = *reinterpret_cast<const float4*>(
            &vp[(size_t)(kt * 64 + vk0 + i) * HD + vd0]);
        vv[i][0] = r4.x; vv[i][1] = r4.y; vv[i][2] = r4.z; vv[i][3] = r4.w;
      }
      #pragma unroll
      for (int j = 0; j < 4; ++j) {
        ushort4 h4, l4;
        unsigned short hh;
        hh = f2bf(vv[0][j]); h4.x = hh; l4.x = f2bf(vv[0][j] - bf2f(hh));
        hh = f2bf(vv[1][j]); h4.y = hh; l4.y = f2bf(vv[1][j] - bf2f(hh));
        hh = f2bf(vv[2][j]); h4.z = hh; l4.z = f2bf(vv[2][j] - bf2f(hh));
        hh = f2bf(vv[3][j]); h4.w = hh; l4.w = f2bf(vv[3][j] - bf2f(hh));
        int row = vd0 + j;
        int idx = (row * 64 + vk0) ^ ((row & 7) << 3);
        *reinterpret_cast<ushort4*>(&VthS[idx]) = h4;
        *reinterpret_cast<ushort4*>(&VtlS[idx]) = l4;
      }
    }
    // gate values for this lane's 4 key columns
    float gval[4];
    #pragma unroll
    for (int ct = 0; ct < 4; ++ct)
      gval[ct] = gp[kt * 64 + ct * 16 + lan15];

    __syncthreads();

    // ---- S = Q K^T (split-bf16, 3 terms) ----
    f32x4 acc[4];
    #pragma unroll
    for (int ct = 0; ct < 4; ++ct) acc[ct] = (f32x4){0.f, 0.f, 0.f, 0.f};
    #pragma unroll
    for (int s = 0; s < 2; ++s) {
      #pragma unroll
      for (int ct = 0; ct < 4; ++ct) {
        int brow = ct * 16 + lan15;
        int bidx = (brow * 64 + s * 32 + 8 * lgrp) ^ ((brow & 7) << 3);
        bf16x8 kbh = *reinterpret_cast<const bf16x8*>(&KhS[bidx]);
        bf16x8 kbl = *reinterpret_cast<const bf16x8*>(&KlS[bidx]);
        acc[ct] = MFMA16(qh[s], kbh, acc[ct]);
        acc[ct] = MFMA16(qh[s], kbl, acc[ct]);
        acc[ct] = MFMA16(ql[s], kbh, acc[ct]);
      }
    }

    // ---- gate + online softmax (rows = w*16 + 4*lgrp + r) ----
    float sv[4][4];   // [ct][r]
    #pragma unroll
    for (int ct = 0; ct < 4; ++ct)
      #pragma unroll
      for (int r = 0; r < 4; ++r)
        sv[ct][r] = acc[ct][r] * ATT_SCALE * gval[ct];

    float rmax[4];
    #pragma unroll
    for (int r = 0; r < 4; ++r) {
      rmax[r] = fmaxf(fmaxf(sv[0][r], sv[1][r]), fmaxf(sv[2][r], sv[3][r]));
      #pragma unroll
      for (int off = 1; off < 16; off <<= 1)
        rmax[r] = fmaxf(rmax[r], __shfl_xor(rmax[r], off));
    }
    float p[4][4], rsum[4];
    #pragma unroll
    for (int r = 0; r < 4; ++r) {
      float mnew = fmaxf(mrun[r], rmax[r]);
      float fsc  = __expf(mrun[r] - mnew);
      mrun[r] = mnew;
      lrun[r] *= fsc;
      #pragma unroll
      for (int dt = 0; dt < 4; ++dt) o[dt][r] *= fsc;
      float s0 = 0.f;
      #pragma unroll
      for (int ct = 0; ct < 4; ++ct) {
        p[ct][r] = __expf(sv[ct][r] - mnew);
        s0 += p[ct][r];
      }
      rsum[r] = s0;
    }
    #pragma unroll
    for (int r = 0; r < 4; ++r) {
      #pragma unroll
      for (int off = 1; off < 16; off <<= 1)
        rsum[r] += __shfl_xor(rsum[r], off);
      lrun[r] += rsum[r];
    }

    // ---- P -> LDS (hi/lo, swizzled; wave-private rows) ----
    #pragma unroll
    for (int r = 0; r < 4; ++r) {
      int prow = w * 16 + 4 * lgrp + r;
      #pragma unroll
      for (int ct = 0; ct < 4; ++ct) {
        float pv = p[ct][r];
        unsigned short hh = f2bf(pv);
        int idx = (prow * 64 + ct * 16 + lan15) ^ ((prow & 7) << 3);
        PhS[idx] = hh;
        PlS[idx] = f2bf(pv - bf2f(hh));
      }
    }

    // ---- O += P V (split-bf16, 3 terms) ----
    #pragma unroll
    for (int s = 0; s < 2; ++s) {
      int arow = w * 16 + lan15;
      int aidx = (arow * 64 + s * 32 + 8 * lgrp) ^ ((arow & 7) << 3);
      bf16x8 pah = *reinterpret_cast<const bf16x8*>(&PhS[aidx]);
      bf16x8 pal = *reinterpret_cast<const bf16x8*>(&PlS[aidx]);
      #pragma unroll
      for (int dt = 0; dt < 4; ++dt) {
        int brow = dt * 16 + lan15;
        int bidx = (brow * 64 + s * 32 + 8 * lgrp) ^ ((brow & 7) << 3);
        bf16x8 vbh = *reinterpret_cast<const bf16x8*>(&VthS[bidx]);
        bf16x8 vbl = *reinterpret_cast<const bf16x8*>(&VtlS[bidx]);
        o[dt] = MFMA16(pah, vbh, o[dt]);
        o[dt] = MFMA16(pah, vbl, o[dt]);
        o[dt] = MFMA16(pal, vbh, o[dt]);
      }
    }
  }

  // ---- epilogue: normalize and write ----
  #pragma unroll
  for (int r = 0; r < 4; ++r) {
    float inv = 1.f / lrun[r];
    int qrow_g = qt * 64 + w * 16 + 4 * lgrp + r;
    #pragma unroll
    for (int dt = 0; dt < 4; ++dt)
      AO[(size_t)(b * SEQ + qrow_g) * DIM + h * HD + dt * 16 + lan15] =
          o[dt][r] * inv;
  }
}

// ---------------------------------------------------------------------------
// Kernel 4: out = AO @ Wo + bo   (4096x768 @ 768x768), same fp32 tiling.
// ---------------------------------------------------------------------------
__global__ __launch_bounds__(256) void outproj_gemm(
    const float* __restrict__ A, const float* __restrict__ W,
    const float* __restrict__ bo, float* __restrict__ out)
{
  __shared__ float As[16][64];
  __shared__ float Bs[16][64];
  const int t  = threadIdx.x;
  const int tx = t & 15, ty = t >> 4;
  const int row0 = blockIdx.y * 64;
  const int col0 = blockIdx.x * 64;
  const int m  = t >> 2;
  const int k4 = (t & 3) << 2;
  const int bk = t >> 6;
  const int bn = t & 63;

  float acc[4][4];
  #pragma unroll
  for (int i = 0; i < 4; ++i)
    #pragma unroll
    for (int j = 0; j < 4; ++j) acc[i][j] = 0.f;

  for (int kb = 0; kb < DIM; kb += 16) {
    float4 av = *reinterpret_cast<const float4*>(
        &A[(size_t)(row0 + m) * DIM + kb + k4]);
    As[k4 + 0][m] = av.x; As[k4 + 1][m] = av.y;
    As[k4 + 2][m] = av.z; As[k4 + 3][m] = av.w;
    #pragma unroll
    for (int i = 0; i < 4; ++i)
      Bs[bk + i * 4][bn] = W[(size_t)(kb + bk + i * 4) * DIM + col0 + bn];
    __syncthreads();
    #pragma unroll
    for (int kk = 0; kk < 16; ++kk) {
      float a[4], bb[4];
      #pragma unroll
      for (int i = 0; i < 4; ++i) a[i] = As[kk][ty * 4 + i];
      #pragma unroll
      for (int j = 0; j < 4; ++j) bb[j] = Bs[kk][tx * 4 + j];
      #pragma unroll
      for (int i = 0; i < 4; ++i)
        #pragma unroll
        for (int j = 0; j < 4; ++j) acc[i][j] += a[i] * bb[j];
    }
    __syncthreads();
  }
  #pragma unroll
  for (int i = 0; i < 4; ++i) {
    int rr = row0 + ty * 4 + i;
    #pragma unroll
    for (int j = 0; j < 4; ++j) {
      int c = col0 + tx * 4 + j;
      out[(size_t)rr * DIM + c] = acc[i][j] + bo[c];
    }
  }
}

// ---------------------------------------------------------------------------
extern "C" void kernel_launch(void* const* d_in, const int* in_sizes, int n_in,
                              void* d_out, int out_size, void* d_ws, size_t ws_size,
                              hipStream_t stream) {
  const float* x    = (const float*)d_in[0];
  const float* cov  = (const float*)d_in[1];
  const float* Wqkv = (const float*)d_in[2];
  const float* Wo   = (const float*)d_in[3];
  const float* bo   = (const float*)d_in[4];
  const float* Wg1  = (const float*)d_in[5];
  const float* bg1  = (const float*)d_in[6];
  const float* Wg2  = (const float*)d_in[7];
  const float* bg2  = (const float*)d_in[8];
  float* out = (float*)d_out;

  float* ws = (float*)d_ws;
  float* g  = ws;                                   // B*H*N          = 49152
  float* Q  = g + (size_t)BATCH * HEADS * SEQ;      // B*H*N*64
  float* K  = Q + (size_t)BATCH * HEADS * SEQ * HD;
  float* V  = K + (size_t)BATCH * HEADS * SEQ * HD;
  float* AO = V + (size_t)BATCH * HEADS * SEQ * HD; // B*N*DIM

  gate_kernel<<<BN_TOT / 256, 256, 0, stream>>>(cov, Wg1, bg1, Wg2, bg2, g);
  qkv_gemm<<<dim3(3 * DIM / 64, BN_TOT / 64), 256, 0, stream>>>(x, Wqkv, Q, K, V);
  attn_mfma<<<dim3(SEQ / 64, BATCH * HEADS), 256, 0, stream>>>(Q, K, V, g, AO);
  outproj_gemm<<<dim3(DIM / 64, BN_TOT / 64), 256, 0, stream>>>(AO, Wo, bo, out);
}

// Round 3
// 412.700 us; speedup vs baseline: 3.7367x; 1.3165x over previous
//
#include <hip/hip_runtime.h>
#include <math.h>

#define DIM 768
#define HEADS 12
#define HD 64
#define GATE_HID 192
#define BATCH 2
#define SEQ 2048
#define BN_TOT (BATCH*SEQ)          // 4096
#define ATT_SCALE 0.125f            // 64^-0.5

typedef unsigned short u16;
typedef __attribute__((ext_vector_type(8))) short bf16x8;
typedef __attribute__((ext_vector_type(4))) float f32x4;

#define MFMA16(a, b, c) __builtin_amdgcn_mfma_f32_16x16x32_bf16(a, b, c, 0, 0, 0)

__device__ inline u16 f2bf(float x) {
  union { float f; unsigned int u; } un; un.f = x;
  unsigned int r = un.u + 0x7FFFu + ((un.u >> 16) & 1u);  // RNE
  return (u16)(r >> 16);
}
__device__ inline float bf2f(u16 h) {
  union { float f; unsigned int u; } un; un.u = ((unsigned int)h) << 16;
  return un.f;
}

// ---------------------------------------------------------------------------
// Prep A: elementwise split fp32 -> bf16 hi/lo.  n4 = n/4 float4 chunks.
// ---------------------------------------------------------------------------
__global__ __launch_bounds__(256) void split_kernel(
    const float* __restrict__ src, u16* __restrict__ h, u16* __restrict__ l,
    int n4)
{
  int i = blockIdx.x * 256 + threadIdx.x;
  if (i >= n4) return;
  float4 v = reinterpret_cast<const float4*>(src)[i];
  float xs[4] = {v.x, v.y, v.z, v.w};
  ushort4 hv, lv;
  u16 hh;
  hh = f2bf(xs[0]); hv.x = hh; lv.x = f2bf(xs[0] - bf2f(hh));
  hh = f2bf(xs[1]); hv.y = hh; lv.y = f2bf(xs[1] - bf2f(hh));
  hh = f2bf(xs[2]); hv.z = hh; lv.z = f2bf(xs[2] - bf2f(hh));
  hh = f2bf(xs[3]); hv.w = hh; lv.w = f2bf(xs[3] - bf2f(hh));
  reinterpret_cast<ushort4*>(h)[i] = hv;
  reinterpret_cast<ushort4*>(l)[i] = lv;
}

// ---------------------------------------------------------------------------
// Prep B: transpose + split.  src [R][C] fp32 -> th/tl [C][R] bf16 hi/lo.
// 64x64 LDS tile, coalesced on both sides.
// ---------------------------------------------------------------------------
__global__ __launch_bounds__(256) void transpose_split(
    const float* __restrict__ src, u16* __restrict__ th, u16* __restrict__ tl,
    int R, int C)
{
  __shared__ float tile[64][65];
  const int t = threadIdx.x;
  const int c = t & 63, r4 = t >> 6;
  const int gr0 = blockIdx.y * 64, gc0 = blockIdx.x * 64;
  #pragma unroll
  for (int i = 0; i < 16; ++i) {
    int row = i * 4 + r4;
    tile[row][c] = src[(size_t)(gr0 + row) * C + gc0 + c];
  }
  __syncthreads();
  #pragma unroll
  for (int i = 0; i < 16; ++i) {
    int rr = i * 4 + r4;               // col index within tile (output row)
    float v = tile[c][rr];
    u16 hh = f2bf(v);
    size_t o = (size_t)(gc0 + rr) * R + gr0 + c;
    th[o] = hh;
    tl[o] = f2bf(v - bf2f(hh));
  }
}

// ---------------------------------------------------------------------------
// Kernel 1: coverage gate MLP.  g[b][h][n] = sigmoid(silu(c*Wg1+bg1)@Wg2+bg2)
// ---------------------------------------------------------------------------
__global__ __launch_bounds__(256) void gate_kernel(
    const float* __restrict__ cov, const float* __restrict__ Wg1,
    const float* __restrict__ bg1, const float* __restrict__ Wg2,
    const float* __restrict__ bg2, float* __restrict__ g)
{
  int idx = blockIdx.x * 256 + threadIdx.x;   // b*SEQ + n
  if (idx >= BN_TOT) return;
  float c = cov[idx];
  float acc[HEADS];
  #pragma unroll
  for (int t = 0; t < HEADS; ++t) acc[t] = bg2[t];
  for (int j = 0; j < GATE_HID; ++j) {
    float hpre = c * Wg1[j] + bg1[j];
    float s = hpre / (1.f + __expf(-hpre));   // silu
    #pragma unroll
    for (int t = 0; t < HEADS; ++t) acc[t] += s * Wg2[j * HEADS + t];
  }
  int b = idx / SEQ, n = idx % SEQ;
  #pragma unroll
  for (int t = 0; t < HEADS; ++t) {
    float val = 1.f / (1.f + __expf(-acc[t]));
    g[(size_t)(b * HEADS + t) * SEQ + n] = val;
  }
}

// ---------------------------------------------------------------------------
// Kernel 2: qkv = x @ Wqkv via split-bf16 MFMA (3-term).  128x128 tile,
// BK=32, 4 waves, frag-blocked LDS (conflict-free).  Epilogue scatters
// Q/K/V as bf16 hi/lo in (B,H,N,64) layout.
// ---------------------------------------------------------------------------
__global__ __launch_bounds__(256) void qkv_mfma(
    const u16* __restrict__ xh, const u16* __restrict__ xl,
    const u16* __restrict__ bth, const u16* __restrict__ btl,
    u16* __restrict__ Qh, u16* __restrict__ Ql,
    u16* __restrict__ Kh, u16* __restrict__ Kl,
    u16* __restrict__ Vh, u16* __restrict__ Vl)
{
  __shared__ u16 AH[4096], AL[4096], BH[4096], BL[4096];
  const int t = threadIdx.x;
  const int w = t >> 6, l = t & 63;
  const int lan15 = l & 15, lgrp = l >> 4;
  const int row0 = blockIdx.y * 128, col0 = blockIdx.x * 128;
  const int wrf = (w >> 1) * 4, wcf = (w & 1) * 4;   // frag-index bases

  f32x4 acc[4][4];
  #pragma unroll
  for (int i = 0; i < 4; ++i)
    #pragma unroll
    for (int j = 0; j < 4; ++j) acc[i][j] = (f32x4){0.f, 0.f, 0.f, 0.f};

  for (int kb = 0; kb < DIM; kb += 32) {
    #pragma unroll
    for (int cc = 0; cc < 2; ++cc) {
      int c = t + cc * 256;
      int mf = c >> 6, lg = (c >> 4) & 3, r = c & 15;
      size_t ga = (size_t)(row0 + mf * 16 + r) * DIM + kb + lg * 8;
      size_t gb = (size_t)(col0 + mf * 16 + r) * DIM + kb + lg * 8;
      *reinterpret_cast<bf16x8*>(&AH[c * 8]) =
          *reinterpret_cast<const bf16x8*>(&xh[ga]);
      *reinterpret_cast<bf16x8*>(&AL[c * 8]) =
          *reinterpret_cast<const bf16x8*>(&xl[ga]);
      *reinterpret_cast<bf16x8*>(&BH[c * 8]) =
          *reinterpret_cast<const bf16x8*>(&bth[gb]);
      *reinterpret_cast<bf16x8*>(&BL[c * 8]) =
          *reinterpret_cast<const bf16x8*>(&btl[gb]);
    }
    __syncthreads();
    bf16x8 ah4[4], al4[4];
    #pragma unroll
    for (int mi = 0; mi < 4; ++mi) {
      ah4[mi] = *reinterpret_cast<const bf16x8*>(&AH[((wrf + mi) * 64 + l) * 8]);
      al4[mi] = *reinterpret_cast<const bf16x8*>(&AL[((wrf + mi) * 64 + l) * 8]);
    }
    #pragma unroll
    for (int ni = 0; ni < 4; ++ni) {
      bf16x8 bh = *reinterpret_cast<const bf16x8*>(&BH[((wcf + ni) * 64 + l) * 8]);
      bf16x8 bl = *reinterpret_cast<const bf16x8*>(&BL[((wcf + ni) * 64 + l) * 8]);
      #pragma unroll
      for (int mi = 0; mi < 4; ++mi) {
        acc[mi][ni] = MFMA16(ah4[mi], bh, acc[mi][ni]);
        acc[mi][ni] = MFMA16(ah4[mi], bl, acc[mi][ni]);
        acc[mi][ni] = MFMA16(al4[mi], bh, acc[mi][ni]);
      }
    }
    __syncthreads();
  }

  // epilogue: wave's 64-col block = exactly one head of one section.
  const int gc0 = col0 + (w & 1) * 64;
  const int sec = gc0 / DIM;
  const int hh_ = (gc0 % DIM) / HD;
  u16* DH = (sec == 0) ? Qh : ((sec == 1) ? Kh : Vh);
  u16* DL = (sec == 0) ? Ql : ((sec == 1) ? Kl : Vl);
  const int wrr = (w >> 1) * 64;
  #pragma unroll
  for (int mi = 0; mi < 4; ++mi) {
    #pragma unroll
    for (int reg = 0; reg < 4; ++reg) {
      int row = row0 + wrr + mi * 16 + lgrp * 4 + reg;
      size_t base =
          ((size_t)((row >> 11) * HEADS + hh_) * SEQ + (row & 2047)) * HD;
      #pragma unroll
      for (int ni = 0; ni < 4; ++ni) {
        float v = acc[mi][ni][reg];
        u16 hb = f2bf(v);
        DH[base + ni * 16 + lan15] = hb;
        DL[base + ni * 16 + lan15] = f2bf(v - bf2f(hb));
      }
    }
  }
}

// ---------------------------------------------------------------------------
// Kernel 3: flash attention, split-bf16 MFMA, pre-split inputs (no f2bf on
// K/V/Q paths).  K frag-blocked LDS; V reg-transposed to swizzled [d][key];
// P via swizzled LDS round-trip.  Epilogue writes AO as bf16 hi/lo.
// ---------------------------------------------------------------------------
__global__ __launch_bounds__(256) void attn_mfma(
    const u16* __restrict__ Qh, const u16* __restrict__ Ql,
    const u16* __restrict__ Kh, const u16* __restrict__ Kl,
    const u16* __restrict__ Vh, const u16* __restrict__ Vl,
    const float* __restrict__ G,
    u16* __restrict__ AOh, u16* __restrict__ AOl)
{
  __shared__ u16 KhS[4096], KlS[4096];
  __shared__ u16 VThS[4096], VTlS[4096];   // [d][key], swizzled
  __shared__ u16 PhS[4096], PlS[4096];     // [q][key], swizzled

  const int t     = threadIdx.x;
  const int w     = t >> 6, l = t & 63;
  const int lan15 = l & 15;
  const int lgrp  = l >> 4;
  const int qt    = blockIdx.x;            // 0..31
  const int bh    = blockIdx.y;            // 0..23
  const int b     = bh / HEADS;
  const int h     = bh % HEADS;
  const size_t kvbase = (size_t)bh * SEQ * HD;
  const float* gp = G + (size_t)bh * SEQ;

  // Q fragments (hi/lo) straight from global
  bf16x8 qh[2], ql[2];
  {
    size_t qrow = kvbase + (size_t)(qt * 64 + w * 16 + lan15) * HD;
    #pragma unroll
    for (int s = 0; s < 2; ++s) {
      qh[s] = *reinterpret_cast<const bf16x8*>(&Qh[qrow + s * 32 + lgrp * 8]);
      ql[s] = *reinterpret_cast<const bf16x8*>(&Ql[qrow + s * 32 + lgrp * 8]);
    }
  }

  f32x4 o[4];
  #pragma unroll
  for (int dt = 0; dt < 4; ++dt) o[dt] = (f32x4){0.f, 0.f, 0.f, 0.f};
  float mrun[4] = {-INFINITY, -INFINITY, -INFINITY, -INFINITY};
  float lrun[4] = {0.f, 0.f, 0.f, 0.f};

  const int vk0 = (t & 15) * 4;     // V-stage: key base
  const int vd0 = (t >> 4) * 4;     // V-stage: d base

  for (int kt = 0; kt < SEQ / 64; ++kt) {
    __syncthreads();   // previous iteration's LDS reads complete

    // ---- stage K (frag-blocked: chunk c -> frag c>>6, lane c&63) ----
    #pragma unroll
    for (int cc = 0; cc < 2; ++cc) {
      int c = t + cc * 256;
      int fi = c >> 6, lg = (c >> 4) & 3, r = c & 15;
      int key = (fi >> 1) * 16 + r;
      int d   = (fi & 1) * 32 + lg * 8;
      size_t gsrc = kvbase + (size_t)(kt * 64 + key) * HD + d;
      *reinterpret_cast<bf16x8*>(&KhS[c * 8]) =
          *reinterpret_cast<const bf16x8*>(&Kh[gsrc]);
      *reinterpret_cast<bf16x8*>(&KlS[c * 8]) =
          *reinterpret_cast<const bf16x8*>(&Kl[gsrc]);
    }
    // ---- stage V transposed (reg transpose, swizzled [d][key]) ----
    {
      ushort4 rh[4], rl[4];
      #pragma unroll
      for (int i = 0; i < 4; ++i) {
        size_t gsrc = kvbase + (size_t)(kt * 64 + vk0 + i) * HD + vd0;
        rh[i] = *reinterpret_cast<const ushort4*>(&Vh[gsrc]);
        rl[i] = *reinterpret_cast<const ushort4*>(&Vl[gsrc]);
      }
      const u16* ph = (const u16*)rh;
      const u16* pl = (const u16*)rl;
      #pragma unroll
      for (int j = 0; j < 4; ++j) {
        int row = vd0 + j;
        int idx = (row * 64 + vk0) ^ ((row & 7) << 3);
        ushort4 oh = {ph[0 * 4 + j], ph[1 * 4 + j], ph[2 * 4 + j], ph[3 * 4 + j]};
        ushort4 ol = {pl[0 * 4 + j], pl[1 * 4 + j], pl[2 * 4 + j], pl[3 * 4 + j]};
        *reinterpret_cast<ushort4*>(&VThS[idx]) = oh;
        *reinterpret_cast<ushort4*>(&VTlS[idx]) = ol;
      }
    }
    // gate values for this lane's 4 key columns
    float gval[4];
    #pragma unroll
    for (int ct = 0; ct < 4; ++ct)
      gval[ct] = gp[kt * 64 + ct * 16 + lan15];

    __syncthreads();

    // ---- S = Q K^T (split-bf16, 3 terms) ----
    f32x4 acc[4];
    #pragma unroll
    for (int ct = 0; ct < 4; ++ct) acc[ct] = (f32x4){0.f, 0.f, 0.f, 0.f};
    #pragma unroll
    for (int s = 0; s < 2; ++s) {
      #pragma unroll
      for (int ct = 0; ct < 4; ++ct) {
        int bidx = ((ct * 2 + s) * 64 + l) * 8;
        bf16x8 kbh = *reinterpret_cast<const bf16x8*>(&KhS[bidx]);
        bf16x8 kbl = *reinterpret_cast<const bf16x8*>(&KlS[bidx]);
        acc[ct] = MFMA16(qh[s], kbh, acc[ct]);
        acc[ct] = MFMA16(qh[s], kbl, acc[ct]);
        acc[ct] = MFMA16(ql[s], kbh, acc[ct]);
      }
    }

    // ---- gate + online softmax (rows = w*16 + 4*lgrp + r) ----
    float sv[4][4];   // [ct][r]
    #pragma unroll
    for (int ct = 0; ct < 4; ++ct)
      #pragma unroll
      for (int r = 0; r < 4; ++r)
        sv[ct][r] = acc[ct][r] * ATT_SCALE * gval[ct];

    float rmax[4];
    #pragma unroll
    for (int r = 0; r < 4; ++r) {
      rmax[r] = fmaxf(fmaxf(sv[0][r], sv[1][r]), fmaxf(sv[2][r], sv[3][r]));
      #pragma unroll
      for (int off = 1; off < 16; off <<= 1)
        rmax[r] = fmaxf(rmax[r], __shfl_xor(rmax[r], off));
    }
    float p[4][4], rsum[4];
    #pragma unroll
    for (int r = 0; r < 4; ++r) {
      float mnew = fmaxf(mrun[r], rmax[r]);
      float fsc  = __expf(mrun[r] - mnew);
      mrun[r] = mnew;
      lrun[r] *= fsc;
      #pragma unroll
      for (int dt = 0; dt < 4; ++dt) o[dt][r] *= fsc;
      float s0 = 0.f;
      #pragma unroll
      for (int ct = 0; ct < 4; ++ct) {
        p[ct][r] = __expf(sv[ct][r] - mnew);
        s0 += p[ct][r];
      }
      rsum[r] = s0;
    }
    #pragma unroll
    for (int r = 0; r < 4; ++r) {
      #pragma unroll
      for (int off = 1; off < 16; off <<= 1)
        rsum[r] += __shfl_xor(rsum[r], off);
      lrun[r] += rsum[r];
    }

    // ---- P -> LDS (hi/lo, swizzled; wave-private rows) ----
    #pragma unroll
    for (int r = 0; r < 4; ++r) {
      int prow = w * 16 + 4 * lgrp + r;
      #pragma unroll
      for (int ct = 0; ct < 4; ++ct) {
        float pv = p[ct][r];
        u16 hb = f2bf(pv);
        int idx = (prow * 64 + ct * 16 + lan15) ^ ((prow & 7) << 3);
        PhS[idx] = hb;
        PlS[idx] = f2bf(pv - bf2f(hb));
      }
    }

    // ---- O += P V (split-bf16, 3 terms) ----
    #pragma unroll
    for (int s = 0; s < 2; ++s) {
      int arow = w * 16 + lan15;
      int aidx = (arow * 64 + s * 32 + 8 * lgrp) ^ ((arow & 7) << 3);
      bf16x8 pah = *reinterpret_cast<const bf16x8*>(&PhS[aidx]);
      bf16x8 pal = *reinterpret_cast<const bf16x8*>(&PlS[aidx]);
      #pragma unroll
      for (int dt = 0; dt < 4; ++dt) {
        int brow = dt * 16 + lan15;
        int bidx = (brow * 64 + s * 32 + 8 * lgrp) ^ ((brow & 7) << 3);
        bf16x8 vbh = *reinterpret_cast<const bf16x8*>(&VThS[bidx]);
        bf16x8 vbl = *reinterpret_cast<const bf16x8*>(&VTlS[bidx]);
        o[dt] = MFMA16(pah, vbh, o[dt]);
        o[dt] = MFMA16(pah, vbl, o[dt]);
        o[dt] = MFMA16(pal, vbh, o[dt]);
      }
    }
  }

  // ---- epilogue: normalize, split, write AO hi/lo ----
  #pragma unroll
  for (int r = 0; r < 4; ++r) {
    float inv = 1.f / lrun[r];
    int qrow_g = qt * 64 + w * 16 + 4 * lgrp + r;
    size_t base = (size_t)(b * SEQ + qrow_g) * DIM + h * HD;
    #pragma unroll
    for (int dt = 0; dt < 4; ++dt) {
      float v = o[dt][r] * inv;
      u16 hb = f2bf(v);
      AOh[base + dt * 16 + lan15] = hb;
      AOl[base + dt * 16 + lan15] = f2bf(v - bf2f(hb));
    }
  }
}

// ---------------------------------------------------------------------------
// Kernel 4: out = AO @ Wo + bo via split-bf16 MFMA.  128x64 tile, BK=32.
// ---------------------------------------------------------------------------
__global__ __launch_bounds__(256) void outproj_mfma(
    const u16* __restrict__ ah, const u16* __restrict__ al,
    const u16* __restrict__ bth, const u16* __restrict__ btl,
    const float* __restrict__ bo, float* __restrict__ out)
{
  __shared__ u16 AH[4096], AL[4096], BH[2048], BL[2048];
  const int t = threadIdx.x;
  const int w = t >> 6, l = t & 63;
  const int lan15 = l & 15, lgrp = l >> 4;
  const int row0 = blockIdx.y * 128, col0 = blockIdx.x * 64;
  const int wrf = (w >> 1) * 4, wcf = (w & 1) * 2;

  f32x4 acc[4][2];
  #pragma unroll
  for (int i = 0; i < 4; ++i)
    #pragma unroll
    for (int j = 0; j < 2; ++j) acc[i][j] = (f32x4){0.f, 0.f, 0.f, 0.f};

  for (int kb = 0; kb < DIM; kb += 32) {
    #pragma unroll
    for (int cc = 0; cc < 2; ++cc) {
      int c = t + cc * 256;
      int mf = c >> 6, lg = (c >> 4) & 3, r = c & 15;
      size_t ga = (size_t)(row0 + mf * 16 + r) * DIM + kb + lg * 8;
      *reinterpret_cast<bf16x8*>(&AH[c * 8]) =
          *reinterpret_cast<const bf16x8*>(&ah[ga]);
      *reinterpret_cast<bf16x8*>(&AL[c * 8]) =
          *reinterpret_cast<const bf16x8*>(&al[ga]);
    }
    {
      int c = t;
      int nf = c >> 6, lg = (c >> 4) & 3, r = c & 15;
      size_t gb = (size_t)(col0 + nf * 16 + r) * DIM + kb + lg * 8;
      *reinterpret_cast<bf16x8*>(&BH[c * 8]) =
          *reinterpret_cast<const bf16x8*>(&bth[gb]);
      *reinterpret_cast<bf16x8*>(&BL[c * 8]) =
          *reinterpret_cast<const bf16x8*>(&btl[gb]);
    }
    __syncthreads();
    bf16x8 ah4[4], al4[4];
    #pragma unroll
    for (int mi = 0; mi < 4; ++mi) {
      ah4[mi] = *reinterpret_cast<const bf16x8*>(&AH[((wrf + mi) * 64 + l) * 8]);
      al4[mi] = *reinterpret_cast<const bf16x8*>(&AL[((wrf + mi) * 64 + l) * 8]);
    }
    #pragma unroll
    for (int ni = 0; ni < 2; ++ni) {
      bf16x8 bh = *reinterpret_cast<const bf16x8*>(&BH[((wcf + ni) * 64 + l) * 8]);
      bf16x8 bl = *reinterpret_cast<const bf16x8*>(&BL[((wcf + ni) * 64 + l) * 8]);
      #pragma unroll
      for (int mi = 0; mi < 4; ++mi) {
        acc[mi][ni] = MFMA16(ah4[mi], bh, acc[mi][ni]);
        acc[mi][ni] = MFMA16(ah4[mi], bl, acc[mi][ni]);
        acc[mi][ni] = MFMA16(al4[mi], bh, acc[mi][ni]);
      }
    }
    __syncthreads();
  }

  const int wrr = (w >> 1) * 64, wcc = (w & 1) * 32;
  #pragma unroll
  for (int mi = 0; mi < 4; ++mi) {
    #pragma unroll
    for (int reg = 0; reg < 4; ++reg) {
      int row = row0 + wrr + mi * 16 + lgrp * 4 + reg;
      #pragma unroll
      for (int ni = 0; ni < 2; ++ni) {
        int col = col0 + wcc + ni * 16 + lan15;
        out[(size_t)row * DIM + col] = acc[mi][ni][reg] + bo[col];
      }
    }
  }
}

// ---------------------------------------------------------------------------
extern "C" void kernel_launch(void* const* d_in, const int* in_sizes, int n_in,
                              void* d_out, int out_size, void* d_ws, size_t ws_size,
                              hipStream_t stream) {
  const float* x    = (const float*)d_in[0];
  const float* cov  = (const float*)d_in[1];
  const float* Wqkv = (const float*)d_in[2];
  const float* Wo   = (const float*)d_in[3];
  const float* bo   = (const float*)d_in[4];
  const float* Wg1  = (const float*)d_in[5];
  const float* bg1  = (const float*)d_in[6];
  const float* Wg2  = (const float*)d_in[7];
  const float* bg2  = (const float*)d_in[8];
  float* out = (float*)d_out;

  const size_t NX   = (size_t)BN_TOT * DIM;        // 3,145,728
  const size_t NWQ  = (size_t)DIM * 3 * DIM;       // 1,769,472
  const size_t NWO  = (size_t)DIM * DIM;           //   589,824
  const size_t NHEA = (size_t)BATCH * HEADS * SEQ * HD;  // 3,145,728

  float* g   = (float*)d_ws;                       // 49152 floats
  u16* base  = (u16*)(g + (size_t)BATCH * HEADS * SEQ);
  u16* xh    = base;          u16* xl   = xh + NX;
  u16* wth   = xl + NX;       u16* wtl  = wth + NWQ;
  u16* woth  = wtl + NWQ;     u16* wotl = woth + NWO;
  u16* Qh    = wotl + NWO;    u16* Ql   = Qh + NHEA;
  u16* Kh    = Ql + NHEA;     u16* Kl   = Kh + NHEA;
  u16* Vh    = Kl + NHEA;     u16* Vl   = Vh + NHEA;
  u16* AOh   = Vl + NHEA;     u16* AOl  = AOh + NX;

  split_kernel<<<(int)(NX / 1024), 256, 0, stream>>>(x, xh, xl, (int)(NX / 4));
  transpose_split<<<dim3(3 * DIM / 64, DIM / 64), 256, 0, stream>>>(
      Wqkv, wth, wtl, DIM, 3 * DIM);
  transpose_split<<<dim3(DIM / 64, DIM / 64), 256, 0, stream>>>(
      Wo, woth, wotl, DIM, DIM);
  gate_kernel<<<BN_TOT / 256, 256, 0, stream>>>(cov, Wg1, bg1, Wg2, bg2, g);
  qkv_mfma<<<dim3(3 * DIM / 128, BN_TOT / 128), 256, 0, stream>>>(
      xh, xl, wth, wtl, Qh, Ql, Kh, Kl, Vh, Vl);
  attn_mfma<<<dim3(SEQ / 64, BATCH * HEADS), 256, 0, stream>>>(
      Qh, Ql, Kh, Kl, Vh, Vl, g, AOh, AOl);
  outproj_mfma<<<dim3(DIM / 64, BN_TOT / 128), 256, 0, stream>>>(
      AOh, AOl, woth, wotl, bo, out);
}

// Round 4
// 366.906 us; speedup vs baseline: 4.2031x; 1.1248x over previous
//
#include <hip/hip_runtime.h>
#include <math.h>

#define DIM 768
#define HEADS 12
#define HD 64
#define GATE_HID 192
#define BATCH 2
#define SEQ 2048
#define BN_TOT (BATCH*SEQ)          // 4096
#define ATT_SCALE 0.125f            // 64^-0.5

typedef unsigned short u16;
typedef __attribute__((ext_vector_type(8))) short bf16x8;
typedef __attribute__((ext_vector_type(4))) float f32x4;

#define MFMA16(a, b, c) __builtin_amdgcn_mfma_f32_16x16x32_bf16(a, b, c, 0, 0, 0)

__device__ inline u16 f2bf(float x) {
  union { float f; unsigned int u; } un; un.f = x;
  unsigned int r = un.u + 0x7FFFu + ((un.u >> 16) & 1u);  // RNE
  return (u16)(r >> 16);
}
__device__ inline float bf2f(u16 h) {
  union { float f; unsigned int u; } un; un.u = ((unsigned int)h) << 16;
  return un.f;
}

// ---------------------------------------------------------------------------
// Prep A: elementwise split fp32 -> bf16 hi/lo.
// ---------------------------------------------------------------------------
__global__ __launch_bounds__(256) void split_kernel(
    const float* __restrict__ src, u16* __restrict__ h, u16* __restrict__ l,
    int n4)
{
  int i = blockIdx.x * 256 + threadIdx.x;
  if (i >= n4) return;
  float4 v = reinterpret_cast<const float4*>(src)[i];
  float xs[4] = {v.x, v.y, v.z, v.w};
  ushort4 hv, lv;
  u16 hh;
  hh = f2bf(xs[0]); hv.x = hh; lv.x = f2bf(xs[0] - bf2f(hh));
  hh = f2bf(xs[1]); hv.y = hh; lv.y = f2bf(xs[1] - bf2f(hh));
  hh = f2bf(xs[2]); hv.z = hh; lv.z = f2bf(xs[2] - bf2f(hh));
  hh = f2bf(xs[3]); hv.w = hh; lv.w = f2bf(xs[3] - bf2f(hh));
  reinterpret_cast<ushort4*>(h)[i] = hv;
  reinterpret_cast<ushort4*>(l)[i] = lv;
}

// ---------------------------------------------------------------------------
// Prep B: transpose + split.  src [R][C] fp32 -> th/tl [C][R] bf16 hi/lo.
// ---------------------------------------------------------------------------
__global__ __launch_bounds__(256) void transpose_split(
    const float* __restrict__ src, u16* __restrict__ th, u16* __restrict__ tl,
    int R, int C)
{
  __shared__ float tile[64][65];
  const int t = threadIdx.x;
  const int c = t & 63, r4 = t >> 6;
  const int gr0 = blockIdx.y * 64, gc0 = blockIdx.x * 64;
  #pragma unroll
  for (int i = 0; i < 16; ++i) {
    int row = i * 4 + r4;
    tile[row][c] = src[(size_t)(gr0 + row) * C + gc0 + c];
  }
  __syncthreads();
  #pragma unroll
  for (int i = 0; i < 16; ++i) {
    int rr = i * 4 + r4;
    float v = tile[c][rr];
    u16 hh = f2bf(v);
    size_t o = (size_t)(gc0 + rr) * R + gr0 + c;
    th[o] = hh;
    tl[o] = f2bf(v - bf2f(hh));
  }
}

// ---------------------------------------------------------------------------
// Kernel 1: coverage gate MLP.
// ---------------------------------------------------------------------------
__global__ __launch_bounds__(256) void gate_kernel(
    const float* __restrict__ cov, const float* __restrict__ Wg1,
    const float* __restrict__ bg1, const float* __restrict__ Wg2,
    const float* __restrict__ bg2, float* __restrict__ g)
{
  int idx = blockIdx.x * 256 + threadIdx.x;   // b*SEQ + n
  if (idx >= BN_TOT) return;
  float c = cov[idx];
  float acc[HEADS];
  #pragma unroll
  for (int t = 0; t < HEADS; ++t) acc[t] = bg2[t];
  for (int j = 0; j < GATE_HID; ++j) {
    float hpre = c * Wg1[j] + bg1[j];
    float s = hpre / (1.f + __expf(-hpre));   // silu
    #pragma unroll
    for (int t = 0; t < HEADS; ++t) acc[t] += s * Wg2[j * HEADS + t];
  }
  int b = idx / SEQ, n = idx % SEQ;
  #pragma unroll
  for (int t = 0; t < HEADS; ++t) {
    float val = 1.f / (1.f + __expf(-acc[t]));
    g[(size_t)(b * HEADS + t) * SEQ + n] = val;
  }
}

// ---------------------------------------------------------------------------
// Kernel 2: qkv = x @ Wqkv via split-bf16 MFMA, T14 reg-prefetch pipeline.
// 128x128 tile, BK=32 (2 K-steps per loop iter), frag-blocked LDS.
// ---------------------------------------------------------------------------
#define QDECL(S) bf16x8 rah_##S[2], ral_##S[2], rbh_##S[2], rbl_##S[2];
#define QLOAD(S, kb) do { \
  _Pragma("unroll") for (int cc = 0; cc < 2; ++cc) { \
    int c = t + cc * 256; int mf = c >> 6, lg = (c >> 4) & 3, rr = c & 15; \
    size_t ga = (size_t)(row0 + mf * 16 + rr) * DIM + (kb) + lg * 8; \
    size_t gb = (size_t)(col0 + mf * 16 + rr) * DIM + (kb) + lg * 8; \
    rah_##S[cc] = *(const bf16x8*)&xh[ga]; \
    ral_##S[cc] = *(const bf16x8*)&xl[ga]; \
    rbh_##S[cc] = *(const bf16x8*)&bth[gb]; \
    rbl_##S[cc] = *(const bf16x8*)&btl[gb]; } } while (0)
#define QWRITE(S) do { \
  _Pragma("unroll") for (int cc = 0; cc < 2; ++cc) { int c = t + cc * 256; \
    *(bf16x8*)&AH[c * 8] = rah_##S[cc]; *(bf16x8*)&AL[c * 8] = ral_##S[cc]; \
    *(bf16x8*)&BH[c * 8] = rbh_##S[cc]; *(bf16x8*)&BL[c * 8] = rbl_##S[cc]; } } while (0)

__global__ __launch_bounds__(256) void qkv_mfma(
    const u16* __restrict__ xh, const u16* __restrict__ xl,
    const u16* __restrict__ bth, const u16* __restrict__ btl,
    u16* __restrict__ Qh, u16* __restrict__ Ql,
    u16* __restrict__ Kh, u16* __restrict__ Kl,
    u16* __restrict__ Vh, u16* __restrict__ Vl)
{
  __shared__ u16 AH[4096], AL[4096], BH[4096], BL[4096];
  const int t = threadIdx.x;
  const int w = t >> 6, l = t & 63;
  const int lan15 = l & 15, lgrp = l >> 4;
  const int row0 = blockIdx.y * 128, col0 = blockIdx.x * 128;
  const int wrf = (w >> 1) * 4, wcf = (w & 1) * 4;

  f32x4 acc[4][4];
  #pragma unroll
  for (int i = 0; i < 4; ++i)
    #pragma unroll
    for (int j = 0; j < 4; ++j) acc[i][j] = (f32x4){0.f, 0.f, 0.f, 0.f};

  auto qcompute = [&]() {
    bf16x8 ah4[4], al4[4];
    #pragma unroll
    for (int mi = 0; mi < 4; ++mi) {
      ah4[mi] = *reinterpret_cast<const bf16x8*>(&AH[((wrf + mi) * 64 + l) * 8]);
      al4[mi] = *reinterpret_cast<const bf16x8*>(&AL[((wrf + mi) * 64 + l) * 8]);
    }
    __builtin_amdgcn_s_setprio(1);
    #pragma unroll
    for (int ni = 0; ni < 4; ++ni) {
      bf16x8 bh = *reinterpret_cast<const bf16x8*>(&BH[((wcf + ni) * 64 + l) * 8]);
      bf16x8 bl = *reinterpret_cast<const bf16x8*>(&BL[((wcf + ni) * 64 + l) * 8]);
      #pragma unroll
      for (int mi = 0; mi < 4; ++mi) {
        acc[mi][ni] = MFMA16(ah4[mi], bh, acc[mi][ni]);
        acc[mi][ni] = MFMA16(ah4[mi], bl, acc[mi][ni]);
        acc[mi][ni] = MFMA16(al4[mi], bh, acc[mi][ni]);
      }
    }
    __builtin_amdgcn_s_setprio(0);
  };

  QDECL(A); QDECL(B);
  QLOAD(A, 0);
  for (int kb = 0; kb < DIM; kb += 64) {
    __syncthreads();
    QWRITE(A);
    QLOAD(B, kb + 32);
    __syncthreads();
    qcompute();
    __syncthreads();
    QWRITE(B);
    if (kb + 64 < DIM) QLOAD(A, kb + 64);
    __syncthreads();
    qcompute();
  }

  const int gc0 = col0 + (w & 1) * 64;
  const int sec = gc0 / DIM;
  const int hh_ = (gc0 % DIM) / HD;
  u16* DH = (sec == 0) ? Qh : ((sec == 1) ? Kh : Vh);
  u16* DL = (sec == 0) ? Ql : ((sec == 1) ? Kl : Vl);
  const int wrr = (w >> 1) * 64;
  #pragma unroll
  for (int mi = 0; mi < 4; ++mi) {
    #pragma unroll
    for (int reg = 0; reg < 4; ++reg) {
      int row = row0 + wrr + mi * 16 + lgrp * 4 + reg;
      size_t base =
          ((size_t)((row >> 11) * HEADS + hh_) * SEQ + (row & 2047)) * HD;
      #pragma unroll
      for (int ni = 0; ni < 4; ++ni) {
        float v = acc[mi][ni][reg];
        u16 hb = f2bf(v);
        DH[base + ni * 16 + lan15] = hb;
        DL[base + ni * 16 + lan15] = f2bf(v - bf2f(hb));
      }
    }
  }
}

// ---------------------------------------------------------------------------
// Kernel 3: flash attention, split-bf16 MFMA, T14 async-STAGE reg-prefetch,
// XCD-aware block swizzle (3 heads per XCD -> K/V fits 4MB L2).
// ---------------------------------------------------------------------------
#define DECL_TILE(S) \
  bf16x8 kh_##S[2], kl_##S[2]; ushort4 vh_##S[4], vl_##S[4]; float4 gv_##S;
#define LOAD_TILE(S, kt) do { \
  _Pragma("unroll") for (int cc = 0; cc < 2; ++cc) { \
    int c = t + cc * 256; int fi = c >> 6, lg = (c >> 4) & 3, rr = c & 15; \
    size_t gsrc = kvbase + (size_t)((kt) * 64 + (fi >> 1) * 16 + rr) * HD \
                  + (fi & 1) * 32 + lg * 8; \
    kh_##S[cc] = *(const bf16x8*)&Kh[gsrc]; \
    kl_##S[cc] = *(const bf16x8*)&Kl[gsrc]; } \
  _Pragma("unroll") for (int i = 0; i < 4; ++i) { \
    size_t gsrc = kvbase + (size_t)((kt) * 64 + vk0 + i) * HD + vd0; \
    vh_##S[i] = *(const ushort4*)&Vh[gsrc]; \
    vl_##S[i] = *(const ushort4*)&Vl[gsrc]; } \
  gv_##S.x = gp[(kt) * 64 +  0 + lan15]; \
  gv_##S.y = gp[(kt) * 64 + 16 + lan15]; \
  gv_##S.z = gp[(kt) * 64 + 32 + lan15]; \
  gv_##S.w = gp[(kt) * 64 + 48 + lan15]; } while (0)
#define VROW(S, j, C) do { \
  int row = vd0 + (j); int idx = (row * 64 + vk0) ^ ((row & 7) << 3); \
  ushort4 oh; oh.x = vh_##S[0].C; oh.y = vh_##S[1].C; oh.z = vh_##S[2].C; oh.w = vh_##S[3].C; \
  ushort4 ol; ol.x = vl_##S[0].C; ol.y = vl_##S[1].C; ol.z = vl_##S[2].C; ol.w = vl_##S[3].C; \
  *(ushort4*)&VThS[idx] = oh; *(ushort4*)&VTlS[idx] = ol; } while (0)
#define WRITE_TILE(S) do { \
  _Pragma("unroll") for (int cc = 0; cc < 2; ++cc) { int c = t + cc * 256; \
    *(bf16x8*)&KhS[c * 8] = kh_##S[cc]; *(bf16x8*)&KlS[c * 8] = kl_##S[cc]; } \
  VROW(S, 0, x); VROW(S, 1, y); VROW(S, 2, z); VROW(S, 3, w); } while (0)

__global__ __launch_bounds__(256) void attn_mfma(
    const u16* __restrict__ Qh, const u16* __restrict__ Ql,
    const u16* __restrict__ Kh, const u16* __restrict__ Kl,
    const u16* __restrict__ Vh, const u16* __restrict__ Vl,
    const float* __restrict__ G,
    u16* __restrict__ AOh, u16* __restrict__ AOl)
{
  __shared__ u16 KhS[4096], KlS[4096];
  __shared__ u16 VThS[4096], VTlS[4096];   // [d][key], swizzled
  __shared__ u16 PhS[4096], PlS[4096];     // [q][key], swizzled

  const int t     = threadIdx.x;
  const int w     = t >> 6, l = t & 63;
  const int lan15 = l & 15;
  const int lgrp  = l >> 4;
  // XCD swizzle: block n -> xcd = n%8 owns heads 3*(n%8)..+2 (K/V < 4MB L2)
  const int n   = blockIdx.x;          // 0..767
  const int s_  = n >> 3;              // 0..95
  const int bh  = (n & 7) * 3 + (s_ >> 5);
  const int qt  = s_ & 31;
  const int b   = bh / HEADS;
  const int h   = bh % HEADS;
  const size_t kvbase = (size_t)bh * SEQ * HD;
  const float* gp = G + (size_t)bh * SEQ;

  // Q fragments (hi/lo) straight from global
  bf16x8 qh[2], ql[2];
  {
    size_t qrow = kvbase + (size_t)(qt * 64 + w * 16 + lan15) * HD;
    #pragma unroll
    for (int s = 0; s < 2; ++s) {
      qh[s] = *reinterpret_cast<const bf16x8*>(&Qh[qrow + s * 32 + lgrp * 8]);
      ql[s] = *reinterpret_cast<const bf16x8*>(&Ql[qrow + s * 32 + lgrp * 8]);
    }
  }

  f32x4 o[4];
  #pragma unroll
  for (int dt = 0; dt < 4; ++dt) o[dt] = (f32x4){0.f, 0.f, 0.f, 0.f};
  float mrun[4] = {-INFINITY, -INFINITY, -INFINITY, -INFINITY};
  float lrun[4] = {0.f, 0.f, 0.f, 0.f};

  const int vk0 = (t & 15) * 4;     // V-stage: key base
  const int vd0 = (t >> 4) * 4;     // V-stage: d base

  auto compute_tile = [&](float4 gvv) {
    float gvals[4] = {gvv.x, gvv.y, gvv.z, gvv.w};
    // ---- S = Q K^T (split-bf16, 3 terms) ----
    f32x4 acc[4];
    #pragma unroll
    for (int ct = 0; ct < 4; ++ct) acc[ct] = (f32x4){0.f, 0.f, 0.f, 0.f};
    __builtin_amdgcn_s_setprio(1);
    #pragma unroll
    for (int s = 0; s < 2; ++s) {
      #pragma unroll
      for (int ct = 0; ct < 4; ++ct) {
        int bidx = ((ct * 2 + s) * 64 + l) * 8;
        bf16x8 kbh = *reinterpret_cast<const bf16x8*>(&KhS[bidx]);
        bf16x8 kbl = *reinterpret_cast<const bf16x8*>(&KlS[bidx]);
        acc[ct] = MFMA16(qh[s], kbh, acc[ct]);
        acc[ct] = MFMA16(qh[s], kbl, acc[ct]);
        acc[ct] = MFMA16(ql[s], kbh, acc[ct]);
      }
    }
    __builtin_amdgcn_s_setprio(0);

    // ---- gate + online softmax ----
    float sv[4][4];
    #pragma unroll
    for (int ct = 0; ct < 4; ++ct)
      #pragma unroll
      for (int r = 0; r < 4; ++r)
        sv[ct][r] = acc[ct][r] * ATT_SCALE * gvals[ct];

    float rmax[4];
    #pragma unroll
    for (int r = 0; r < 4; ++r) {
      rmax[r] = fmaxf(fmaxf(sv[0][r], sv[1][r]), fmaxf(sv[2][r], sv[3][r]));
      #pragma unroll
      for (int off = 1; off < 16; off <<= 1)
        rmax[r] = fmaxf(rmax[r], __shfl_xor(rmax[r], off));
    }
    float p[4][4], rsum[4];
    #pragma unroll
    for (int r = 0; r < 4; ++r) {
      float mnew = fmaxf(mrun[r], rmax[r]);
      float fsc  = __expf(mrun[r] - mnew);
      mrun[r] = mnew;
      lrun[r] *= fsc;
      #pragma unroll
      for (int dt = 0; dt < 4; ++dt) o[dt][r] *= fsc;
      float s0 = 0.f;
      #pragma unroll
      for (int ct = 0; ct < 4; ++ct) {
        p[ct][r] = __expf(sv[ct][r] - mnew);
        s0 += p[ct][r];
      }
      rsum[r] = s0;
    }
    #pragma unroll
    for (int r = 0; r < 4; ++r) {
      #pragma unroll
      for (int off = 1; off < 16; off <<= 1)
        rsum[r] += __shfl_xor(rsum[r], off);
      lrun[r] += rsum[r];
    }

    // ---- P -> LDS (hi/lo, swizzled; wave-private rows) ----
    #pragma unroll
    for (int r = 0; r < 4; ++r) {
      int prow = w * 16 + 4 * lgrp + r;
      #pragma unroll
      for (int ct = 0; ct < 4; ++ct) {
        float pv = p[ct][r];
        u16 hb = f2bf(pv);
        int idx = (prow * 64 + ct * 16 + lan15) ^ ((prow & 7) << 3);
        PhS[idx] = hb;
        PlS[idx] = f2bf(pv - bf2f(hb));
      }
    }

    // ---- O += P V (split-bf16, 3 terms) ----
    __builtin_amdgcn_s_setprio(1);
    #pragma unroll
    for (int s = 0; s < 2; ++s) {
      int arow = w * 16 + lan15;
      int aidx = (arow * 64 + s * 32 + 8 * lgrp) ^ ((arow & 7) << 3);
      bf16x8 pah = *reinterpret_cast<const bf16x8*>(&PhS[aidx]);
      bf16x8 pal = *reinterpret_cast<const bf16x8*>(&PlS[aidx]);
      #pragma unroll
      for (int dt = 0; dt < 4; ++dt) {
        int brow = dt * 16 + lan15;
        int bidx = (brow * 64 + s * 32 + 8 * lgrp) ^ ((brow & 7) << 3);
        bf16x8 vbh = *reinterpret_cast<const bf16x8*>(&VThS[bidx]);
        bf16x8 vbl = *reinterpret_cast<const bf16x8*>(&VTlS[bidx]);
        o[dt] = MFMA16(pah, vbh, o[dt]);
        o[dt] = MFMA16(pah, vbl, o[dt]);
        o[dt] = MFMA16(pal, vbh, o[dt]);
      }
    }
    __builtin_amdgcn_s_setprio(0);
  };

  DECL_TILE(A); DECL_TILE(B);
  LOAD_TILE(A, 0);
  for (int kt = 0; kt < SEQ / 64; kt += 2) {
    __syncthreads();                 // prior readers of LDS done
    WRITE_TILE(A);
    LOAD_TILE(B, kt + 1);            // prefetch under compute(A)
    __syncthreads();
    compute_tile(gv_A);
    __syncthreads();
    WRITE_TILE(B);
    if (kt + 2 < SEQ / 64) LOAD_TILE(A, kt + 2);
    __syncthreads();
    compute_tile(gv_B);
  }

  // ---- epilogue: normalize, split, write AO hi/lo ----
  #pragma unroll
  for (int r = 0; r < 4; ++r) {
    float inv = 1.f / lrun[r];
    int qrow_g = qt * 64 + w * 16 + 4 * lgrp + r;
    size_t base = (size_t)(b * SEQ + qrow_g) * DIM + h * HD;
    #pragma unroll
    for (int dt = 0; dt < 4; ++dt) {
      float v = o[dt][r] * inv;
      u16 hb = f2bf(v);
      AOh[base + dt * 16 + lan15] = hb;
      AOl[base + dt * 16 + lan15] = f2bf(v - bf2f(hb));
    }
  }
}

// ---------------------------------------------------------------------------
// Kernel 4: out = AO @ Wo + bo, split-bf16 MFMA, reg-prefetch pipeline.
// ---------------------------------------------------------------------------
#define ODECL(S) bf16x8 rah_##S[2], ral_##S[2], rbh_##S, rbl_##S;
#define OLOAD(S, kb) do { \
  _Pragma("unroll") for (int cc = 0; cc < 2; ++cc) { \
    int c = t + cc * 256; int mf = c >> 6, lg = (c >> 4) & 3, rr = c & 15; \
    size_t ga = (size_t)(row0 + mf * 16 + rr) * DIM + (kb) + lg * 8; \
    rah_##S[cc] = *(const bf16x8*)&ah[ga]; \
    ral_##S[cc] = *(const bf16x8*)&al[ga]; } \
  { int c = t; int nf = c >> 6, lg = (c >> 4) & 3, rr = c & 15; \
    size_t gb = (size_t)(col0 + nf * 16 + rr) * DIM + (kb) + lg * 8; \
    rbh_##S = *(const bf16x8*)&bth[gb]; \
    rbl_##S = *(const bf16x8*)&btl[gb]; } } while (0)
#define OWRITE(S) do { \
  _Pragma("unroll") for (int cc = 0; cc < 2; ++cc) { int c = t + cc * 256; \
    *(bf16x8*)&AH[c * 8] = rah_##S[cc]; *(bf16x8*)&AL[c * 8] = ral_##S[cc]; } \
  *(bf16x8*)&BH[t * 8] = rbh_##S; *(bf16x8*)&BL[t * 8] = rbl_##S; } while (0)

__global__ __launch_bounds__(256) void outproj_mfma(
    const u16* __restrict__ ah, const u16* __restrict__ al,
    const u16* __restrict__ bth, const u16* __restrict__ btl,
    const float* __restrict__ bo, float* __restrict__ out)
{
  __shared__ u16 AH[4096], AL[4096], BH[2048], BL[2048];
  const int t = threadIdx.x;
  const int w = t >> 6, l = t & 63;
  const int lan15 = l & 15, lgrp = l >> 4;
  const int row0 = blockIdx.y * 128, col0 = blockIdx.x * 64;
  const int wrf = (w >> 1) * 4, wcf = (w & 1) * 2;

  f32x4 acc[4][2];
  #pragma unroll
  for (int i = 0; i < 4; ++i)
    #pragma unroll
    for (int j = 0; j < 2; ++j) acc[i][j] = (f32x4){0.f, 0.f, 0.f, 0.f};

  auto ocompute = [&]() {
    bf16x8 ah4[4], al4[4];
    #pragma unroll
    for (int mi = 0; mi < 4; ++mi) {
      ah4[mi] = *reinterpret_cast<const bf16x8*>(&AH[((wrf + mi) * 64 + l) * 8]);
      al4[mi] = *reinterpret_cast<const bf16x8*>(&AL[((wrf + mi) * 64 + l) * 8]);
    }
    __builtin_amdgcn_s_setprio(1);
    #pragma unroll
    for (int ni = 0; ni < 2; ++ni) {
      bf16x8 bh = *reinterpret_cast<const bf16x8*>(&BH[((wcf + ni) * 64 + l) * 8]);
      bf16x8 bl = *reinterpret_cast<const bf16x8*>(&BL[((wcf + ni) * 64 + l) * 8]);
      #pragma unroll
      for (int mi = 0; mi < 4; ++mi) {
        acc[mi][ni] = MFMA16(ah4[mi], bh, acc[mi][ni]);
        acc[mi][ni] = MFMA16(ah4[mi], bl, acc[mi][ni]);
        acc[mi][ni] = MFMA16(al4[mi], bh, acc[mi][ni]);
      }
    }
    __builtin_amdgcn_s_setprio(0);
  };

  ODECL(A); ODECL(B);
  OLOAD(A, 0);
  for (int kb = 0; kb < DIM; kb += 64) {
    __syncthreads();
    OWRITE(A);
    OLOAD(B, kb + 32);
    __syncthreads();
    ocompute();
    __syncthreads();
    OWRITE(B);
    if (kb + 64 < DIM) OLOAD(A, kb + 64);
    __syncthreads();
    ocompute();
  }

  const int wrr = (w >> 1) * 64, wcc = (w & 1) * 32;
  #pragma unroll
  for (int mi = 0; mi < 4; ++mi) {
    #pragma unroll
    for (int reg = 0; reg < 4; ++reg) {
      int row = row0 + wrr + mi * 16 + lgrp * 4 + reg;
      #pragma unroll
      for (int ni = 0; ni < 2; ++ni) {
        int col = col0 + wcc + ni * 16 + lan15;
        out[(size_t)row * DIM + col] = acc[mi][ni][reg] + bo[col];
      }
    }
  }
}

// ---------------------------------------------------------------------------
extern "C" void kernel_launch(void* const* d_in, const int* in_sizes, int n_in,
                              void* d_out, int out_size, void* d_ws, size_t ws_size,
                              hipStream_t stream) {
  const float* x    = (const float*)d_in[0];
  const float* cov  = (const float*)d_in[1];
  const float* Wqkv = (const float*)d_in[2];
  const float* Wo   = (const float*)d_in[3];
  const float* bo   = (const float*)d_in[4];
  const float* Wg1  = (const float*)d_in[5];
  const float* bg1  = (const float*)d_in[6];
  const float* Wg2  = (const float*)d_in[7];
  const float* bg2  = (const float*)d_in[8];
  float* out = (float*)d_out;

  const size_t NX   = (size_t)BN_TOT * DIM;
  const size_t NWQ  = (size_t)DIM * 3 * DIM;
  const size_t NWO  = (size_t)DIM * DIM;
  const size_t NHEA = (size_t)BATCH * HEADS * SEQ * HD;

  float* g   = (float*)d_ws;
  u16* base  = (u16*)(g + (size_t)BATCH * HEADS * SEQ);
  u16* xh    = base;          u16* xl   = xh + NX;
  u16* wth   = xl + NX;       u16* wtl  = wth + NWQ;
  u16* woth  = wtl + NWQ;     u16* wotl = woth + NWO;
  u16* Qh    = wotl + NWO;    u16* Ql   = Qh + NHEA;
  u16* Kh    = Ql + NHEA;     u16* Kl   = Kh + NHEA;
  u16* Vh    = Kl + NHEA;     u16* Vl   = Vh + NHEA;
  u16* AOh   = Vl + NHEA;     u16* AOl  = AOh + NX;

  split_kernel<<<(int)(NX / 1024), 256, 0, stream>>>(x, xh, xl, (int)(NX / 4));
  transpose_split<<<dim3(3 * DIM / 64, DIM / 64), 256, 0, stream>>>(
      Wqkv, wth, wtl, DIM, 3 * DIM);
  transpose_split<<<dim3(DIM / 64, DIM / 64), 256, 0, stream>>>(
      Wo, woth, wotl, DIM, DIM);
  gate_kernel<<<BN_TOT / 256, 256, 0, stream>>>(cov, Wg1, bg1, Wg2, bg2, g);
  qkv_mfma<<<dim3(3 * DIM / 128, BN_TOT / 128), 256, 0, stream>>>(
      xh, xl, wth, wtl, Qh, Ql, Kh, Kl, Vh, Vl);
  attn_mfma<<<SEQ / 64 * BATCH * HEADS, 256, 0, stream>>>(
      Qh, Ql, Kh, Kl, Vh, Vl, g, AOh, AOl);
  outproj_mfma<<<dim3(DIM / 64, BN_TOT / 128), 256, 0, stream>>>(
      AOh, AOl, woth, wotl, bo, out);
}

// Round 6
// 324.560 us; speedup vs baseline: 4.7514x; 1.1305x over previous
//
#include <hip/hip_runtime.h>
#include <math.h>

#define DIM 768
#define HEADS 12
#define HD 64
#define GATE_HID 192
#define BATCH 2
#define SEQ 2048
#define BN_TOT (BATCH*SEQ)          // 4096
#define ATT_SCALE 0.125f            // 64^-0.5
#define SCL2E 0.180336879f          // ATT_SCALE * log2(e)

typedef unsigned short u16;
typedef __attribute__((ext_vector_type(8))) short bf16x8;
typedef __attribute__((ext_vector_type(8))) _Float16 f16x8;
typedef __attribute__((ext_vector_type(2))) __fp16 fp16v2;
typedef __attribute__((ext_vector_type(4))) float f32x4;

#define MFMA16(a, b, c)  __builtin_amdgcn_mfma_f32_16x16x32_bf16(a, b, c, 0, 0, 0)
#define MFMA16F(a, b, c) __builtin_amdgcn_mfma_f32_16x16x32_f16(a, b, c, 0, 0, 0)

__device__ inline u16 f2bf(float x) {
  union { float f; unsigned int u; } un; un.f = x;
  unsigned int r = un.u + 0x7FFFu + ((un.u >> 16) & 1u);  // RNE
  return (u16)(r >> 16);
}
__device__ inline float bf2f(u16 h) {
  union { float f; unsigned int u; } un; un.u = ((unsigned int)h) << 16;
  return un.f;
}
__device__ inline unsigned fbits(float x) {
  union { float f; unsigned int u; } un; un.f = x; return un.u;
}
__device__ inline float bitsf(unsigned u) {
  union { float f; unsigned int u; } un; un.u = u; return un.f;
}
__device__ inline float fexp2(float x) { return exp2f(x); }

// ---------------------------------------------------------------------------
// Prep A: elementwise split fp32 -> bf16 hi/lo.
// ---------------------------------------------------------------------------
__global__ __launch_bounds__(256) void split_kernel(
    const float* __restrict__ src, u16* __restrict__ h, u16* __restrict__ l,
    int n4)
{
  int i = blockIdx.x * 256 + threadIdx.x;
  if (i >= n4) return;
  float4 v = reinterpret_cast<const float4*>(src)[i];
  float xs[4] = {v.x, v.y, v.z, v.w};
  ushort4 hv, lv;
  u16 hh;
  hh = f2bf(xs[0]); hv.x = hh; lv.x = f2bf(xs[0] - bf2f(hh));
  hh = f2bf(xs[1]); hv.y = hh; lv.y = f2bf(xs[1] - bf2f(hh));
  hh = f2bf(xs[2]); hv.z = hh; lv.z = f2bf(xs[2] - bf2f(hh));
  hh = f2bf(xs[3]); hv.w = hh; lv.w = f2bf(xs[3] - bf2f(hh));
  reinterpret_cast<ushort4*>(h)[i] = hv;
  reinterpret_cast<ushort4*>(l)[i] = lv;
}

// ---------------------------------------------------------------------------
// Prep B: transpose + split.  src [R][C] fp32 -> th/tl [C][R] bf16 hi/lo.
// ---------------------------------------------------------------------------
__global__ __launch_bounds__(256) void transpose_split(
    const float* __restrict__ src, u16* __restrict__ th, u16* __restrict__ tl,
    int R, int C)
{
  __shared__ float tile[64][65];
  const int t = threadIdx.x;
  const int c = t & 63, r4 = t >> 6;
  const int gr0 = blockIdx.y * 64, gc0 = blockIdx.x * 64;
  #pragma unroll
  for (int i = 0; i < 16; ++i) {
    int row = i * 4 + r4;
    tile[row][c] = src[(size_t)(gr0 + row) * C + gc0 + c];
  }
  __syncthreads();
  #pragma unroll
  for (int i = 0; i < 16; ++i) {
    int rr = i * 4 + r4;
    float v = tile[c][rr];
    u16 hh = f2bf(v);
    size_t o = (size_t)(gc0 + rr) * R + gr0 + c;
    th[o] = hh;
    tl[o] = f2bf(v - bf2f(hh));
  }
}

// ---------------------------------------------------------------------------
// Kernel 1: coverage gate MLP.
// ---------------------------------------------------------------------------
__global__ __launch_bounds__(256) void gate_kernel(
    const float* __restrict__ cov, const float* __restrict__ Wg1,
    const float* __restrict__ bg1, const float* __restrict__ Wg2,
    const float* __restrict__ bg2, float* __restrict__ g)
{
  int idx = blockIdx.x * 256 + threadIdx.x;   // b*SEQ + n
  if (idx >= BN_TOT) return;
  float c = cov[idx];
  float acc[HEADS];
  #pragma unroll
  for (int t = 0; t < HEADS; ++t) acc[t] = bg2[t];
  for (int j = 0; j < GATE_HID; ++j) {
    float hpre = c * Wg1[j] + bg1[j];
    float s = hpre / (1.f + __expf(-hpre));   // silu
    #pragma unroll
    for (int t = 0; t < HEADS; ++t) acc[t] += s * Wg2[j * HEADS + t];
  }
  int b = idx / SEQ, n = idx % SEQ;
  #pragma unroll
  for (int t = 0; t < HEADS; ++t) {
    float val = 1.f / (1.f + __expf(-acc[t]));
    g[(size_t)(b * HEADS + t) * SEQ + n] = val;
  }
}

// ---------------------------------------------------------------------------
// Kernel 2: qkv = x @ Wqkv via split-bf16 MFMA, reg-prefetch pipeline.
// Q/K written as bf16 hi/lo in kappa-d layout (packed b64 stores);
// V written as single fp16 (real-d layout).
// ---------------------------------------------------------------------------
#define QDECL(S) bf16x8 rah_##S[2], ral_##S[2], rbh_##S[2], rbl_##S[2];
#define QLOAD(S, kb) do { \
  _Pragma("unroll") for (int cc = 0; cc < 2; ++cc) { \
    int c = t + cc * 256; int mf = c >> 6, lg = (c >> 4) & 3, rr = c & 15; \
    size_t ga = (size_t)(row0 + mf * 16 + rr) * DIM + (kb) + lg * 8; \
    size_t gb = (size_t)(col0 + mf * 16 + rr) * DIM + (kb) + lg * 8; \
    rah_##S[cc] = *(const bf16x8*)&xh[ga]; \
    ral_##S[cc] = *(const bf16x8*)&xl[ga]; \
    rbh_##S[cc] = *(const bf16x8*)&bth[gb]; \
    rbl_##S[cc] = *(const bf16x8*)&btl[gb]; } } while (0)
#define QWRITE(S) do { \
  _Pragma("unroll") for (int cc = 0; cc < 2; ++cc) { int c = t + cc * 256; \
    *(bf16x8*)&AH[c * 8] = rah_##S[cc]; *(bf16x8*)&AL[c * 8] = ral_##S[cc]; \
    *(bf16x8*)&BH[c * 8] = rbh_##S[cc]; *(bf16x8*)&BL[c * 8] = rbl_##S[cc]; } } while (0)

__global__ __launch_bounds__(256) void qkv_mfma(
    const u16* __restrict__ xh, const u16* __restrict__ xl,
    const u16* __restrict__ bth, const u16* __restrict__ btl,
    u16* __restrict__ Qh, u16* __restrict__ Ql,
    u16* __restrict__ Kh, u16* __restrict__ Kl,
    u16* __restrict__ V16)
{
  __shared__ u16 AH[4096], AL[4096], BH[4096], BL[4096];
  const int t = threadIdx.x;
  const int w = t >> 6, l = t & 63;
  const int lan15 = l & 15, lgrp = l >> 4;
  const int row0 = blockIdx.y * 128, col0 = blockIdx.x * 128;
  const int wrf = (w >> 1) * 4, wcf = (w & 1) * 4;

  f32x4 acc[4][4];
  #pragma unroll
  for (int i = 0; i < 4; ++i)
    #pragma unroll
    for (int j = 0; j < 4; ++j) acc[i][j] = (f32x4){0.f, 0.f, 0.f, 0.f};

  auto qcompute = [&]() {
    bf16x8 ah4[4], al4[4];
    #pragma unroll
    for (int mi = 0; mi < 4; ++mi) {
      ah4[mi] = *reinterpret_cast<const bf16x8*>(&AH[((wrf + mi) * 64 + l) * 8]);
      al4[mi] = *reinterpret_cast<const bf16x8*>(&AL[((wrf + mi) * 64 + l) * 8]);
    }
    __builtin_amdgcn_s_setprio(1);
    #pragma unroll
    for (int ni = 0; ni < 4; ++ni) {
      bf16x8 bh = *reinterpret_cast<const bf16x8*>(&BH[((wcf + ni) * 64 + l) * 8]);
      bf16x8 bl = *reinterpret_cast<const bf16x8*>(&BL[((wcf + ni) * 64 + l) * 8]);
      #pragma unroll
      for (int mi = 0; mi < 4; ++mi) {
        acc[mi][ni] = MFMA16(ah4[mi], bh, acc[mi][ni]);
        acc[mi][ni] = MFMA16(ah4[mi], bl, acc[mi][ni]);
        acc[mi][ni] = MFMA16(al4[mi], bh, acc[mi][ni]);
      }
    }
    __builtin_amdgcn_s_setprio(0);
  };

  QDECL(A); QDECL(B);
  QLOAD(A, 0);
  for (int kb = 0; kb < DIM; kb += 64) {
    __syncthreads();
    QWRITE(A);
    QLOAD(B, kb + 32);
    __syncthreads();
    qcompute();
    __syncthreads();
    QWRITE(B);
    if (kb + 64 < DIM) QLOAD(A, kb + 64);
    __syncthreads();
    qcompute();
  }

  // epilogue: wave's 64-col block = one head of one section.
  const int gc0 = col0 + (w & 1) * 64;
  const int sec = gc0 / DIM;
  const int hh_ = (gc0 % DIM) / HD;
  const int wrr = (w >> 1) * 64;
  #pragma unroll
  for (int mi = 0; mi < 4; ++mi) {
    #pragma unroll
    for (int reg = 0; reg < 4; ++reg) {
      int row = row0 + wrr + mi * 16 + lgrp * 4 + reg;
      size_t base =
          ((size_t)((row >> 11) * HEADS + hh_) * SEQ + (row & 2047)) * HD;
      float f0 = acc[mi][0][reg], f1 = acc[mi][1][reg];
      float f2 = acc[mi][2][reg], f3 = acc[mi][3][reg];
      if (sec < 2) {
        // kappa-d layout: kappa = lan15*4 + ni -> packed b64 hi/lo stores
        u16* DH = (sec == 0) ? Qh : Kh;
        u16* DL = (sec == 0) ? Ql : Kl;
        unsigned u0 = fbits(f0), u1 = fbits(f1), u2 = fbits(f2), u3 = fbits(f3);
        uint2 hiw, low;
        hiw.x = (u0 >> 16) | (u1 & 0xFFFF0000u);
        hiw.y = (u2 >> 16) | (u3 & 0xFFFF0000u);
        unsigned l0 = fbits(f0 - bitsf(u0 & 0xFFFF0000u));
        unsigned l1 = fbits(f1 - bitsf(u1 & 0xFFFF0000u));
        unsigned l2 = fbits(f2 - bitsf(u2 & 0xFFFF0000u));
        unsigned l3 = fbits(f3 - bitsf(u3 & 0xFFFF0000u));
        low.x = (l0 >> 16) | (l1 & 0xFFFF0000u);
        low.y = (l2 >> 16) | (l3 & 0xFFFF0000u);
        *reinterpret_cast<uint2*>(&DH[base + lan15 * 4]) = hiw;
        *reinterpret_cast<uint2*>(&DL[base + lan15 * 4]) = low;
      } else {
        union { _Float16 h; u16 u; } cv;
        cv.h = (_Float16)f0; V16[base +  0 + lan15] = cv.u;
        cv.h = (_Float16)f1; V16[base + 16 + lan15] = cv.u;
        cv.h = (_Float16)f2; V16[base + 32 + lan15] = cv.u;
        cv.h = (_Float16)f3; V16[base + 48 + lan15] = cv.u;
      }
    }
  }
}

// ---------------------------------------------------------------------------
// Kernel 3: flash attention.  QK^T split-bf16 (3 MFMA terms); softmax in
// exp2 domain; P -> fp16 via v_cvt_pkrtz; PV single-term fp16 MFMA.
// P and V^T share a common key-permutation kappa = (key&15)*4 + (key>>4).
// T14 reg-prefetch double pipeline + XCD-aware swizzle.
// ---------------------------------------------------------------------------
#define DECL_TILE(S) \
  bf16x8 kh_##S[2], kl_##S[2]; ushort4 vv_##S[4]; float4 gv_##S;
#define LOAD_TILE(S, kt) do { \
  _Pragma("unroll") for (int cc = 0; cc < 2; ++cc) { \
    int c = t + cc * 256; int fi = c >> 6, lg = (c >> 4) & 3, rr = c & 15; \
    size_t gsrc = kvbase + (size_t)((kt) * 64 + (fi >> 1) * 16 + rr) * HD \
                  + (fi & 1) * 32 + lg * 8; \
    kh_##S[cc] = *(const bf16x8*)&Kh[gsrc]; \
    kl_##S[cc] = *(const bf16x8*)&Kl[gsrc]; } \
  _Pragma("unroll") for (int i = 0; i < 4; ++i) { \
    size_t gsrc = kvbase + (size_t)((kt) * 64 + vm + i * 16) * HD + vd0; \
    vv_##S[i] = *(const ushort4*)&V16[gsrc]; } \
  gv_##S.x = gp[(kt) * 64 +  0 + lan15]; \
  gv_##S.y = gp[(kt) * 64 + 16 + lan15]; \
  gv_##S.z = gp[(kt) * 64 + 32 + lan15]; \
  gv_##S.w = gp[(kt) * 64 + 48 + lan15]; } while (0)
#define VROW(S, j, C) do { \
  int row = vd0 + (j); int idx = (row * 64 + vm * 4) ^ ((row & 7) << 3); \
  ushort4 ov; ov.x = vv_##S[0].C; ov.y = vv_##S[1].C; \
  ov.z = vv_##S[2].C; ov.w = vv_##S[3].C; \
  *(ushort4*)&VTS[idx] = ov; } while (0)
#define WRITE_TILE(S) do { \
  _Pragma("unroll") for (int cc = 0; cc < 2; ++cc) { int c = t + cc * 256; \
    *(bf16x8*)&KhS[c * 8] = kh_##S[cc]; *(bf16x8*)&KlS[c * 8] = kl_##S[cc]; } \
  VROW(S, 0, x); VROW(S, 1, y); VROW(S, 2, z); VROW(S, 3, w); } while (0)

__global__ __launch_bounds__(256) void attn_mfma(
    const u16* __restrict__ Qh, const u16* __restrict__ Ql,
    const u16* __restrict__ Kh, const u16* __restrict__ Kl,
    const u16* __restrict__ V16, const float* __restrict__ G,
    u16* __restrict__ AOh, u16* __restrict__ AOl)
{
  __shared__ u16 KhS[4096], KlS[4096];
  __shared__ u16 VTS[4096];   // [d][kappa], fp16, swizzled
  __shared__ u16 PS[4096];    // [q][kappa], fp16, swizzled

  const int t     = threadIdx.x;
  const int w     = t >> 6, l = t & 63;
  const int lan15 = l & 15;
  const int lgrp  = l >> 4;
  // XCD swizzle: block n -> xcd = n%8 owns heads 3*(n%8)..+2
  const int n   = blockIdx.x;          // 0..767
  const int s_  = n >> 3;              // 0..95
  const int bh  = (n & 7) * 3 + (s_ >> 5);
  const int qt  = s_ & 31;
  const int b   = bh / HEADS;
  const int h   = bh % HEADS;
  const size_t kvbase = (size_t)bh * SEQ * HD;
  const float* gp = G + (size_t)bh * SEQ;

  // Q fragments (hi/lo, kappa-d layout) straight from global
  bf16x8 qh[2], ql[2];
  {
    size_t qrow = kvbase + (size_t)(qt * 64 + w * 16 + lan15) * HD;
    #pragma unroll
    for (int s = 0; s < 2; ++s) {
      qh[s] = *reinterpret_cast<const bf16x8*>(&Qh[qrow + s * 32 + lgrp * 8]);
      ql[s] = *reinterpret_cast<const bf16x8*>(&Ql[qrow + s * 32 + lgrp * 8]);
    }
  }

  f32x4 o[4];
  #pragma unroll
  for (int dt = 0; dt < 4; ++dt) o[dt] = (f32x4){0.f, 0.f, 0.f, 0.f};
  float mrun[4] = {-INFINITY, -INFINITY, -INFINITY, -INFINITY};
  float lrun[4] = {0.f, 0.f, 0.f, 0.f};

  const int vm  = t & 15;           // V-stage: key low bits
  const int vd0 = (t >> 4) * 4;     // V-stage: d base

  auto compute_tile = [&](float4 gvv) {
    // fold gate * scale * log2e into per-column constant
    float gl[4] = {gvv.x * SCL2E, gvv.y * SCL2E, gvv.z * SCL2E, gvv.w * SCL2E};
    // ---- S = Q K^T (split-bf16, 3 terms) ----
    f32x4 acc[4];
    #pragma unroll
    for (int ct = 0; ct < 4; ++ct) acc[ct] = (f32x4){0.f, 0.f, 0.f, 0.f};
    __builtin_amdgcn_s_setprio(1);
    #pragma unroll
    for (int s = 0; s < 2; ++s) {
      #pragma unroll
      for (int ct = 0; ct < 4; ++ct) {
        int bidx = ((ct * 2 + s) * 64 + l) * 8;
        bf16x8 kbh = *reinterpret_cast<const bf16x8*>(&KhS[bidx]);
        bf16x8 kbl = *reinterpret_cast<const bf16x8*>(&KlS[bidx]);
        acc[ct] = MFMA16(qh[s], kbh, acc[ct]);
        acc[ct] = MFMA16(qh[s], kbl, acc[ct]);
        acc[ct] = MFMA16(ql[s], kbh, acc[ct]);
      }
    }
    __builtin_amdgcn_s_setprio(0);

    // ---- gate + online softmax (exp2 domain) ----
    float sv[4][4];
    #pragma unroll
    for (int ct = 0; ct < 4; ++ct)
      #pragma unroll
      for (int r = 0; r < 4; ++r)
        sv[ct][r] = acc[ct][r] * gl[ct];

    float rmax[4];
    #pragma unroll
    for (int r = 0; r < 4; ++r) {
      rmax[r] = fmaxf(fmaxf(sv[0][r], sv[1][r]), fmaxf(sv[2][r], sv[3][r]));
      #pragma unroll
      for (int off = 1; off < 16; off <<= 1)
        rmax[r] = fmaxf(rmax[r], __shfl_xor(rmax[r], off));
    }
    float p[4][4], rsum[4];
    #pragma unroll
    for (int r = 0; r < 4; ++r) {
      float mnew = fmaxf(mrun[r], rmax[r]);
      float fsc  = fexp2(mrun[r] - mnew);
      mrun[r] = mnew;
      lrun[r] *= fsc;
      #pragma unroll
      for (int dt = 0; dt < 4; ++dt) o[dt][r] *= fsc;
      float s0 = 0.f;
      #pragma unroll
      for (int ct = 0; ct < 4; ++ct) {
        p[ct][r] = fexp2(sv[ct][r] - mnew);
        s0 += p[ct][r];
      }
      rsum[r] = s0;
    }
    #pragma unroll
    for (int r = 0; r < 4; ++r) {
      #pragma unroll
      for (int off = 1; off < 16; off <<= 1)
        rsum[r] += __shfl_xor(rsum[r], off);
      lrun[r] += rsum[r];
    }

    // ---- P -> LDS fp16 (kappa layout: kappa = lan15*4 + ct) ----
    #pragma unroll
    for (int r = 0; r < 4; ++r) {
      int prow = w * 16 + 4 * lgrp + r;
      union { fp16v2 h; unsigned u; } cA, cB;
      cA.h = __builtin_amdgcn_cvt_pkrtz(p[0][r], p[1][r]);
      cB.h = __builtin_amdgcn_cvt_pkrtz(p[2][r], p[3][r]);
      uint2 st; st.x = cA.u; st.y = cB.u;
      int idx = (prow * 64 + lan15 * 4) ^ ((prow & 7) << 3);
      *reinterpret_cast<uint2*>(&PS[idx]) = st;
    }

    // ---- O += P V (single fp16 MFMA per frag) ----
    __builtin_amdgcn_s_setprio(1);
    #pragma unroll
    for (int s = 0; s < 2; ++s) {
      int arow = w * 16 + lan15;
      int aidx = (arow * 64 + s * 32 + 8 * lgrp) ^ ((arow & 7) << 3);
      f16x8 pa = *reinterpret_cast<const f16x8*>(&PS[aidx]);
      #pragma unroll
      for (int dt = 0; dt < 4; ++dt) {
        int brow = dt * 16 + lan15;
        int bidx = (brow * 64 + s * 32 + 8 * lgrp) ^ ((brow & 7) << 3);
        f16x8 vb = *reinterpret_cast<const f16x8*>(&VTS[bidx]);
        o[dt] = MFMA16F(pa, vb, o[dt]);
      }
    }
    __builtin_amdgcn_s_setprio(0);
  };

  DECL_TILE(A); DECL_TILE(B);
  LOAD_TILE(A, 0);
  for (int kt = 0; kt < SEQ / 64; kt += 2) {
    __syncthreads();                 // prior readers of LDS done
    WRITE_TILE(A);
    LOAD_TILE(B, kt + 1);            // prefetch under compute(A)
    __syncthreads();
    compute_tile(gv_A);
    __syncthreads();
    WRITE_TILE(B);
    if (kt + 2 < SEQ / 64) LOAD_TILE(A, kt + 2);
    __syncthreads();
    compute_tile(gv_B);
  }

  // ---- epilogue: normalize, trunc-split, write AO hi/lo ----
  #pragma unroll
  for (int r = 0; r < 4; ++r) {
    float inv = 1.f / lrun[r];
    int qrow_g = qt * 64 + w * 16 + 4 * lgrp + r;
    size_t base = (size_t)(b * SEQ + qrow_g) * DIM + h * HD;
    #pragma unroll
    for (int dt = 0; dt < 4; ++dt) {
      float v = o[dt][r] * inv;
      unsigned uv = fbits(v);
      AOh[base + dt * 16 + lan15] = (u16)(uv >> 16);
      float lo = v - bitsf(uv & 0xFFFF0000u);
      AOl[base + dt * 16 + lan15] = (u16)(fbits(lo) >> 16);
    }
  }
}

// ---------------------------------------------------------------------------
// Kernel 4: out = AO @ Wo + bo, split-bf16 MFMA, reg-prefetch pipeline.
// ---------------------------------------------------------------------------
#define ODECL(S) bf16x8 rah_##S[2], ral_##S[2], rbh_##S, rbl_##S;
#define OLOAD(S, kb) do { \
  _Pragma("unroll") for (int cc = 0; cc < 2; ++cc) { \
    int c = t + cc * 256; int mf = c >> 6, lg = (c >> 4) & 3, rr = c & 15; \
    size_t ga = (size_t)(row0 + mf * 16 + rr) * DIM + (kb) + lg * 8; \
    rah_##S[cc] = *(const bf16x8*)&ah[ga]; \
    ral_##S[cc] = *(const bf16x8*)&al[ga]; } \
  { int c = t; int nf = c >> 6, lg = (c >> 4) & 3, rr = c & 15; \
    size_t gb = (size_t)(col0 + nf * 16 + rr) * DIM + (kb) + lg * 8; \
    rbh_##S = *(const bf16x8*)&bth[gb]; \
    rbl_##S = *(const bf16x8*)&btl[gb]; } } while (0)
#define OWRITE(S) do { \
  _Pragma("unroll") for (int cc = 0; cc < 2; ++cc) { int c = t + cc * 256; \
    *(bf16x8*)&AH[c * 8] = rah_##S[cc]; *(bf16x8*)&AL[c * 8] = ral_##S[cc]; } \
  *(bf16x8*)&BH[t * 8] = rbh_##S; *(bf16x8*)&BL[t * 8] = rbl_##S; } while (0)

__global__ __launch_bounds__(256) void outproj_mfma(
    const u16* __restrict__ ah, const u16* __restrict__ al,
    const u16* __restrict__ bth, const u16* __restrict__ btl,
    const float* __restrict__ bo, float* __restrict__ out)
{
  __shared__ u16 AH[4096], AL[4096], BH[2048], BL[2048];
  const int t = threadIdx.x;
  const int w = t >> 6, l = t & 63;
  const int lan15 = l & 15, lgrp = l >> 4;
  const int row0 = blockIdx.y * 128, col0 = blockIdx.x * 64;
  const int wrf = (w >> 1) * 4, wcf = (w & 1) * 2;

  f32x4 acc[4][2];
  #pragma unroll
  for (int i = 0; i < 4; ++i)
    #pragma unroll
    for (int j = 0; j < 2; ++j) acc[i][j] = (f32x4){0.f, 0.f, 0.f, 0.f};

  auto ocompute = [&]() {
    bf16x8 ah4[4], al4[4];
    #pragma unroll
    for (int mi = 0; mi < 4; ++mi) {
      ah4[mi] = *reinterpret_cast<const bf16x8*>(&AH[((wrf + mi) * 64 + l) * 8]);
      al4[mi] = *reinterpret_cast<const bf16x8*>(&AL[((wrf + mi) * 64 + l) * 8]);
    }
    __builtin_amdgcn_s_setprio(1);
    #pragma unroll
    for (int ni = 0; ni < 2; ++ni) {
      bf16x8 bh = *reinterpret_cast<const bf16x8*>(&BH[((wcf + ni) * 64 + l) * 8]);
      bf16x8 bl = *reinterpret_cast<const bf16x8*>(&BL[((wcf + ni) * 64 + l) * 8]);
      #pragma unroll
      for (int mi = 0; mi < 4; ++mi) {
        acc[mi][ni] = MFMA16(ah4[mi], bh, acc[mi][ni]);
        acc[mi][ni] = MFMA16(ah4[mi], bl, acc[mi][ni]);
        acc[mi][ni] = MFMA16(al4[mi], bh, acc[mi][ni]);
      }
    }
    __builtin_amdgcn_s_setprio(0);
  };

  ODECL(A); ODECL(B);
  OLOAD(A, 0);
  for (int kb = 0; kb < DIM; kb += 64) {
    __syncthreads();
    OWRITE(A);
    OLOAD(B, kb + 32);
    __syncthreads();
    ocompute();
    __syncthreads();
    OWRITE(B);
    if (kb + 64 < DIM) OLOAD(A, kb + 64);
    __syncthreads();
    ocompute();
  }

  const int wrr = (w >> 1) * 64, wcc = (w & 1) * 32;
  #pragma unroll
  for (int mi = 0; mi < 4; ++mi) {
    #pragma unroll
    for (int reg = 0; reg < 4; ++reg) {
      int row = row0 + wrr + mi * 16 + lgrp * 4 + reg;
      #pragma unroll
      for (int ni = 0; ni < 2; ++ni) {
        int col = col0 + wcc + ni * 16 + lan15;
        out[(size_t)row * DIM + col] = acc[mi][ni][reg] + bo[col];
      }
    }
  }
}

// ---------------------------------------------------------------------------
extern "C" void kernel_launch(void* const* d_in, const int* in_sizes, int n_in,
                              void* d_out, int out_size, void* d_ws, size_t ws_size,
                              hipStream_t stream) {
  const float* x    = (const float*)d_in[0];
  const float* cov  = (const float*)d_in[1];
  const float* Wqkv = (const float*)d_in[2];
  const float* Wo   = (const float*)d_in[3];
  const float* bo   = (const float*)d_in[4];
  const float* Wg1  = (const float*)d_in[5];
  const float* bg1  = (const float*)d_in[6];
  const float* Wg2  = (const float*)d_in[7];
  const float* bg2  = (const float*)d_in[8];
  float* out = (float*)d_out;

  const size_t NX   = (size_t)BN_TOT * DIM;
  const size_t NWQ  = (size_t)DIM * 3 * DIM;
  const size_t NWO  = (size_t)DIM * DIM;
  const size_t NHEA = (size_t)BATCH * HEADS * SEQ * HD;

  float* g   = (float*)d_ws;
  u16* base  = (u16*)(g + (size_t)BATCH * HEADS * SEQ);
  u16* xh    = base;          u16* xl   = xh + NX;
  u16* wth   = xl + NX;       u16* wtl  = wth + NWQ;
  u16* woth  = wtl + NWQ;     u16* wotl = woth + NWO;
  u16* Qh    = wotl + NWO;    u16* Ql   = Qh + NHEA;
  u16* Kh    = Ql + NHEA;     u16* Kl   = Kh + NHEA;
  u16* V16   = Kl + NHEA;
  u16* AOh   = V16 + NHEA;    u16* AOl  = AOh + NX;

  split_kernel<<<(int)(NX / 1024), 256, 0, stream>>>(x, xh, xl, (int)(NX / 4));
  transpose_split<<<dim3(3 * DIM / 64, DIM / 64), 256, 0, stream>>>(
      Wqkv, wth, wtl, DIM, 3 * DIM);
  transpose_split<<<dim3(DIM / 64, DIM / 64), 256, 0, stream>>>(
      Wo, woth, wotl, DIM, DIM);
  gate_kernel<<<BN_TOT / 256, 256, 0, stream>>>(cov, Wg1, bg1, Wg2, bg2, g);
  qkv_mfma<<<dim3(3 * DIM / 128, BN_TOT / 128), 256, 0, stream>>>(
      xh, xl, wth, wtl, Qh, Ql, Kh, Kl, V16);
  attn_mfma<<<SEQ / 64 * BATCH * HEADS, 256, 0, stream>>>(
      Qh, Ql, Kh, Kl, V16, g, AOh, AOl);
  outproj_mfma<<<dim3(DIM / 64, BN_TOT / 128), 256, 0, stream>>>(
      AOh, AOl, woth, wotl, bo, out);
}

// Round 7
// 308.345 us; speedup vs baseline: 5.0013x; 1.0526x over previous
//
#include <hip/hip_runtime.h>
#include <math.h>

#define DIM 768
#define HEADS 12
#define HD 64
#define GATE_HID 192
#define BATCH 2
#define SEQ 2048
#define BN_TOT (BATCH*SEQ)          // 4096
#define ATT_SCALE 0.125f            // 64^-0.5
#define SCL2E 0.180336879f          // ATT_SCALE * log2(e)

typedef unsigned short u16;
typedef __attribute__((ext_vector_type(8))) short bf16x8;
typedef __attribute__((ext_vector_type(8))) _Float16 f16x8;
typedef __attribute__((ext_vector_type(2))) __fp16 fp16v2;
typedef __attribute__((ext_vector_type(4))) float f32x4;

#define MFMA16(a, b, c)  __builtin_amdgcn_mfma_f32_16x16x32_bf16(a, b, c, 0, 0, 0)
#define MFMA16F(a, b, c) __builtin_amdgcn_mfma_f32_16x16x32_f16(a, b, c, 0, 0, 0)

// global -> LDS direct copy, 16B per lane; lds dest = wave-uniform base + lane*16
__device__ __forceinline__ void gld16(const u16* g, u16* lds) {
  __builtin_amdgcn_global_load_lds(
      (const __attribute__((address_space(1))) void*)g,
      (__attribute__((address_space(3))) void*)lds, 16, 0, 0);
}

__device__ inline u16 f2bf(float x) {
  union { float f; unsigned int u; } un; un.f = x;
  unsigned int r = un.u + 0x7FFFu + ((un.u >> 16) & 1u);  // RNE
  return (u16)(r >> 16);
}
__device__ inline float bf2f(u16 h) {
  union { float f; unsigned int u; } un; un.u = ((unsigned int)h) << 16;
  return un.f;
}
__device__ inline unsigned fbits(float x) {
  union { float f; unsigned int u; } un; un.f = x; return un.u;
}
__device__ inline float bitsf(unsigned u) {
  union { float f; unsigned int u; } un; un.u = u; return un.f;
}

// ---------------------------------------------------------------------------
// Prep A: elementwise split fp32 -> bf16 hi/lo.
// ---------------------------------------------------------------------------
__global__ __launch_bounds__(256) void split_kernel(
    const float* __restrict__ src, u16* __restrict__ h, u16* __restrict__ l,
    int n4)
{
  int i = blockIdx.x * 256 + threadIdx.x;
  if (i >= n4) return;
  float4 v = reinterpret_cast<const float4*>(src)[i];
  float xs[4] = {v.x, v.y, v.z, v.w};
  ushort4 hv, lv;
  u16 hh;
  hh = f2bf(xs[0]); hv.x = hh; lv.x = f2bf(xs[0] - bf2f(hh));
  hh = f2bf(xs[1]); hv.y = hh; lv.y = f2bf(xs[1] - bf2f(hh));
  hh = f2bf(xs[2]); hv.z = hh; lv.z = f2bf(xs[2] - bf2f(hh));
  hh = f2bf(xs[3]); hv.w = hh; lv.w = f2bf(xs[3] - bf2f(hh));
  reinterpret_cast<ushort4*>(h)[i] = hv;
  reinterpret_cast<ushort4*>(l)[i] = lv;
}

// ---------------------------------------------------------------------------
// Prep B: transpose + split.  src [R][C] fp32 -> th/tl [C][R] bf16 hi/lo.
// ---------------------------------------------------------------------------
__global__ __launch_bounds__(256) void transpose_split(
    const float* __restrict__ src, u16* __restrict__ th, u16* __restrict__ tl,
    int R, int C)
{
  __shared__ float tile[64][65];
  const int t = threadIdx.x;
  const int c = t & 63, r4 = t >> 6;
  const int gr0 = blockIdx.y * 64, gc0 = blockIdx.x * 64;
  #pragma unroll
  for (int i = 0; i < 16; ++i) {
    int row = i * 4 + r4;
    tile[row][c] = src[(size_t)(gr0 + row) * C + gc0 + c];
  }
  __syncthreads();
  #pragma unroll
  for (int i = 0; i < 16; ++i) {
    int rr = i * 4 + r4;
    float v = tile[c][rr];
    u16 hh = f2bf(v);
    size_t o = (size_t)(gc0 + rr) * R + gr0 + c;
    th[o] = hh;
    tl[o] = f2bf(v - bf2f(hh));
  }
}

// ---------------------------------------------------------------------------
// Kernel 1: coverage gate MLP.
// ---------------------------------------------------------------------------
__global__ __launch_bounds__(256) void gate_kernel(
    const float* __restrict__ cov, const float* __restrict__ Wg1,
    const float* __restrict__ bg1, const float* __restrict__ Wg2,
    const float* __restrict__ bg2, float* __restrict__ g)
{
  int idx = blockIdx.x * 256 + threadIdx.x;   // b*SEQ + n
  if (idx >= BN_TOT) return;
  float c = cov[idx];
  float acc[HEADS];
  #pragma unroll
  for (int t = 0; t < HEADS; ++t) acc[t] = bg2[t];
  for (int j = 0; j < GATE_HID; ++j) {
    float hpre = c * Wg1[j] + bg1[j];
    float s = hpre / (1.f + __expf(-hpre));   // silu
    #pragma unroll
    for (int t = 0; t < HEADS; ++t) acc[t] += s * Wg2[j * HEADS + t];
  }
  int b = idx / SEQ, n = idx % SEQ;
  #pragma unroll
  for (int t = 0; t < HEADS; ++t) {
    float val = 1.f / (1.f + __expf(-acc[t]));
    g[(size_t)(b * HEADS + t) * SEQ + n] = val;
  }
}

// ---------------------------------------------------------------------------
// Kernel 2: qkv = x @ Wqkv via split-bf16 MFMA.  global_load_lds staging,
// double-buffered LDS, 1 barrier per 32-K step, loads in flight across a
// full compute phase.  Epilogue: Q/K bf16 hi/lo kappa-d packed; V fp16.
// ---------------------------------------------------------------------------
#define QISSUE(kb, X) do { \
  _Pragma("unroll") for (int cc = 0; cc < 2; ++cc) { \
    int c = t + cc * 256; int mf = c >> 6, lg = (c >> 4) & 3, rr = c & 15; \
    size_t ga = (size_t)(row0 + mf * 16 + rr) * DIM + (kb) + lg * 8; \
    size_t gb = (size_t)(col0 + mf * 16 + rr) * DIM + (kb) + lg * 8; \
    int lo = (w * 64 + cc * 256) * 8; \
    gld16(&xh[ga], &AH##X[lo]); gld16(&xl[ga], &AL##X[lo]); \
    gld16(&bth[gb], &BH##X[lo]); gld16(&btl[gb], &BL##X[lo]); \
  } } while (0)

__global__ __launch_bounds__(256) void qkv_mfma(
    const u16* __restrict__ xh, const u16* __restrict__ xl,
    const u16* __restrict__ bth, const u16* __restrict__ btl,
    u16* __restrict__ Qh, u16* __restrict__ Ql,
    u16* __restrict__ Kh, u16* __restrict__ Kl,
    u16* __restrict__ V16)
{
  __shared__ u16 AH0[4096], AL0[4096], BH0[4096], BL0[4096];
  __shared__ u16 AH1[4096], AL1[4096], BH1[4096], BL1[4096];
  const int t = threadIdx.x;
  const int w = t >> 6, l = t & 63;
  const int lan15 = l & 15, lgrp = l >> 4;
  const int row0 = blockIdx.y * 128, col0 = blockIdx.x * 128;
  const int wrf = (w >> 1) * 4, wcf = (w & 1) * 4;

  f32x4 acc[4][4];
  #pragma unroll
  for (int i = 0; i < 4; ++i)
    #pragma unroll
    for (int j = 0; j < 4; ++j) acc[i][j] = (f32x4){0.f, 0.f, 0.f, 0.f};

  auto qcompute = [&](int buf) {
    const u16* AHc = buf ? AH1 : AH0; const u16* ALc = buf ? AL1 : AL0;
    const u16* BHc = buf ? BH1 : BH0; const u16* BLc = buf ? BL1 : BL0;
    bf16x8 ah4[4], al4[4];
    #pragma unroll
    for (int mi = 0; mi < 4; ++mi) {
      ah4[mi] = *reinterpret_cast<const bf16x8*>(&AHc[((wrf + mi) * 64 + l) * 8]);
      al4[mi] = *reinterpret_cast<const bf16x8*>(&ALc[((wrf + mi) * 64 + l) * 8]);
    }
    __builtin_amdgcn_s_setprio(1);
    #pragma unroll
    for (int ni = 0; ni < 4; ++ni) {
      bf16x8 bh = *reinterpret_cast<const bf16x8*>(&BHc[((wcf + ni) * 64 + l) * 8]);
      bf16x8 bl = *reinterpret_cast<const bf16x8*>(&BLc[((wcf + ni) * 64 + l) * 8]);
      #pragma unroll
      for (int mi = 0; mi < 4; ++mi) {
        acc[mi][ni] = MFMA16(ah4[mi], bh, acc[mi][ni]);
        acc[mi][ni] = MFMA16(ah4[mi], bl, acc[mi][ni]);
        acc[mi][ni] = MFMA16(al4[mi], bh, acc[mi][ni]);
      }
    }
    __builtin_amdgcn_s_setprio(0);
  };

  QISSUE(0, 0);
  for (int kb = 0; kb < DIM; kb += 64) {
    __syncthreads();               // drains buf0 loads (kb); prev readers done
    QISSUE(kb + 32, 1);            // in flight across qcompute(0)
    qcompute(0);
    __syncthreads();               // drains buf1 loads; buf0 readers done
    if (kb + 64 < DIM) QISSUE(kb + 64, 0);
    qcompute(1);
  }

  // epilogue: wave's 64-col block = one head of one section.
  const int gc0 = col0 + (w & 1) * 64;
  const int sec = gc0 / DIM;
  const int hh_ = (gc0 % DIM) / HD;
  const int wrr = (w >> 1) * 64;
  #pragma unroll
  for (int mi = 0; mi < 4; ++mi) {
    #pragma unroll
    for (int reg = 0; reg < 4; ++reg) {
      int row = row0 + wrr + mi * 16 + lgrp * 4 + reg;
      size_t base =
          ((size_t)((row >> 11) * HEADS + hh_) * SEQ + (row & 2047)) * HD;
      float f0 = acc[mi][0][reg], f1 = acc[mi][1][reg];
      float f2 = acc[mi][2][reg], f3 = acc[mi][3][reg];
      if (sec < 2) {
        // kappa-d layout: kappa = lan15*4 + ni -> packed b64 hi/lo stores
        u16* DH = (sec == 0) ? Qh : Kh;
        u16* DL = (sec == 0) ? Ql : Kl;
        unsigned u0 = fbits(f0), u1 = fbits(f1), u2 = fbits(f2), u3 = fbits(f3);
        uint2 hiw, low;
        hiw.x = (u0 >> 16) | (u1 & 0xFFFF0000u);
        hiw.y = (u2 >> 16) | (u3 & 0xFFFF0000u);
        unsigned l0 = fbits(f0 - bitsf(u0 & 0xFFFF0000u));
        unsigned l1 = fbits(f1 - bitsf(u1 & 0xFFFF0000u));
        unsigned l2 = fbits(f2 - bitsf(u2 & 0xFFFF0000u));
        unsigned l3 = fbits(f3 - bitsf(u3 & 0xFFFF0000u));
        low.x = (l0 >> 16) | (l1 & 0xFFFF0000u);
        low.y = (l2 >> 16) | (l3 & 0xFFFF0000u);
        *reinterpret_cast<uint2*>(&DH[base + lan15 * 4]) = hiw;
        *reinterpret_cast<uint2*>(&DL[base + lan15 * 4]) = low;
      } else {
        union { _Float16 h; u16 u; } cv;
        cv.h = (_Float16)f0; V16[base +  0 + lan15] = cv.u;
        cv.h = (_Float16)f1; V16[base + 16 + lan15] = cv.u;
        cv.h = (_Float16)f2; V16[base + 32 + lan15] = cv.u;
        cv.h = (_Float16)f3; V16[base + 48 + lan15] = cv.u;
      }
    }
  }
}

// ---------------------------------------------------------------------------
// Kernel 3: flash attention.  K staged via global_load_lds (double-buffered);
// V reg-staged (transpose) with T14 prefetch; QK^T split-bf16 3-term; exp2
// softmax with per-lane deferred l-sum + exact rescale-skip; PV fp16 MFMA.
// ---------------------------------------------------------------------------
#define KISSUE(kt, X) do { \
  _Pragma("unroll") for (int cc = 0; cc < 2; ++cc) { \
    int c = t + cc * 256; int fi = c >> 6, lg = (c >> 4) & 3, rr = c & 15; \
    size_t gsrc = kvbase + (size_t)((kt) * 64 + (fi >> 1) * 16 + rr) * HD \
                  + (fi & 1) * 32 + lg * 8; \
    int lo = (w * 64 + cc * 256) * 8; \
    gld16(&Kh[gsrc], &KhS##X[lo]); gld16(&Kl[gsrc], &KlS##X[lo]); \
  } } while (0)

#define VLOAD(S, kt) do { \
  _Pragma("unroll") for (int i = 0; i < 4; ++i) { \
    size_t gsrc = kvbase + (size_t)((kt) * 64 + vm + i * 16) * HD + vd0; \
    vv_##S[i] = *(const ushort4*)&V16[gsrc]; } \
  gv_##S.x = gp[(kt) * 64 +  0 + lan15]; \
  gv_##S.y = gp[(kt) * 64 + 16 + lan15]; \
  gv_##S.z = gp[(kt) * 64 + 32 + lan15]; \
  gv_##S.w = gp[(kt) * 64 + 48 + lan15]; } while (0)

#define VROW(S, j, C) do { \
  int row = vd0 + (j); int idx = (row * 64 + vm * 4) ^ ((row & 7) << 3); \
  ushort4 ov; ov.x = vv_##S[0].C; ov.y = vv_##S[1].C; \
  ov.z = vv_##S[2].C; ov.w = vv_##S[3].C; \
  *(ushort4*)&VTS[idx] = ov; } while (0)
#define VWRITE(S) do { \
  VROW(S, 0, x); VROW(S, 1, y); VROW(S, 2, z); VROW(S, 3, w); } while (0)

__global__ __launch_bounds__(256) void attn_mfma(
    const u16* __restrict__ Qh, const u16* __restrict__ Ql,
    const u16* __restrict__ Kh, const u16* __restrict__ Kl,
    const u16* __restrict__ V16, const float* __restrict__ G,
    u16* __restrict__ AOh, u16* __restrict__ AOl)
{
  __shared__ u16 KhS0[4096], KlS0[4096];
  __shared__ u16 KhS1[4096], KlS1[4096];
  __shared__ u16 VTS[4096];   // [d][kappa], fp16, swizzled
  __shared__ u16 PS[4096];    // [q][kappa], fp16, swizzled (wave-private rows)

  const int t     = threadIdx.x;
  const int w     = t >> 6, l = t & 63;
  const int lan15 = l & 15;
  const int lgrp  = l >> 4;
  // XCD swizzle: block n -> xcd = n%8 owns heads 3*(n%8)..+2
  const int n   = blockIdx.x;          // 0..767
  const int s_  = n >> 3;              // 0..95
  const int bh  = (n & 7) * 3 + (s_ >> 5);
  const int qt  = s_ & 31;
  const int b   = bh / HEADS;
  const int h   = bh % HEADS;
  const size_t kvbase = (size_t)bh * SEQ * HD;
  const float* gp = G + (size_t)bh * SEQ;

  // Q fragments (hi/lo, kappa-d layout) straight from global
  bf16x8 qh[2], ql[2];
  {
    size_t qrow = kvbase + (size_t)(qt * 64 + w * 16 + lan15) * HD;
    #pragma unroll
    for (int s = 0; s < 2; ++s) {
      qh[s] = *reinterpret_cast<const bf16x8*>(&Qh[qrow + s * 32 + lgrp * 8]);
      ql[s] = *reinterpret_cast<const bf16x8*>(&Ql[qrow + s * 32 + lgrp * 8]);
    }
  }

  f32x4 o[4];
  #pragma unroll
  for (int dt = 0; dt < 4; ++dt) o[dt] = (f32x4){0.f, 0.f, 0.f, 0.f};
  float mrun[4]  = {-INFINITY, -INFINITY, -INFINITY, -INFINITY};
  float lpart[4] = {0.f, 0.f, 0.f, 0.f};   // per-lane partial l (4 cols each)

  const int vm  = t & 15;           // V-stage: key low bits
  const int vd0 = (t >> 4) * 4;     // V-stage: d base

  auto compute_tile = [&](float4 gvv, int buf) {
    const u16* KhC = buf ? KhS1 : KhS0;
    const u16* KlC = buf ? KlS1 : KlS0;
    float gl[4] = {gvv.x * SCL2E, gvv.y * SCL2E, gvv.z * SCL2E, gvv.w * SCL2E};

    // ---- S = Q K^T (split-bf16, 3 terms) ----
    f32x4 acc[4];
    #pragma unroll
    for (int ct = 0; ct < 4; ++ct) acc[ct] = (f32x4){0.f, 0.f, 0.f, 0.f};
    __builtin_amdgcn_s_setprio(1);
    #pragma unroll
    for (int s = 0; s < 2; ++s) {
      #pragma unroll
      for (int ct = 0; ct < 4; ++ct) {
        int bidx = ((ct * 2 + s) * 64 + l) * 8;
        bf16x8 kbh = *reinterpret_cast<const bf16x8*>(&KhC[bidx]);
        bf16x8 kbl = *reinterpret_cast<const bf16x8*>(&KlC[bidx]);
        acc[ct] = MFMA16(qh[s], kbh, acc[ct]);
        acc[ct] = MFMA16(qh[s], kbl, acc[ct]);
        acc[ct] = MFMA16(ql[s], kbh, acc[ct]);
      }
    }
    __builtin_amdgcn_s_setprio(0);

    // ---- gate + online softmax (exp2 domain) ----
    float sv[4][4];
    #pragma unroll
    for (int ct = 0; ct < 4; ++ct)
      #pragma unroll
      for (int r = 0; r < 4; ++r)
        sv[ct][r] = acc[ct][r] * gl[ct];

    float rmax[4];
    #pragma unroll
    for (int r = 0; r < 4; ++r) {
      rmax[r] = fmaxf(fmaxf(sv[0][r], sv[1][r]), fmaxf(sv[2][r], sv[3][r]));
      #pragma unroll
      for (int off = 1; off < 16; off <<= 1)
        rmax[r] = fmaxf(rmax[r], __shfl_xor(rmax[r], off));
    }
    // exact rescale-skip: when no row's max grew, fsc == 1 exactly
    int need = 0;
    #pragma unroll
    for (int r = 0; r < 4; ++r) need |= (rmax[r] > mrun[r]) ? 1 : 0;
    if (__any(need)) {
      #pragma unroll
      for (int r = 0; r < 4; ++r) {
        float mnew = fmaxf(mrun[r], rmax[r]);
        float fsc  = exp2f(mrun[r] - mnew);
        mrun[r] = mnew;
        lpart[r] *= fsc;
        #pragma unroll
        for (int dt = 0; dt < 4; ++dt) o[dt][r] *= fsc;
      }
    }
    float p[4][4];
    #pragma unroll
    for (int r = 0; r < 4; ++r) {
      float s0 = 0.f;
      #pragma unroll
      for (int ct = 0; ct < 4; ++ct) {
        p[ct][r] = exp2f(sv[ct][r] - mrun[r]);
        s0 += p[ct][r];
      }
      lpart[r] += s0;            // per-lane partial; cross-lane reduce deferred
    }

    // ---- P -> LDS fp16 (kappa layout: kappa = lan15*4 + ct) ----
    #pragma unroll
    for (int r = 0; r < 4; ++r) {
      int prow = w * 16 + 4 * lgrp + r;
      union { fp16v2 h; unsigned u; } cA, cB;
      cA.h = __builtin_amdgcn_cvt_pkrtz(p[0][r], p[1][r]);
      cB.h = __builtin_amdgcn_cvt_pkrtz(p[2][r], p[3][r]);
      uint2 st; st.x = cA.u; st.y = cB.u;
      int idx = (prow * 64 + lan15 * 4) ^ ((prow & 7) << 3);
      *reinterpret_cast<uint2*>(&PS[idx]) = st;
    }

    // ---- O += P V (single fp16 MFMA per frag) ----
    __builtin_amdgcn_s_setprio(1);
    #pragma unroll
    for (int s = 0; s < 2; ++s) {
      int arow = w * 16 + lan15;
      int aidx = (arow * 64 + s * 32 + 8 * lgrp) ^ ((arow & 7) << 3);
      f16x8 pa = *reinterpret_cast<const f16x8*>(&PS[aidx]);
      #pragma unroll
      for (int dt = 0; dt < 4; ++dt) {
        int brow = dt * 16 + lan15;
        int bidx = (brow * 64 + s * 32 + 8 * lgrp) ^ ((brow & 7) << 3);
        f16x8 vb = *reinterpret_cast<const f16x8*>(&VTS[bidx]);
        o[dt] = MFMA16F(pa, vb, o[dt]);
      }
    }
    __builtin_amdgcn_s_setprio(0);
  };

  ushort4 vv_A[4], vv_B[4]; float4 gv_A, gv_B;
  KISSUE(0, 0);
  VLOAD(A, 0);
  for (int kt = 0; kt < SEQ / 64; kt += 2) {
    VLOAD(B, kt + 1);                 // reg prefetch (survives barriers)
    __syncthreads();                  // PV(kt-1) readers done; drains K(kt)
    VWRITE(A);
    __syncthreads();                  // VTS(kt) visible
    KISSUE(kt + 1, 1);                // in flight across compute(kt)
    compute_tile(gv_A, 0);
    if (kt + 2 < SEQ / 64) VLOAD(A, kt + 2);
    __syncthreads();                  // PV(kt) done; drains K(kt+1)
    VWRITE(B);
    __syncthreads();
    if (kt + 2 < SEQ / 64) KISSUE(kt + 2, 0);
    compute_tile(gv_B, 1);
  }

  // ---- epilogue: reduce l across the 16-lane row group, normalize, write ----
  #pragma unroll
  for (int r = 0; r < 4; ++r) {
    float s = lpart[r];
    #pragma unroll
    for (int off = 1; off < 16; off <<= 1) s += __shfl_xor(s, off);
    float inv = 1.f / s;
    int qrow_g = qt * 64 + w * 16 + 4 * lgrp + r;
    size_t base = (size_t)(b * SEQ + qrow_g) * DIM + h * HD;
    #pragma unroll
    for (int dt = 0; dt < 4; ++dt) {
      float v = o[dt][r] * inv;
      unsigned uv = fbits(v);
      AOh[base + dt * 16 + lan15] = (u16)(uv >> 16);
      float lo = v - bitsf(uv & 0xFFFF0000u);
      AOl[base + dt * 16 + lan15] = (u16)(fbits(lo) >> 16);
    }
  }
}

// ---------------------------------------------------------------------------
// Kernel 4: out = AO @ Wo + bo, split-bf16 MFMA, global_load_lds staging.
// ---------------------------------------------------------------------------
#define OISSUE(kb, X) do { \
  _Pragma("unroll") for (int cc = 0; cc < 2; ++cc) { \
    int c = t + cc * 256; int mf = c >> 6, lg = (c >> 4) & 3, rr = c & 15; \
    size_t ga = (size_t)(row0 + mf * 16 + rr) * DIM + (kb) + lg * 8; \
    int lo = (w * 64 + cc * 256) * 8; \
    gld16(&ah[ga], &AH##X[lo]); gld16(&al[ga], &AL##X[lo]); } \
  { int c = t; int nf = c >> 6, lg = (c >> 4) & 3, rr = c & 15; \
    size_t gb = (size_t)(col0 + nf * 16 + rr) * DIM + (kb) + lg * 8; \
    int lo = (w * 64) * 8; \
    gld16(&bth[gb], &BH##X[lo]); gld16(&btl[gb], &BL##X[lo]); } } while (0)

__global__ __launch_bounds__(256) void outproj_mfma(
    const u16* __restrict__ ah, const u16* __restrict__ al,
    const u16* __restrict__ bth, const u16* __restrict__ btl,
    const float* __restrict__ bo, float* __restrict__ out)
{
  __shared__ u16 AH0[4096], AL0[4096], AH1[4096], AL1[4096];
  __shared__ u16 BH0[2048], BL0[2048], BH1[2048], BL1[2048];
  const int t = threadIdx.x;
  const int w = t >> 6, l = t & 63;
  const int lan15 = l & 15, lgrp = l >> 4;
  const int row0 = blockIdx.y * 128, col0 = blockIdx.x * 64;
  const int wrf = (w >> 1) * 4, wcf = (w & 1) * 2;

  f32x4 acc[4][2];
  #pragma unroll
  for (int i = 0; i < 4; ++i)
    #pragma unroll
    for (int j = 0; j < 2; ++j) acc[i][j] = (f32x4){0.f, 0.f, 0.f, 0.f};

  auto ocompute = [&](int buf) {
    const u16* AHc = buf ? AH1 : AH0; const u16* ALc = buf ? AL1 : AL0;
    const u16* BHc = buf ? BH1 : BH0; const u16* BLc = buf ? BL1 : BL0;
    bf16x8 ah4[4], al4[4];
    #pragma unroll
    for (int mi = 0; mi < 4; ++mi) {
      ah4[mi] = *reinterpret_cast<const bf16x8*>(&AHc[((wrf + mi) * 64 + l) * 8]);
      al4[mi] = *reinterpret_cast<const bf16x8*>(&ALc[((wrf + mi) * 64 + l) * 8]);
    }
    __builtin_amdgcn_s_setprio(1);
    #pragma unroll
    for (int ni = 0; ni < 2; ++ni) {
      bf16x8 bh = *reinterpret_cast<const bf16x8*>(&BHc[((wcf + ni) * 64 + l) * 8]);
      bf16x8 bl = *reinterpret_cast<const bf16x8*>(&BLc[((wcf + ni) * 64 + l) * 8]);
      #pragma unroll
      for (int mi = 0; mi < 4; ++mi) {
        acc[mi][ni] = MFMA16(ah4[mi], bh, acc[mi][ni]);
        acc[mi][ni] = MFMA16(ah4[mi], bl, acc[mi][ni]);
        acc[mi][ni] = MFMA16(al4[mi], bh, acc[mi][ni]);
      }
    }
    __builtin_amdgcn_s_setprio(0);
  };

  OISSUE(0, 0);
  for (int kb = 0; kb < DIM; kb += 64) {
    __syncthreads();
    OISSUE(kb + 32, 1);
    ocompute(0);
    __syncthreads();
    if (kb + 64 < DIM) OISSUE(kb + 64, 0);
    ocompute(1);
  }

  const int wrr = (w >> 1) * 64, wcc = (w & 1) * 32;
  #pragma unroll
  for (int mi = 0; mi < 4; ++mi) {
    #pragma unroll
    for (int reg = 0; reg < 4; ++reg) {
      int row = row0 + wrr + mi * 16 + lgrp * 4 + reg;
      #pragma unroll
      for (int ni = 0; ni < 2; ++ni) {
        int col = col0 + wcc + ni * 16 + lan15;
        out[(size_t)row * DIM + col] = acc[mi][ni][reg] + bo[col];
      }
    }
  }
}

// ---------------------------------------------------------------------------
extern "C" void kernel_launch(void* const* d_in, const int* in_sizes, int n_in,
                              void* d_out, int out_size, void* d_ws, size_t ws_size,
                              hipStream_t stream) {
  const float* x    = (const float*)d_in[0];
  const float* cov  = (const float*)d_in[1];
  const float* Wqkv = (const float*)d_in[2];
  const float* Wo   = (const float*)d_in[3];
  const float* bo   = (const float*)d_in[4];
  const float* Wg1  = (const float*)d_in[5];
  const float* bg1  = (const float*)d_in[6];
  const float* Wg2  = (const float*)d_in[7];
  const float* bg2  = (const float*)d_in[8];
  float* out = (float*)d_out;

  const size_t NX   = (size_t)BN_TOT * DIM;
  const size_t NWQ  = (size_t)DIM * 3 * DIM;
  const size_t NWO  = (size_t)DIM * DIM;
  const size_t NHEA = (size_t)BATCH * HEADS * SEQ * HD;

  float* g   = (float*)d_ws;
  u16* base  = (u16*)(g + (size_t)BATCH * HEADS * SEQ);
  u16* xh    = base;          u16* xl   = xh + NX;
  u16* wth   = xl + NX;       u16* wtl  = wth + NWQ;
  u16* woth  = wtl + NWQ;     u16* wotl = woth + NWO;
  u16* Qh    = wotl + NWO;    u16* Ql   = Qh + NHEA;
  u16* Kh    = Ql + NHEA;     u16* Kl   = Kh + NHEA;
  u16* V16   = Kl + NHEA;
  u16* AOh   = V16 + NHEA;    u16* AOl  = AOh + NX;

  split_kernel<<<(int)(NX / 1024), 256, 0, stream>>>(x, xh, xl, (int)(NX / 4));
  transpose_split<<<dim3(3 * DIM / 64, DIM / 64), 256, 0, stream>>>(
      Wqkv, wth, wtl, DIM, 3 * DIM);
  transpose_split<<<dim3(DIM / 64, DIM / 64), 256, 0, stream>>>(
      Wo, woth, wotl, DIM, DIM);
  gate_kernel<<<BN_TOT / 256, 256, 0, stream>>>(cov, Wg1, bg1, Wg2, bg2, g);
  qkv_mfma<<<dim3(3 * DIM / 128, BN_TOT / 128), 256, 0, stream>>>(
      xh, xl, wth, wtl, Qh, Ql, Kh, Kl, V16);
  attn_mfma<<<SEQ / 64 * BATCH * HEADS, 256, 0, stream>>>(
      Qh, Ql, Kh, Kl, V16, g, AOh, AOl);
  outproj_mfma<<<dim3(DIM / 64, BN_TOT / 128), 256, 0, stream>>>(
      AOh, AOl, woth, wotl, bo, out);
}

// Round 8
// 267.996 us; speedup vs baseline: 5.7543x; 1.1506x over previous
//
#include <hip/hip_runtime.h>
#include <math.h>

#define DIM 768
#define HEADS 12
#define HD 64
#define GATE_HID 192
#define BATCH 2
#define SEQ 2048
#define BN_TOT (BATCH*SEQ)          // 4096
#define ATT_SCALE 0.125f            // 64^-0.5
#define SCL2E 0.180336879f          // ATT_SCALE * log2(e)

typedef unsigned short u16;
typedef __attribute__((ext_vector_type(8))) short bf16x8;
typedef __attribute__((ext_vector_type(8))) _Float16 f16x8;
typedef __attribute__((ext_vector_type(2))) __fp16 fp16v2;
typedef __attribute__((ext_vector_type(4))) float f32x4;

#define MFMA16(a, b, c)  __builtin_amdgcn_mfma_f32_16x16x32_bf16(a, b, c, 0, 0, 0)
#define MFMA16F(a, b, c) __builtin_amdgcn_mfma_f32_16x16x32_f16(a, b, c, 0, 0, 0)

// global -> LDS direct copy, 16B per lane; lds dest = wave-uniform base + lane*16
__device__ __forceinline__ void gld16(const u16* g, u16* lds) {
  __builtin_amdgcn_global_load_lds(
      (const __attribute__((address_space(1))) void*)g,
      (__attribute__((address_space(3))) void*)lds, 16, 0, 0);
}

__device__ inline u16 f2bf(float x) {
  union { float f; unsigned int u; } un; un.f = x;
  unsigned int r = un.u + 0x7FFFu + ((un.u >> 16) & 1u);  // RNE
  return (u16)(r >> 16);
}
__device__ inline float bf2f(u16 h) {
  union { float f; unsigned int u; } un; un.u = ((unsigned int)h) << 16;
  return un.f;
}
__device__ inline unsigned fbits(float x) {
  union { float f; unsigned int u; } un; un.f = x; return un.u;
}
__device__ inline float bitsf(unsigned u) {
  union { float f; unsigned int u; } un; un.u = u; return un.f;
}
__device__ inline unsigned cvtpk(float a, float b) {
  union { fp16v2 h; unsigned u; } c;
  c.h = __builtin_amdgcn_cvt_pkrtz(a, b);
  return c.u;
}

// ---------------------------------------------------------------------------
// Prep A: elementwise split fp32 -> bf16 hi/lo.
// ---------------------------------------------------------------------------
__global__ __launch_bounds__(256) void split_kernel(
    const float* __restrict__ src, u16* __restrict__ h, u16* __restrict__ l,
    int n4)
{
  int i = blockIdx.x * 256 + threadIdx.x;
  if (i >= n4) return;
  float4 v = reinterpret_cast<const float4*>(src)[i];
  float xs[4] = {v.x, v.y, v.z, v.w};
  ushort4 hv, lv;
  u16 hh;
  hh = f2bf(xs[0]); hv.x = hh; lv.x = f2bf(xs[0] - bf2f(hh));
  hh = f2bf(xs[1]); hv.y = hh; lv.y = f2bf(xs[1] - bf2f(hh));
  hh = f2bf(xs[2]); hv.z = hh; lv.z = f2bf(xs[2] - bf2f(hh));
  hh = f2bf(xs[3]); hv.w = hh; lv.w = f2bf(xs[3] - bf2f(hh));
  reinterpret_cast<ushort4*>(h)[i] = hv;
  reinterpret_cast<ushort4*>(l)[i] = lv;
}

// ---------------------------------------------------------------------------
// Prep B: transpose + split.  src [R][C] fp32 -> th/tl [C][R] bf16 hi/lo.
// ---------------------------------------------------------------------------
__global__ __launch_bounds__(256) void transpose_split(
    const float* __restrict__ src, u16* __restrict__ th, u16* __restrict__ tl,
    int R, int C)
{
  __shared__ float tile[64][65];
  const int t = threadIdx.x;
  const int c = t & 63, r4 = t >> 6;
  const int gr0 = blockIdx.y * 64, gc0 = blockIdx.x * 64;
  #pragma unroll
  for (int i = 0; i < 16; ++i) {
    int row = i * 4 + r4;
    tile[row][c] = src[(size_t)(gr0 + row) * C + gc0 + c];
  }
  __syncthreads();
  #pragma unroll
  for (int i = 0; i < 16; ++i) {
    int rr = i * 4 + r4;
    float v = tile[c][rr];
    u16 hh = f2bf(v);
    size_t o = (size_t)(gc0 + rr) * R + gr0 + c;
    th[o] = hh;
    tl[o] = f2bf(v - bf2f(hh));
  }
}

// ---------------------------------------------------------------------------
// Kernel 1: coverage gate MLP.  Output pre-scaled by SCL2E (exp2-domain fold).
// ---------------------------------------------------------------------------
__global__ __launch_bounds__(256) void gate_kernel(
    const float* __restrict__ cov, const float* __restrict__ Wg1,
    const float* __restrict__ bg1, const float* __restrict__ Wg2,
    const float* __restrict__ bg2, float* __restrict__ g)
{
  int idx = blockIdx.x * 256 + threadIdx.x;   // b*SEQ + n
  if (idx >= BN_TOT) return;
  float c = cov[idx];
  float acc[HEADS];
  #pragma unroll
  for (int t = 0; t < HEADS; ++t) acc[t] = bg2[t];
  for (int j = 0; j < GATE_HID; ++j) {
    float hpre = c * Wg1[j] + bg1[j];
    float s = hpre / (1.f + __expf(-hpre));   // silu
    #pragma unroll
    for (int t = 0; t < HEADS; ++t) acc[t] += s * Wg2[j * HEADS + t];
  }
  int b = idx / SEQ, n = idx % SEQ;
  #pragma unroll
  for (int t = 0; t < HEADS; ++t) {
    float val = SCL2E / (1.f + __expf(-acc[t]));
    g[(size_t)(b * HEADS + t) * SEQ + n] = val;
  }
}

// ---------------------------------------------------------------------------
// Kernel 2: qkv = x @ Wqkv via split-bf16 MFMA.  global_load_lds staging,
// double-buffered LDS.  Epilogue: Q/K bf16 hi/lo kappa-d packed; V fp16.
// ---------------------------------------------------------------------------
#define QISSUE(kb, X) do { \
  _Pragma("unroll") for (int cc = 0; cc < 2; ++cc) { \
    int c = t + cc * 256; int mf = c >> 6, lg = (c >> 4) & 3, rr = c & 15; \
    size_t ga = (size_t)(row0 + mf * 16 + rr) * DIM + (kb) + lg * 8; \
    size_t gb = (size_t)(col0 + mf * 16 + rr) * DIM + (kb) + lg * 8; \
    int lo = (w * 64 + cc * 256) * 8; \
    gld16(&xh[ga], &AH##X[lo]); gld16(&xl[ga], &AL##X[lo]); \
    gld16(&bth[gb], &BH##X[lo]); gld16(&btl[gb], &BL##X[lo]); \
  } } while (0)

__global__ __launch_bounds__(256) void qkv_mfma(
    const u16* __restrict__ xh, const u16* __restrict__ xl,
    const u16* __restrict__ bth, const u16* __restrict__ btl,
    u16* __restrict__ Qh, u16* __restrict__ Ql,
    u16* __restrict__ Kh, u16* __restrict__ Kl,
    u16* __restrict__ V16)
{
  __shared__ u16 AH0[4096], AL0[4096], BH0[4096], BL0[4096];
  __shared__ u16 AH1[4096], AL1[4096], BH1[4096], BL1[4096];
  const int t = threadIdx.x;
  const int w = t >> 6, l = t & 63;
  const int lan15 = l & 15, lgrp = l >> 4;
  const int row0 = blockIdx.y * 128, col0 = blockIdx.x * 128;
  const int wrf = (w >> 1) * 4, wcf = (w & 1) * 4;

  f32x4 acc[4][4];
  #pragma unroll
  for (int i = 0; i < 4; ++i)
    #pragma unroll
    for (int j = 0; j < 4; ++j) acc[i][j] = (f32x4){0.f, 0.f, 0.f, 0.f};

  auto qcompute = [&](int buf) {
    const u16* AHc = buf ? AH1 : AH0; const u16* ALc = buf ? AL1 : AL0;
    const u16* BHc = buf ? BH1 : BH0; const u16* BLc = buf ? BL1 : BL0;
    bf16x8 ah4[4], al4[4];
    #pragma unroll
    for (int mi = 0; mi < 4; ++mi) {
      ah4[mi] = *reinterpret_cast<const bf16x8*>(&AHc[((wrf + mi) * 64 + l) * 8]);
      al4[mi] = *reinterpret_cast<const bf16x8*>(&ALc[((wrf + mi) * 64 + l) * 8]);
    }
    __builtin_amdgcn_s_setprio(1);
    #pragma unroll
    for (int ni = 0; ni < 4; ++ni) {
      bf16x8 bh = *reinterpret_cast<const bf16x8*>(&BHc[((wcf + ni) * 64 + l) * 8]);
      bf16x8 bl = *reinterpret_cast<const bf16x8*>(&BLc[((wcf + ni) * 64 + l) * 8]);
      #pragma unroll
      for (int mi = 0; mi < 4; ++mi) {
        acc[mi][ni] = MFMA16(ah4[mi], bh, acc[mi][ni]);
        acc[mi][ni] = MFMA16(ah4[mi], bl, acc[mi][ni]);
        acc[mi][ni] = MFMA16(al4[mi], bh, acc[mi][ni]);
      }
    }
    __builtin_amdgcn_s_setprio(0);
  };

  QISSUE(0, 0);
  for (int kb = 0; kb < DIM; kb += 64) {
    __syncthreads();               // drains buf0 loads (kb); prev readers done
    QISSUE(kb + 32, 1);            // in flight across qcompute(0)
    qcompute(0);
    __syncthreads();               // drains buf1 loads; buf0 readers done
    if (kb + 64 < DIM) QISSUE(kb + 64, 0);
    qcompute(1);
  }

  // epilogue: wave's 64-col block = one head of one section.
  const int gc0 = col0 + (w & 1) * 64;
  const int sec = gc0 / DIM;
  const int hh_ = (gc0 % DIM) / HD;
  const int wrr = (w >> 1) * 64;
  #pragma unroll
  for (int mi = 0; mi < 4; ++mi) {
    #pragma unroll
    for (int reg = 0; reg < 4; ++reg) {
      int row = row0 + wrr + mi * 16 + lgrp * 4 + reg;
      size_t base =
          ((size_t)((row >> 11) * HEADS + hh_) * SEQ + (row & 2047)) * HD;
      float f0 = acc[mi][0][reg], f1 = acc[mi][1][reg];
      float f2 = acc[mi][2][reg], f3 = acc[mi][3][reg];
      if (sec < 2) {
        // kappa-d layout: kappa = lan15*4 + ni -> packed b64 hi/lo stores
        u16* DH = (sec == 0) ? Qh : Kh;
        u16* DL = (sec == 0) ? Ql : Kl;
        unsigned u0 = fbits(f0), u1 = fbits(f1), u2 = fbits(f2), u3 = fbits(f3);
        uint2 hiw, low;
        hiw.x = (u0 >> 16) | (u1 & 0xFFFF0000u);
        hiw.y = (u2 >> 16) | (u3 & 0xFFFF0000u);
        unsigned l0 = fbits(f0 - bitsf(u0 & 0xFFFF0000u));
        unsigned l1 = fbits(f1 - bitsf(u1 & 0xFFFF0000u));
        unsigned l2 = fbits(f2 - bitsf(u2 & 0xFFFF0000u));
        unsigned l3 = fbits(f3 - bitsf(u3 & 0xFFFF0000u));
        low.x = (l0 >> 16) | (l1 & 0xFFFF0000u);
        low.y = (l2 >> 16) | (l3 & 0xFFFF0000u);
        *reinterpret_cast<uint2*>(&DH[base + lan15 * 4]) = hiw;
        *reinterpret_cast<uint2*>(&DL[base + lan15 * 4]) = low;
      } else {
        union { _Float16 h; u16 u; } cv;
        cv.h = (_Float16)f0; V16[base +  0 + lan15] = cv.u;
        cv.h = (_Float16)f1; V16[base + 16 + lan15] = cv.u;
        cv.h = (_Float16)f2; V16[base + 32 + lan15] = cv.u;
        cv.h = (_Float16)f3; V16[base + 48 + lan15] = cv.u;
      }
    }
  }
}

// ---------------------------------------------------------------------------
// Kernel 3: flash attention, SWAPPED QK^T (T12): S^T = mfma(K, Q) so each
// lane owns one q-row.  Softmax: 15 in-lane fmax + 2 shfl; single m/l per
// lane; P packed in-register to fp16 B-frag (kappa-matched) -> PV =
// mfma(V^T, P^T) -> O^T.  No P LDS.  K via gld_lds dbuf; V reg-staged.
//   kappa(key: ct,lgrp,r) = (ct>>1)*32 + lgrp*8 + (ct&1)*4 + r
// ---------------------------------------------------------------------------
#define KISSUE(kt, X) do { \
  _Pragma("unroll") for (int cc = 0; cc < 2; ++cc) { \
    int c = t + cc * 256; int fi = c >> 6, lg = (c >> 4) & 3, rr = c & 15; \
    size_t gsrc = kvbase + (size_t)((kt) * 64 + (fi >> 1) * 16 + rr) * HD \
                  + (fi & 1) * 32 + lg * 8; \
    int lo = (w * 64 + cc * 256) * 8; \
    gld16(&Kh[gsrc], &KhS##X[lo]); gld16(&Kl[gsrc], &KlS##X[lo]); \
  } } while (0)

#define VLOAD(S, kt) do { \
  _Pragma("unroll") for (int i = 0; i < 4; ++i) { \
    size_t gsrc = kvbase + (size_t)((kt) * 64 + vkey0 + i) * HD + vd0; \
    vv_##S[i] = *(const ushort4*)&V16[gsrc]; } } while (0)

#define VROW(S, j, C) do { \
  int row = vd0 + (j); int idx = (row * 64 + vkappa0) ^ ((row & 7) << 3); \
  ushort4 ov; ov.x = vv_##S[0].C; ov.y = vv_##S[1].C; \
  ov.z = vv_##S[2].C; ov.w = vv_##S[3].C; \
  *(ushort4*)&VTS[idx] = ov; } while (0)
#define VWRITE(S) do { \
  VROW(S, 0, x); VROW(S, 1, y); VROW(S, 2, z); VROW(S, 3, w); } while (0)

__global__ __launch_bounds__(256) void attn_mfma(
    const u16* __restrict__ Qh, const u16* __restrict__ Ql,
    const u16* __restrict__ Kh, const u16* __restrict__ Kl,
    const u16* __restrict__ V16, const float* __restrict__ G,
    u16* __restrict__ AOh, u16* __restrict__ AOl)
{
  __shared__ u16 KhS0[4096], KlS0[4096];
  __shared__ u16 KhS1[4096], KlS1[4096];
  __shared__ u16 VTS[4096];   // [d][kappa], fp16, swizzled

  const int t     = threadIdx.x;
  const int w     = t >> 6, l = t & 63;
  const int lan15 = l & 15;
  const int lgrp  = l >> 4;
  // XCD swizzle: block n -> xcd = n%8 owns heads 3*(n%8)..+2
  const int n   = blockIdx.x;          // 0..767
  const int s_  = n >> 3;              // 0..95
  const int bh  = (n & 7) * 3 + (s_ >> 5);
  const int qt  = s_ & 31;
  const int b   = bh / HEADS;
  const int h   = bh % HEADS;
  const size_t kvbase = (size_t)bh * SEQ * HD;
  const float* gp = G + (size_t)bh * SEQ;

  // Q fragments (hi/lo, kappa-d layout): B-operand, lane's q-row = lan15
  bf16x8 qh[2], ql[2];
  {
    size_t qrow = kvbase + (size_t)(qt * 64 + w * 16 + lan15) * HD;
    #pragma unroll
    for (int s = 0; s < 2; ++s) {
      qh[s] = *reinterpret_cast<const bf16x8*>(&Qh[qrow + s * 32 + lgrp * 8]);
      ql[s] = *reinterpret_cast<const bf16x8*>(&Ql[qrow + s * 32 + lgrp * 8]);
    }
  }

  f32x4 o[4];      // O^T: o[dt] rows d = dt*16 + lgrp*4 + reg, col q = lan15
  #pragma unroll
  for (int dt = 0; dt < 4; ++dt) o[dt] = (f32x4){0.f, 0.f, 0.f, 0.f};
  float mrun  = -INFINITY;
  float lpart = 0.f;   // per-lane partial over this lane's 16 keys/tile

  // V staging: thread handles 4 consecutive keys -> 4 consecutive kappa
  const int vm      = t & 15;
  const int vd0     = (t >> 4) * 4;
  const int vkey0   = ((vm >> 2) * 16) + ((vm & 3) * 4);
  const int vkappa0 = ((vm >> 3) * 32) + ((vm & 3) * 8) + (((vm >> 2) & 1) * 4);

  auto compute_tile = [&](int kt, int buf) {
    const u16* KhC = buf ? KhS1 : KhS0;
    const u16* KlC = buf ? KlS1 : KlS0;

    // gate (pre-scaled by SCL2E): lane's 16 keys = ct*16 + lgrp*4 + r
    float4 g4[4];
    #pragma unroll
    for (int ct = 0; ct < 4; ++ct)
      g4[ct] = *reinterpret_cast<const float4*>(&gp[kt * 64 + ct * 16 + lgrp * 4]);

    // ---- S^T = K Q^T (split-bf16, 3 terms); A=K, B=Q ----
    f32x4 acc[4];
    #pragma unroll
    for (int ct = 0; ct < 4; ++ct) acc[ct] = (f32x4){0.f, 0.f, 0.f, 0.f};
    __builtin_amdgcn_s_setprio(1);
    #pragma unroll
    for (int s = 0; s < 2; ++s) {
      #pragma unroll
      for (int ct = 0; ct < 4; ++ct) {
        int bidx = ((ct * 2 + s) * 64 + l) * 8;
        bf16x8 kbh = *reinterpret_cast<const bf16x8*>(&KhC[bidx]);
        bf16x8 kbl = *reinterpret_cast<const bf16x8*>(&KlC[bidx]);
        acc[ct] = MFMA16(kbh, qh[s], acc[ct]);
        acc[ct] = MFMA16(kbl, qh[s], acc[ct]);
        acc[ct] = MFMA16(kbh, ql[s], acc[ct]);
      }
    }
    __builtin_amdgcn_s_setprio(0);

    // ---- gate + online softmax (exp2 domain, lane-local row) ----
    float sv[4][4];
    #pragma unroll
    for (int ct = 0; ct < 4; ++ct) {
      sv[ct][0] = acc[ct][0] * g4[ct].x;
      sv[ct][1] = acc[ct][1] * g4[ct].y;
      sv[ct][2] = acc[ct][2] * g4[ct].z;
      sv[ct][3] = acc[ct][3] * g4[ct].w;
    }
    float tmax = sv[0][0];
    #pragma unroll
    for (int ct = 0; ct < 4; ++ct)
      #pragma unroll
      for (int r = 0; r < 4; ++r) tmax = fmaxf(tmax, sv[ct][r]);
    tmax = fmaxf(tmax, __shfl_xor(tmax, 16));
    tmax = fmaxf(tmax, __shfl_xor(tmax, 32));
    // exact rescale-skip: when no row's max grew, fsc == 1 exactly
    if (__any(tmax > mrun)) {
      float mnew = fmaxf(mrun, tmax);
      float fsc  = exp2f(mrun - mnew);
      mrun = mnew;
      lpart *= fsc;
      #pragma unroll
      for (int dt = 0; dt < 4; ++dt) o[dt] *= fsc;
    }
    float p[4][4];
    float s0 = 0.f;
    #pragma unroll
    for (int ct = 0; ct < 4; ++ct)
      #pragma unroll
      for (int r = 0; r < 4; ++r) {
        p[ct][r] = exp2f(sv[ct][r] - mrun);
        s0 += p[ct][r];
      }
    lpart += s0;

    // ---- P -> fp16 B-frags IN REGISTER (kappa-matched, no LDS) ----
    union { uint4 u; f16x8 h; } pb0, pb1;
    pb0.u.x = cvtpk(p[0][0], p[0][1]); pb0.u.y = cvtpk(p[0][2], p[0][3]);
    pb0.u.z = cvtpk(p[1][0], p[1][1]); pb0.u.w = cvtpk(p[1][2], p[1][3]);
    pb1.u.x = cvtpk(p[2][0], p[2][1]); pb1.u.y = cvtpk(p[2][2], p[2][3]);
    pb1.u.z = cvtpk(p[3][0], p[3][1]); pb1.u.w = cvtpk(p[3][2], p[3][3]);

    // ---- O^T += V^T P^T (single fp16 MFMA per frag); A=V^T, B=P^T ----
    __builtin_amdgcn_s_setprio(1);
    #pragma unroll
    for (int s = 0; s < 2; ++s) {
      #pragma unroll
      for (int dt = 0; dt < 4; ++dt) {
        int brow = dt * 16 + lan15;
        int bidx = (brow * 64 + s * 32 + lgrp * 8) ^ ((brow & 7) << 3);
        f16x8 va = *reinterpret_cast<const f16x8*>(&VTS[bidx]);
        o[dt] = MFMA16F(va, s ? pb1.h : pb0.h, o[dt]);
      }
    }
    __builtin_amdgcn_s_setprio(0);
  };

  ushort4 vv_A[4], vv_B[4];
  KISSUE(0, 0);
  VLOAD(A, 0);
  for (int kt = 0; kt < SEQ / 64; kt += 2) {
    VLOAD(B, kt + 1);                 // reg prefetch (survives barriers)
    __syncthreads();                  // PV(kt-1) readers done; drains K(kt)
    VWRITE(A);
    __syncthreads();                  // VTS(kt) visible
    KISSUE(kt + 1, 1);                // in flight across compute(kt)
    compute_tile(kt, 0);
    if (kt + 2 < SEQ / 64) VLOAD(A, kt + 2);
    __syncthreads();                  // PV(kt) done; drains K(kt+1)
    VWRITE(B);
    __syncthreads();
    if (kt + 2 < SEQ / 64) KISSUE(kt + 2, 0);
    compute_tile(kt + 1, 1);
  }

  // ---- epilogue: reduce l across lgrp groups, normalize, packed write ----
  lpart += __shfl_xor(lpart, 16);
  lpart += __shfl_xor(lpart, 32);
  float inv = 1.f / lpart;
  const int qrow = qt * 64 + w * 16 + lan15;
  const size_t base = (size_t)(b * SEQ + qrow) * DIM + h * HD;
  #pragma unroll
  for (int dt = 0; dt < 4; ++dt) {
    float f0 = o[dt][0] * inv, f1 = o[dt][1] * inv;
    float f2 = o[dt][2] * inv, f3 = o[dt][3] * inv;
    unsigned u0 = fbits(f0), u1 = fbits(f1), u2 = fbits(f2), u3 = fbits(f3);
    uint2 hiw, low;
    hiw.x = (u0 >> 16) | (u1 & 0xFFFF0000u);
    hiw.y = (u2 >> 16) | (u3 & 0xFFFF0000u);
    unsigned l0 = fbits(f0 - bitsf(u0 & 0xFFFF0000u));
    unsigned l1 = fbits(f1 - bitsf(u1 & 0xFFFF0000u));
    unsigned l2 = fbits(f2 - bitsf(u2 & 0xFFFF0000u));
    unsigned l3 = fbits(f3 - bitsf(u3 & 0xFFFF0000u));
    low.x = (l0 >> 16) | (l1 & 0xFFFF0000u);
    low.y = (l2 >> 16) | (l3 & 0xFFFF0000u);
    *reinterpret_cast<uint2*>(&AOh[base + dt * 16 + lgrp * 4]) = hiw;
    *reinterpret_cast<uint2*>(&AOl[base + dt * 16 + lgrp * 4]) = low;
  }
}

// ---------------------------------------------------------------------------
// Kernel 4: out = AO @ Wo + bo, split-bf16 MFMA, global_load_lds staging.
// ---------------------------------------------------------------------------
#define OISSUE(kb, X) do { \
  _Pragma("unroll") for (int cc = 0; cc < 2; ++cc) { \
    int c = t + cc * 256; int mf = c >> 6, lg = (c >> 4) & 3, rr = c & 15; \
    size_t ga = (size_t)(row0 + mf * 16 + rr) * DIM + (kb) + lg * 8; \
    int lo = (w * 64 + cc * 256) * 8; \
    gld16(&ah[ga], &AH##X[lo]); gld16(&al[ga], &AL##X[lo]); } \
  { int c = t; int nf = c >> 6, lg = (c >> 4) & 3, rr = c & 15; \
    size_t gb = (size_t)(col0 + nf * 16 + rr) * DIM + (kb) + lg * 8; \
    int lo = (w * 64) * 8; \
    gld16(&bth[gb], &BH##X[lo]); gld16(&btl[gb], &BL##X[lo]); } } while (0)

__global__ __launch_bounds__(256) void outproj_mfma(
    const u16* __restrict__ ah, const u16* __restrict__ al,
    const u16* __restrict__ bth, const u16* __restrict__ btl,
    const float* __restrict__ bo, float* __restrict__ out)
{
  __shared__ u16 AH0[4096], AL0[4096], AH1[4096], AL1[4096];
  __shared__ u16 BH0[2048], BL0[2048], BH1[2048], BL1[2048];
  const int t = threadIdx.x;
  const int w = t >> 6, l = t & 63;
  const int lan15 = l & 15, lgrp = l >> 4;
  const int row0 = blockIdx.y * 128, col0 = blockIdx.x * 64;
  const int wrf = (w >> 1) * 4, wcf = (w & 1) * 2;

  f32x4 acc[4][2];
  #pragma unroll
  for (int i = 0; i < 4; ++i)
    #pragma unroll
    for (int j = 0; j < 2; ++j) acc[i][j] = (f32x4){0.f, 0.f, 0.f, 0.f};

  auto ocompute = [&](int buf) {
    const u16* AHc = buf ? AH1 : AH0; const u16* ALc = buf ? AL1 : AL0;
    const u16* BHc = buf ? BH1 : BH0; const u16* BLc = buf ? BL1 : BL0;
    bf16x8 ah4[4], al4[4];
    #pragma unroll
    for (int mi = 0; mi < 4; ++mi) {
      ah4[mi] = *reinterpret_cast<const bf16x8*>(&AHc[((wrf + mi) * 64 + l) * 8]);
      al4[mi] = *reinterpret_cast<const bf16x8*>(&ALc[((wrf + mi) * 64 + l) * 8]);
    }
    __builtin_amdgcn_s_setprio(1);
    #pragma unroll
    for (int ni = 0; ni < 2; ++ni) {
      bf16x8 bh = *reinterpret_cast<const bf16x8*>(&BHc[((wcf + ni) * 64 + l) * 8]);
      bf16x8 bl = *reinterpret_cast<const bf16x8*>(&BLc[((wcf + ni) * 64 + l) * 8]);
      #pragma unroll
      for (int mi = 0; mi < 4; ++mi) {
        acc[mi][ni] = MFMA16(ah4[mi], bh, acc[mi][ni]);
        acc[mi][ni] = MFMA16(ah4[mi], bl, acc[mi][ni]);
        acc[mi][ni] = MFMA16(al4[mi], bh, acc[mi][ni]);
      }
    }
    __builtin_amdgcn_s_setprio(0);
  };

  OISSUE(0, 0);
  for (int kb = 0; kb < DIM; kb += 64) {
    __syncthreads();
    OISSUE(kb + 32, 1);
    ocompute(0);
    __syncthreads();
    if (kb + 64 < DIM) OISSUE(kb + 64, 0);
    ocompute(1);
  }

  const int wrr = (w >> 1) * 64, wcc = (w & 1) * 32;
  #pragma unroll
  for (int mi = 0; mi < 4; ++mi) {
    #pragma unroll
    for (int reg = 0; reg < 4; ++reg) {
      int row = row0 + wrr + mi * 16 + lgrp * 4 + reg;
      #pragma unroll
      for (int ni = 0; ni < 2; ++ni) {
        int col = col0 + wcc + ni * 16 + lan15;
        out[(size_t)row * DIM + col] = acc[mi][ni][reg] + bo[col];
      }
    }
  }
}

// ---------------------------------------------------------------------------
extern "C" void kernel_launch(void* const* d_in, const int* in_sizes, int n_in,
                              void* d_out, int out_size, void* d_ws, size_t ws_size,
                              hipStream_t stream) {
  const float* x    = (const float*)d_in[0];
  const float* cov  = (const float*)d_in[1];
  const float* Wqkv = (const float*)d_in[2];
  const float* Wo   = (const float*)d_in[3];
  const float* bo   = (const float*)d_in[4];
  const float* Wg1  = (const float*)d_in[5];
  const float* bg1  = (const float*)d_in[6];
  const float* Wg2  = (const float*)d_in[7];
  const float* bg2  = (const float*)d_in[8];
  float* out = (float*)d_out;

  const size_t NX   = (size_t)BN_TOT * DIM;
  const size_t NWQ  = (size_t)DIM * 3 * DIM;
  const size_t NWO  = (size_t)DIM * DIM;
  const size_t NHEA = (size_t)BATCH * HEADS * SEQ * HD;

  float* g   = (float*)d_ws;
  u16* base  = (u16*)(g + (size_t)BATCH * HEADS * SEQ);
  u16* xh    = base;          u16* xl   = xh + NX;
  u16* wth   = xl + NX;       u16* wtl  = wth + NWQ;
  u16* woth  = wtl + NWQ;     u16* wotl = woth + NWO;
  u16* Qh    = wotl + NWO;    u16* Ql   = Qh + NHEA;
  u16* Kh    = Ql + NHEA;     u16* Kl   = Kh + NHEA;
  u16* V16   = Kl + NHEA;
  u16* AOh   = V16 + NHEA;    u16* AOl  = AOh + NX;

  split_kernel<<<(int)(NX / 1024), 256, 0, stream>>>(x, xh, xl, (int)(NX / 4));
  transpose_split<<<dim3(3 * DIM / 64, DIM / 64), 256, 0, stream>>>(
      Wqkv, wth, wtl, DIM, 3 * DIM);
  transpose_split<<<dim3(DIM / 64, DIM / 64), 256, 0, stream>>>(
      Wo, woth, wotl, DIM, DIM);
  gate_kernel<<<BN_TOT / 256, 256, 0, stream>>>(cov, Wg1, bg1, Wg2, bg2, g);
  qkv_mfma<<<dim3(3 * DIM / 128, BN_TOT / 128), 256, 0, stream>>>(
      xh, xl, wth, wtl, Qh, Ql, Kh, Kl, V16);
  attn_mfma<<<SEQ / 64 * BATCH * HEADS, 256, 0, stream>>>(
      Qh, Ql, Kh, Kl, V16, g, AOh, AOl);
  outproj_mfma<<<dim3(DIM / 64, BN_TOT / 128), 256, 0, stream>>>(
      AOh, AOl, woth, wotl, bo, out);
}

// Round 9
// 218.619 us; speedup vs baseline: 7.0539x; 1.2259x over previous
//
#include <hip/hip_runtime.h>
#include <math.h>

#define DIM 768
#define HEADS 12
#define HD 64
#define GATE_HID 192
#define BATCH 2
#define SEQ 2048
#define BN_TOT (BATCH*SEQ)          // 4096
#define ATT_SCALE 0.125f            // 64^-0.5
#define SCL2E 0.180336879f          // ATT_SCALE * log2(e)

typedef unsigned short u16;
typedef __attribute__((ext_vector_type(8))) _Float16 f16x8;
typedef __attribute__((ext_vector_type(2))) __fp16 fp16v2;
typedef __attribute__((ext_vector_type(4))) float f32x4;

#define MFMA16F(a, b, c) __builtin_amdgcn_mfma_f32_16x16x32_f16(a, b, c, 0, 0, 0)

// global -> LDS direct copy, 16B per lane; lds dest = wave-uniform base + lane*16
__device__ __forceinline__ void gld16(const u16* g, u16* lds) {
  __builtin_amdgcn_global_load_lds(
      (const __attribute__((address_space(1))) void*)g,
      (__attribute__((address_space(3))) void*)lds, 16, 0, 0);
}

__device__ inline u16 f2h(float x) {            // RNE fp32->fp16
  union { _Float16 h; u16 u; } c; c.h = (_Float16)x; return c.u;
}
__device__ inline float h2f(u16 u) {
  union { _Float16 h; u16 u; } c; c.u = u; return (float)c.h;
}
__device__ inline unsigned cvtpk(float a, float b) {   // RTZ packed
  union { fp16v2 h; unsigned u; } c;
  c.h = __builtin_amdgcn_cvt_pkrtz(a, b);
  return c.u;
}

// ---------------------------------------------------------------------------
// Prep A: elementwise fp32 -> fp16 (RNE).
// ---------------------------------------------------------------------------
__global__ __launch_bounds__(256) void cvt16_kernel(
    const float* __restrict__ src, u16* __restrict__ dst, int n4)
{
  int i = blockIdx.x * 256 + threadIdx.x;
  if (i >= n4) return;
  float4 v = reinterpret_cast<const float4*>(src)[i];
  uint2 o;
  o.x = (unsigned)f2h(v.x) | ((unsigned)f2h(v.y) << 16);
  o.y = (unsigned)f2h(v.z) | ((unsigned)f2h(v.w) << 16);
  reinterpret_cast<uint2*>(dst)[i] = o;
}

// ---------------------------------------------------------------------------
// Prep B: transpose + fp16 hi/lo split.  src [R][C] fp32 -> th/tl [C][R].
// ---------------------------------------------------------------------------
__global__ __launch_bounds__(256) void transpose_split(
    const float* __restrict__ src, u16* __restrict__ th, u16* __restrict__ tl,
    int R, int C)
{
  __shared__ float tile[64][65];
  const int t = threadIdx.x;
  const int c = t & 63, r4 = t >> 6;
  const int gr0 = blockIdx.y * 64, gc0 = blockIdx.x * 64;
  #pragma unroll
  for (int i = 0; i < 16; ++i) {
    int row = i * 4 + r4;
    tile[row][c] = src[(size_t)(gr0 + row) * C + gc0 + c];
  }
  __syncthreads();
  #pragma unroll
  for (int i = 0; i < 16; ++i) {
    int rr = i * 4 + r4;
    float v = tile[c][rr];
    u16 hh = f2h(v);
    size_t o = (size_t)(gc0 + rr) * R + gr0 + c;
    th[o] = hh;
    tl[o] = f2h(v - h2f(hh));
  }
}

// ---------------------------------------------------------------------------
// Kernel 1: coverage gate MLP.  Output pre-scaled by SCL2E (exp2-domain fold).
// ---------------------------------------------------------------------------
__global__ __launch_bounds__(256) void gate_kernel(
    const float* __restrict__ cov, const float* __restrict__ Wg1,
    const float* __restrict__ bg1, const float* __restrict__ Wg2,
    const float* __restrict__ bg2, float* __restrict__ g)
{
  int idx = blockIdx.x * 256 + threadIdx.x;   // b*SEQ + n
  if (idx >= BN_TOT) return;
  float c = cov[idx];
  float acc[HEADS];
  #pragma unroll
  for (int t = 0; t < HEADS; ++t) acc[t] = bg2[t];
  for (int j = 0; j < GATE_HID; ++j) {
    float hpre = c * Wg1[j] + bg1[j];
    float s = hpre / (1.f + __expf(-hpre));   // silu
    #pragma unroll
    for (int t = 0; t < HEADS; ++t) acc[t] += s * Wg2[j * HEADS + t];
  }
  int b = idx / SEQ, n = idx % SEQ;
  #pragma unroll
  for (int t = 0; t < HEADS; ++t) {
    float val = SCL2E / (1.f + __expf(-acc[t]));
    g[(size_t)(b * HEADS + t) * SEQ + n] = val;
  }
}

// ---------------------------------------------------------------------------
// Kernel 2: qkv = x @ Wqkv.  x fp16 single (A), W fp16 hi/lo (B) -> 2-term
// fp16 MFMA.  global_load_lds staging, double-buffered LDS (48KB).
// Epilogue: Q fp16 hi/lo kappa-d; K fp16 single kappa-d; V fp16 real-d.
// ---------------------------------------------------------------------------
#define QISSUE(kb, X) do { \
  _Pragma("unroll") for (int cc = 0; cc < 2; ++cc) { \
    int c = t + cc * 256; int mf = c >> 6, lg = (c >> 4) & 3, rr = c & 15; \
    size_t ga = (size_t)(row0 + mf * 16 + rr) * DIM + (kb) + lg * 8; \
    size_t gb = (size_t)(col0 + mf * 16 + rr) * DIM + (kb) + lg * 8; \
    int lo = (w * 64 + cc * 256) * 8; \
    gld16(&x16[ga], &AS##X[lo]); \
    gld16(&wth[gb], &BH##X[lo]); gld16(&wtl[gb], &BL##X[lo]); \
  } } while (0)

__global__ __launch_bounds__(256) void qkv_mfma(
    const u16* __restrict__ x16,
    const u16* __restrict__ wth, const u16* __restrict__ wtl,
    u16* __restrict__ Qh, u16* __restrict__ Ql,
    u16* __restrict__ K16, u16* __restrict__ V16)
{
  __shared__ u16 AS0[4096], BH0[4096], BL0[4096];
  __shared__ u16 AS1[4096], BH1[4096], BL1[4096];
  const int t = threadIdx.x;
  const int w = t >> 6, l = t & 63;
  const int lan15 = l & 15, lgrp = l >> 4;
  const int row0 = blockIdx.y * 128, col0 = blockIdx.x * 128;
  const int wrf = (w >> 1) * 4, wcf = (w & 1) * 4;

  f32x4 acc[4][4];
  #pragma unroll
  for (int i = 0; i < 4; ++i)
    #pragma unroll
    for (int j = 0; j < 4; ++j) acc[i][j] = (f32x4){0.f, 0.f, 0.f, 0.f};

  auto qcompute = [&](int buf) {
    const u16* ASc = buf ? AS1 : AS0;
    const u16* BHc = buf ? BH1 : BH0; const u16* BLc = buf ? BL1 : BL0;
    f16x8 a4[4];
    #pragma unroll
    for (int mi = 0; mi < 4; ++mi)
      a4[mi] = *reinterpret_cast<const f16x8*>(&ASc[((wrf + mi) * 64 + l) * 8]);
    __builtin_amdgcn_s_setprio(1);
    #pragma unroll
    for (int ni = 0; ni < 4; ++ni) {
      f16x8 bh = *reinterpret_cast<const f16x8*>(&BHc[((wcf + ni) * 64 + l) * 8]);
      f16x8 bl = *reinterpret_cast<const f16x8*>(&BLc[((wcf + ni) * 64 + l) * 8]);
      #pragma unroll
      for (int mi = 0; mi < 4; ++mi) {
        acc[mi][ni] = MFMA16F(a4[mi], bh, acc[mi][ni]);
        acc[mi][ni] = MFMA16F(a4[mi], bl, acc[mi][ni]);
      }
    }
    __builtin_amdgcn_s_setprio(0);
  };

  QISSUE(0, 0);
  for (int kb = 0; kb < DIM; kb += 64) {
    __syncthreads();               // drains buf0 loads (kb); prev readers done
    QISSUE(kb + 32, 1);            // in flight across qcompute(0)
    qcompute(0);
    __syncthreads();               // drains buf1 loads; buf0 readers done
    if (kb + 64 < DIM) QISSUE(kb + 64, 0);
    qcompute(1);
  }

  // epilogue: wave's 64-col block = one head of one section.
  const int gc0 = col0 + (w & 1) * 64;
  const int sec = gc0 / DIM;
  const int hh_ = (gc0 % DIM) / HD;
  const int wrr = (w >> 1) * 64;
  #pragma unroll
  for (int mi = 0; mi < 4; ++mi) {
    #pragma unroll
    for (int reg = 0; reg < 4; ++reg) {
      int row = row0 + wrr + mi * 16 + lgrp * 4 + reg;
      size_t base =
          ((size_t)((row >> 11) * HEADS + hh_) * SEQ + (row & 2047)) * HD;
      float f0 = acc[mi][0][reg], f1 = acc[mi][1][reg];
      float f2 = acc[mi][2][reg], f3 = acc[mi][3][reg];
      if (sec == 0) {
        // Q: fp16 hi/lo, kappa-d layout (kappa = lan15*4 + ni), packed b64
        u16 h0 = f2h(f0), h1 = f2h(f1), h2 = f2h(f2), h3 = f2h(f3);
        uint2 hiw, low;
        hiw.x = (unsigned)h0 | ((unsigned)h1 << 16);
        hiw.y = (unsigned)h2 | ((unsigned)h3 << 16);
        low.x = (unsigned)f2h(f0 - h2f(h0)) | ((unsigned)f2h(f1 - h2f(h1)) << 16);
        low.y = (unsigned)f2h(f2 - h2f(h2)) | ((unsigned)f2h(f3 - h2f(h3)) << 16);
        *reinterpret_cast<uint2*>(&Qh[base + lan15 * 4]) = hiw;
        *reinterpret_cast<uint2*>(&Ql[base + lan15 * 4]) = low;
      } else if (sec == 1) {
        // K: fp16 single, kappa-d layout, packed b64
        uint2 kw;
        kw.x = (unsigned)f2h(f0) | ((unsigned)f2h(f1) << 16);
        kw.y = (unsigned)f2h(f2) | ((unsigned)f2h(f3) << 16);
        *reinterpret_cast<uint2*>(&K16[base + lan15 * 4]) = kw;
      } else {
        // V: fp16 single, real-d layout
        V16[base +  0 + lan15] = f2h(f0);
        V16[base + 16 + lan15] = f2h(f1);
        V16[base + 32 + lan15] = f2h(f2);
        V16[base + 48 + lan15] = f2h(f3);
      }
    }
  }
}

// ---------------------------------------------------------------------------
// Kernel 3: flash attention, swapped QK^T: S^T = mfma(K, Q).  K fp16 single
// (gld_lds dbuf, 16KB); Q fp16 hi/lo (regs, exact) -> 2-term QK.  Lane-local
// softmax (exp2 domain), P in-register fp16 B-frag, PV fp16 MFMA -> O^T.
//   kappa(key: ct,lgrp,r) = (ct>>1)*32 + lgrp*8 + (ct&1)*4 + r
// ---------------------------------------------------------------------------
#define KISSUE(kt, X) do { \
  _Pragma("unroll") for (int cc = 0; cc < 2; ++cc) { \
    int c = t + cc * 256; int fi = c >> 6, lg = (c >> 4) & 3, rr = c & 15; \
    size_t gsrc = kvbase + (size_t)((kt) * 64 + (fi >> 1) * 16 + rr) * HD \
                  + (fi & 1) * 32 + lg * 8; \
    int lo = (w * 64 + cc * 256) * 8; \
    gld16(&K16[gsrc], &KS##X[lo]); \
  } } while (0)

#define VLOAD(S, kt) do { \
  _Pragma("unroll") for (int i = 0; i < 4; ++i) { \
    size_t gsrc = kvbase + (size_t)((kt) * 64 + vkey0 + i) * HD + vd0; \
    vv_##S[i] = *(const ushort4*)&V16[gsrc]; } } while (0)

#define VROW(S, j, C) do { \
  int row = vd0 + (j); int idx = (row * 64 + vkappa0) ^ ((row & 7) << 3); \
  ushort4 ov; ov.x = vv_##S[0].C; ov.y = vv_##S[1].C; \
  ov.z = vv_##S[2].C; ov.w = vv_##S[3].C; \
  *(ushort4*)&VTS[idx] = ov; } while (0)
#define VWRITE(S) do { \
  VROW(S, 0, x); VROW(S, 1, y); VROW(S, 2, z); VROW(S, 3, w); } while (0)

__global__ __launch_bounds__(256) void attn_mfma(
    const u16* __restrict__ Qh, const u16* __restrict__ Ql,
    const u16* __restrict__ K16, const u16* __restrict__ V16,
    const float* __restrict__ G, u16* __restrict__ AO16)
{
  __shared__ u16 KS0[4096], KS1[4096];
  __shared__ u16 VTS[4096];   // [d][kappa], fp16, swizzled

  const int t     = threadIdx.x;
  const int w     = t >> 6, l = t & 63;
  const int lan15 = l & 15;
  const int lgrp  = l >> 4;
  // XCD swizzle: block n -> xcd = n%8 owns heads 3*(n%8)..+2
  const int n   = blockIdx.x;          // 0..767
  const int s_  = n >> 3;              // 0..95
  const int bh  = (n & 7) * 3 + (s_ >> 5);
  const int qt  = s_ & 31;
  const int b   = bh / HEADS;
  const int h   = bh % HEADS;
  const size_t kvbase = (size_t)bh * SEQ * HD;
  const float* gp = G + (size_t)bh * SEQ;

  // Q fragments (fp16 hi/lo, kappa-d layout): B-operand, lane's q-row = lan15
  f16x8 qh[2], ql[2];
  {
    size_t qrow = kvbase + (size_t)(qt * 64 + w * 16 + lan15) * HD;
    #pragma unroll
    for (int s = 0; s < 2; ++s) {
      qh[s] = *reinterpret_cast<const f16x8*>(&Qh[qrow + s * 32 + lgrp * 8]);
      ql[s] = *reinterpret_cast<const f16x8*>(&Ql[qrow + s * 32 + lgrp * 8]);
    }
  }

  f32x4 o[4];      // O^T: o[dt] rows d = dt*16 + lgrp*4 + reg, col q = lan15
  #pragma unroll
  for (int dt = 0; dt < 4; ++dt) o[dt] = (f32x4){0.f, 0.f, 0.f, 0.f};
  float mrun  = -INFINITY;
  float lpart = 0.f;   // per-lane partial over this lane's 16 keys/tile

  // V staging: thread handles 4 consecutive keys -> 4 consecutive kappa
  const int vm      = t & 15;
  const int vd0     = (t >> 4) * 4;
  const int vkey0   = ((vm >> 2) * 16) + ((vm & 3) * 4);
  const int vkappa0 = ((vm >> 3) * 32) + ((vm & 3) * 8) + (((vm >> 2) & 1) * 4);

  auto compute_tile = [&](int kt, int buf) {
    const u16* KC = buf ? KS1 : KS0;

    // gate (pre-scaled by SCL2E): lane's 16 keys = ct*16 + lgrp*4 + r
    float4 g4[4];
    #pragma unroll
    for (int ct = 0; ct < 4; ++ct)
      g4[ct] = *reinterpret_cast<const float4*>(&gp[kt * 64 + ct * 16 + lgrp * 4]);

    // ---- S^T = K Q^T (fp16 2-term: Q exact via hi+lo); A=K, B=Q ----
    f32x4 acc[4];
    #pragma unroll
    for (int ct = 0; ct < 4; ++ct) acc[ct] = (f32x4){0.f, 0.f, 0.f, 0.f};
    __builtin_amdgcn_s_setprio(1);
    #pragma unroll
    for (int s = 0; s < 2; ++s) {
      #pragma unroll
      for (int ct = 0; ct < 4; ++ct) {
        int aidx = ((ct * 2 + s) * 64 + l) * 8;
        f16x8 ka = *reinterpret_cast<const f16x8*>(&KC[aidx]);
        acc[ct] = MFMA16F(ka, qh[s], acc[ct]);
        acc[ct] = MFMA16F(ka, ql[s], acc[ct]);
      }
    }
    __builtin_amdgcn_s_setprio(0);

    // ---- gate + online softmax (exp2 domain, lane-local row) ----
    float sv[4][4];
    #pragma unroll
    for (int ct = 0; ct < 4; ++ct) {
      sv[ct][0] = acc[ct][0] * g4[ct].x;
      sv[ct][1] = acc[ct][1] * g4[ct].y;
      sv[ct][2] = acc[ct][2] * g4[ct].z;
      sv[ct][3] = acc[ct][3] * g4[ct].w;
    }
    float tmax = sv[0][0];
    #pragma unroll
    for (int ct = 0; ct < 4; ++ct)
      #pragma unroll
      for (int r = 0; r < 4; ++r) tmax = fmaxf(tmax, sv[ct][r]);
    tmax = fmaxf(tmax, __shfl_xor(tmax, 16));
    tmax = fmaxf(tmax, __shfl_xor(tmax, 32));
    // exact rescale-skip: when no row's max grew, fsc == 1 exactly
    if (__any(tmax > mrun)) {
      float mnew = fmaxf(mrun, tmax);
      float fsc  = exp2f(mrun - mnew);
      mrun = mnew;
      lpart *= fsc;
      #pragma unroll
      for (int dt = 0; dt < 4; ++dt) o[dt] *= fsc;
    }
    float p[4][4];
    float s0 = 0.f;
    #pragma unroll
    for (int ct = 0; ct < 4; ++ct)
      #pragma unroll
      for (int r = 0; r < 4; ++r) {
        p[ct][r] = exp2f(sv[ct][r] - mrun);
        s0 += p[ct][r];
      }
    lpart += s0;

    // ---- P -> fp16 B-frags IN REGISTER (kappa-matched, no LDS) ----
    union { uint4 u; f16x8 h; } pb0, pb1;
    pb0.u.x = cvtpk(p[0][0], p[0][1]); pb0.u.y = cvtpk(p[0][2], p[0][3]);
    pb0.u.z = cvtpk(p[1][0], p[1][1]); pb0.u.w = cvtpk(p[1][2], p[1][3]);
    pb1.u.x = cvtpk(p[2][0], p[2][1]); pb1.u.y = cvtpk(p[2][2], p[2][3]);
    pb1.u.z = cvtpk(p[3][0], p[3][1]); pb1.u.w = cvtpk(p[3][2], p[3][3]);

    // ---- O^T += V^T P^T (single fp16 MFMA per frag); A=V^T, B=P^T ----
    __builtin_amdgcn_s_setprio(1);
    #pragma unroll
    for (int s = 0; s < 2; ++s) {
      #pragma unroll
      for (int dt = 0; dt < 4; ++dt) {
        int brow = dt * 16 + lan15;
        int bidx = (brow * 64 + s * 32 + lgrp * 8) ^ ((brow & 7) << 3);
        f16x8 va = *reinterpret_cast<const f16x8*>(&VTS[bidx]);
        o[dt] = MFMA16F(va, s ? pb1.h : pb0.h, o[dt]);
      }
    }
    __builtin_amdgcn_s_setprio(0);
  };

  ushort4 vv_A[4], vv_B[4];
  KISSUE(0, 0);
  VLOAD(A, 0);
  for (int kt = 0; kt < SEQ / 64; kt += 2) {
    VLOAD(B, kt + 1);                 // reg prefetch (survives barriers)
    __syncthreads();                  // PV(kt-1) readers done; drains K(kt)
    VWRITE(A);
    __syncthreads();                  // VTS(kt) visible
    KISSUE(kt + 1, 1);                // in flight across compute(kt)
    compute_tile(kt, 0);
    if (kt + 2 < SEQ / 64) VLOAD(A, kt + 2);
    __syncthreads();                  // PV(kt) done; drains K(kt+1)
    VWRITE(B);
    __syncthreads();
    if (kt + 2 < SEQ / 64) KISSUE(kt + 2, 0);
    compute_tile(kt + 1, 1);
  }

  // ---- epilogue: reduce l, normalize, packed fp16 write (RNE) ----
  lpart += __shfl_xor(lpart, 16);
  lpart += __shfl_xor(lpart, 32);
  float inv = 1.f / lpart;
  const int qrow = qt * 64 + w * 16 + lan15;
  const size_t base = (size_t)(b * SEQ + qrow) * DIM + h * HD;
  #pragma unroll
  for (int dt = 0; dt < 4; ++dt) {
    float f0 = o[dt][0] * inv, f1 = o[dt][1] * inv;
    float f2 = o[dt][2] * inv, f3 = o[dt][3] * inv;
    uint2 ow;
    ow.x = (unsigned)f2h(f0) | ((unsigned)f2h(f1) << 16);
    ow.y = (unsigned)f2h(f2) | ((unsigned)f2h(f3) << 16);
    *reinterpret_cast<uint2*>(&AO16[base + dt * 16 + lgrp * 4]) = ow;
  }
}

// ---------------------------------------------------------------------------
// Kernel 4: out = AO @ Wo + bo.  AO fp16 single (A), Wo fp16 hi/lo (B),
// 2-term fp16 MFMA, global_load_lds staging (32KB dbuf).
// ---------------------------------------------------------------------------
#define OISSUE(kb, X) do { \
  _Pragma("unroll") for (int cc = 0; cc < 2; ++cc) { \
    int c = t + cc * 256; int mf = c >> 6, lg = (c >> 4) & 3, rr = c & 15; \
    size_t ga = (size_t)(row0 + mf * 16 + rr) * DIM + (kb) + lg * 8; \
    int lo = (w * 64 + cc * 256) * 8; \
    gld16(&a16[ga], &AS##X[lo]); } \
  { int c = t; int nf = c >> 6, lg = (c >> 4) & 3, rr = c & 15; \
    size_t gb = (size_t)(col0 + nf * 16 + rr) * DIM + (kb) + lg * 8; \
    int lo = (w * 64) * 8; \
    gld16(&bth[gb], &BH##X[lo]); gld16(&btl[gb], &BL##X[lo]); } } while (0)

__global__ __launch_bounds__(256) void outproj_mfma(
    const u16* __restrict__ a16,
    const u16* __restrict__ bth, const u16* __restrict__ btl,
    const float* __restrict__ bo, float* __restrict__ out)
{
  __shared__ u16 AS0[4096], AS1[4096];
  __shared__ u16 BH0[2048], BL0[2048], BH1[2048], BL1[2048];
  const int t = threadIdx.x;
  const int w = t >> 6, l = t & 63;
  const int lan15 = l & 15, lgrp = l >> 4;
  const int row0 = blockIdx.y * 128, col0 = blockIdx.x * 64;
  const int wrf = (w >> 1) * 4, wcf = (w & 1) * 2;

  f32x4 acc[4][2];
  #pragma unroll
  for (int i = 0; i < 4; ++i)
    #pragma unroll
    for (int j = 0; j < 2; ++j) acc[i][j] = (f32x4){0.f, 0.f, 0.f, 0.f};

  auto ocompute = [&](int buf) {
    const u16* ASc = buf ? AS1 : AS0;
    const u16* BHc = buf ? BH1 : BH0; const u16* BLc = buf ? BL1 : BL0;
    f16x8 a4[4];
    #pragma unroll
    for (int mi = 0; mi < 4; ++mi)
      a4[mi] = *reinterpret_cast<const f16x8*>(&ASc[((wrf + mi) * 64 + l) * 8]);
    __builtin_amdgcn_s_setprio(1);
    #pragma unroll
    for (int ni = 0; ni < 2; ++ni) {
      f16x8 bh = *reinterpret_cast<const f16x8*>(&BHc[((wcf + ni) * 64 + l) * 8]);
      f16x8 bl = *reinterpret_cast<const f16x8*>(&BLc[((wcf + ni) * 64 + l) * 8]);
      #pragma unroll
      for (int mi = 0; mi < 4; ++mi) {
        acc[mi][ni] = MFMA16F(a4[mi], bh, acc[mi][ni]);
        acc[mi][ni] = MFMA16F(a4[mi], bl, acc[mi][ni]);
      }
    }
    __builtin_amdgcn_s_setprio(0);
  };

  OISSUE(0, 0);
  for (int kb = 0; kb < DIM; kb += 64) {
    __syncthreads();
    OISSUE(kb + 32, 1);
    ocompute(0);
    __syncthreads();
    if (kb + 64 < DIM) OISSUE(kb + 64, 0);
    ocompute(1);
  }

  const int wrr = (w >> 1) * 64, wcc = (w & 1) * 32;
  #pragma unroll
  for (int mi = 0; mi < 4; ++mi) {
    #pragma unroll
    for (int reg = 0; reg < 4; ++reg) {
      int row = row0 + wrr + mi * 16 + lgrp * 4 + reg;
      #pragma unroll
      for (int ni = 0; ni < 2; ++ni) {
        int col = col0 + wcc + ni * 16 + lan15;
        out[(size_t)row * DIM + col] = acc[mi][ni][reg] + bo[col];
      }
    }
  }
}

// ---------------------------------------------------------------------------
extern "C" void kernel_launch(void* const* d_in, const int* in_sizes, int n_in,
                              void* d_out, int out_size, void* d_ws, size_t ws_size,
                              hipStream_t stream) {
  const float* x    = (const float*)d_in[0];
  const float* cov  = (const float*)d_in[1];
  const float* Wqkv = (const float*)d_in[2];
  const float* Wo   = (const float*)d_in[3];
  const float* bo   = (const float*)d_in[4];
  const float* Wg1  = (const float*)d_in[5];
  const float* bg1  = (const float*)d_in[6];
  const float* Wg2  = (const float*)d_in[7];
  const float* bg2  = (const float*)d_in[8];
  float* out = (float*)d_out;

  const size_t NX   = (size_t)BN_TOT * DIM;
  const size_t NWQ  = (size_t)DIM * 3 * DIM;
  const size_t NWO  = (size_t)DIM * DIM;
  const size_t NHEA = (size_t)BATCH * HEADS * SEQ * HD;

  float* g   = (float*)d_ws;
  u16* base  = (u16*)(g + (size_t)BATCH * HEADS * SEQ);
  u16* x16   = base;          u16* wth  = x16 + NX;
  u16* wtl   = wth + NWQ;     u16* woth = wtl + NWQ;
  u16* wotl  = woth + NWO;
  u16* Qh    = wotl + NWO;    u16* Ql   = Qh + NHEA;
  u16* K16   = Ql + NHEA;     u16* V16  = K16 + NHEA;
  u16* AO16  = V16 + NHEA;

  cvt16_kernel<<<(int)(NX / 1024), 256, 0, stream>>>(x, x16, (int)(NX / 4));
  transpose_split<<<dim3(3 * DIM / 64, DIM / 64), 256, 0, stream>>>(
      Wqkv, wth, wtl, DIM, 3 * DIM);
  transpose_split<<<dim3(DIM / 64, DIM / 64), 256, 0, stream>>>(
      Wo, woth, wotl, DIM, DIM);
  gate_kernel<<<BN_TOT / 256, 256, 0, stream>>>(cov, Wg1, bg1, Wg2, bg2, g);
  qkv_mfma<<<dim3(3 * DIM / 128, BN_TOT / 128), 256, 0, stream>>>(
      x16, wth, wtl, Qh, Ql, K16, V16);
  attn_mfma<<<SEQ / 64 * BATCH * HEADS, 256, 0, stream>>>(
      Qh, Ql, K16, V16, g, AO16);
  outproj_mfma<<<dim3(DIM / 64, BN_TOT / 128), 256, 0, stream>>>(
      AO16, woth, wotl, bo, out);
}

// Round 10
// 206.149 us; speedup vs baseline: 7.4806x; 1.0605x over previous
//
#include <hip/hip_runtime.h>
#include <math.h>

#define DIM 768
#define HEADS 12
#define HD 64
#define GATE_HID 192
#define BATCH 2
#define SEQ 2048
#define BN_TOT (BATCH*SEQ)          // 4096
#define ATT_SCALE 0.125f            // 64^-0.5
#define SCL2E 0.180336879f          // ATT_SCALE * log2(e)

typedef unsigned short u16;
typedef __attribute__((ext_vector_type(8))) _Float16 f16x8;
typedef __attribute__((ext_vector_type(2))) __fp16 fp16v2;
typedef __attribute__((ext_vector_type(4))) float f32x4;

#define MFMA16F(a, b, c) __builtin_amdgcn_mfma_f32_16x16x32_f16(a, b, c, 0, 0, 0)

// global -> LDS direct copy, 16B per lane; lds dest = wave-uniform base + lane*16
__device__ __forceinline__ void gld16(const u16* g, u16* lds) {
  __builtin_amdgcn_global_load_lds(
      (const __attribute__((address_space(1))) void*)g,
      (__attribute__((address_space(3))) void*)lds, 16, 0, 0);
}

__device__ inline u16 f2h(float x) {            // RNE fp32->fp16
  union { _Float16 h; u16 u; } c; c.h = (_Float16)x; return c.u;
}
__device__ inline float h2f(u16 u) {
  union { _Float16 h; u16 u; } c; c.u = u; return (float)c.h;
}
__device__ inline unsigned cvtpk(float a, float b) {   // RTZ packed
  union { fp16v2 h; unsigned u; } c;
  c.h = __builtin_amdgcn_cvt_pkrtz(a, b);
  return c.u;
}

// ---------------------------------------------------------------------------
// Prep A: elementwise fp32 -> fp16 (RNE).
// ---------------------------------------------------------------------------
__global__ __launch_bounds__(256) void cvt16_kernel(
    const float* __restrict__ src, u16* __restrict__ dst, int n4)
{
  int i = blockIdx.x * 256 + threadIdx.x;
  if (i >= n4) return;
  float4 v = reinterpret_cast<const float4*>(src)[i];
  uint2 o;
  o.x = (unsigned)f2h(v.x) | ((unsigned)f2h(v.y) << 16);
  o.y = (unsigned)f2h(v.z) | ((unsigned)f2h(v.w) << 16);
  reinterpret_cast<uint2*>(dst)[i] = o;
}

// ---------------------------------------------------------------------------
// Prep B: transpose + fp16 hi/lo split.  src [R][C] fp32 -> th/tl [C][R].
// ---------------------------------------------------------------------------
__global__ __launch_bounds__(256) void transpose_split(
    const float* __restrict__ src, u16* __restrict__ th, u16* __restrict__ tl,
    int R, int C)
{
  __shared__ float tile[64][65];
  const int t = threadIdx.x;
  const int c = t & 63, r4 = t >> 6;
  const int gr0 = blockIdx.y * 64, gc0 = blockIdx.x * 64;
  #pragma unroll
  for (int i = 0; i < 16; ++i) {
    int row = i * 4 + r4;
    tile[row][c] = src[(size_t)(gr0 + row) * C + gc0 + c];
  }
  __syncthreads();
  #pragma unroll
  for (int i = 0; i < 16; ++i) {
    int rr = i * 4 + r4;
    float v = tile[c][rr];
    u16 hh = f2h(v);
    size_t o = (size_t)(gc0 + rr) * R + gr0 + c;
    th[o] = hh;
    tl[o] = f2h(v - h2f(hh));
  }
}

// ---------------------------------------------------------------------------
// Kernel 1: coverage gate MLP.  Output pre-scaled by SCL2E (exp2-domain fold).
// ---------------------------------------------------------------------------
__global__ __launch_bounds__(256) void gate_kernel(
    const float* __restrict__ cov, const float* __restrict__ Wg1,
    const float* __restrict__ bg1, const float* __restrict__ Wg2,
    const float* __restrict__ bg2, float* __restrict__ g)
{
  int idx = blockIdx.x * 256 + threadIdx.x;   // b*SEQ + n
  if (idx >= BN_TOT) return;
  float c = cov[idx];
  float acc[HEADS];
  #pragma unroll
  for (int t = 0; t < HEADS; ++t) acc[t] = bg2[t];
  for (int j = 0; j < GATE_HID; ++j) {
    float hpre = c * Wg1[j] + bg1[j];
    float s = hpre / (1.f + __expf(-hpre));   // silu
    #pragma unroll
    for (int t = 0; t < HEADS; ++t) acc[t] += s * Wg2[j * HEADS + t];
  }
  int b = idx / SEQ, n = idx % SEQ;
  #pragma unroll
  for (int t = 0; t < HEADS; ++t) {
    float val = SCL2E / (1.f + __expf(-acc[t]));
    g[(size_t)(b * HEADS + t) * SEQ + n] = val;
  }
}

// ---------------------------------------------------------------------------
// Kernel 2: qkv = x @ Wqkv.  x fp16 single (A), W fp16 hi/lo (B) -> 2-term
// fp16 MFMA.  global_load_lds staging, double-buffered LDS (48KB).
// Epilogue: Q fp16 hi/lo kappa-d; K fp16 single kappa-d;
// V written PRE-TRANSPOSED + PRE-SWIZZLED as flat 8KB tiles:
//   VT[(bh*32+kt)*4096 + ((d*64 + kappa(key)) ^ ((d&7)<<3))] = V[key][d]
//   kappa(key) = (ct>>1)*32 + lgrp*8 + (ct&1)*4 + r,  key = ct*16+lgrp*4+r
// so attn can stage it with global_load_lds into a linear LDS tile (rule #21).
// ---------------------------------------------------------------------------
#define QISSUE(kb, X) do { \
  _Pragma("unroll") for (int cc = 0; cc < 2; ++cc) { \
    int c = t + cc * 256; int mf = c >> 6, lg = (c >> 4) & 3, rr = c & 15; \
    size_t ga = (size_t)(row0 + mf * 16 + rr) * DIM + (kb) + lg * 8; \
    size_t gb = (size_t)(col0 + mf * 16 + rr) * DIM + (kb) + lg * 8; \
    int lo = (w * 64 + cc * 256) * 8; \
    gld16(&x16[ga], &AS##X[lo]); \
    gld16(&wth[gb], &BH##X[lo]); gld16(&wtl[gb], &BL##X[lo]); \
  } } while (0)

__global__ __launch_bounds__(256) void qkv_mfma(
    const u16* __restrict__ x16,
    const u16* __restrict__ wth, const u16* __restrict__ wtl,
    u16* __restrict__ Qh, u16* __restrict__ Ql,
    u16* __restrict__ K16, u16* __restrict__ VT)
{
  __shared__ u16 AS0[4096], BH0[4096], BL0[4096];
  __shared__ u16 AS1[4096], BH1[4096], BL1[4096];
  const int t = threadIdx.x;
  const int w = t >> 6, l = t & 63;
  const int lan15 = l & 15, lgrp = l >> 4;
  const int row0 = blockIdx.y * 128, col0 = blockIdx.x * 128;
  const int wrf = (w >> 1) * 4, wcf = (w & 1) * 4;

  f32x4 acc[4][4];
  #pragma unroll
  for (int i = 0; i < 4; ++i)
    #pragma unroll
    for (int j = 0; j < 4; ++j) acc[i][j] = (f32x4){0.f, 0.f, 0.f, 0.f};

  auto qcompute = [&](int buf) {
    const u16* ASc = buf ? AS1 : AS0;
    const u16* BHc = buf ? BH1 : BH0; const u16* BLc = buf ? BL1 : BL0;
    f16x8 a4[4];
    #pragma unroll
    for (int mi = 0; mi < 4; ++mi)
      a4[mi] = *reinterpret_cast<const f16x8*>(&ASc[((wrf + mi) * 64 + l) * 8]);
    __builtin_amdgcn_s_setprio(1);
    #pragma unroll
    for (int ni = 0; ni < 4; ++ni) {
      f16x8 bh = *reinterpret_cast<const f16x8*>(&BHc[((wcf + ni) * 64 + l) * 8]);
      f16x8 bl = *reinterpret_cast<const f16x8*>(&BLc[((wcf + ni) * 64 + l) * 8]);
      #pragma unroll
      for (int mi = 0; mi < 4; ++mi) {
        acc[mi][ni] = MFMA16F(a4[mi], bh, acc[mi][ni]);
        acc[mi][ni] = MFMA16F(a4[mi], bl, acc[mi][ni]);
      }
    }
    __builtin_amdgcn_s_setprio(0);
  };

  QISSUE(0, 0);
  for (int kb = 0; kb < DIM; kb += 64) {
    __syncthreads();               // drains buf0 loads (kb); prev readers done
    QISSUE(kb + 32, 1);            // in flight across qcompute(0)
    qcompute(0);
    __syncthreads();               // drains buf1 loads; buf0 readers done
    if (kb + 64 < DIM) QISSUE(kb + 64, 0);
    qcompute(1);
  }

  // epilogue: wave's 64-col block = one head of one section.
  const int gc0 = col0 + (w & 1) * 64;
  const int sec = gc0 / DIM;
  const int hh_ = (gc0 % DIM) / HD;
  const int wrr = (w >> 1) * 64;
  #pragma unroll
  for (int mi = 0; mi < 4; ++mi) {
    #pragma unroll
    for (int reg = 0; reg < 4; ++reg) {
      int row = row0 + wrr + mi * 16 + lgrp * 4 + reg;
      size_t base =
          ((size_t)((row >> 11) * HEADS + hh_) * SEQ + (row & 2047)) * HD;
      float f0 = acc[mi][0][reg], f1 = acc[mi][1][reg];
      float f2 = acc[mi][2][reg], f3 = acc[mi][3][reg];
      if (sec == 0) {
        // Q: fp16 hi/lo, kappa-d layout (kappa = lan15*4 + ni), packed b64
        u16 h0 = f2h(f0), h1 = f2h(f1), h2 = f2h(f2), h3 = f2h(f3);
        uint2 hiw, low;
        hiw.x = (unsigned)h0 | ((unsigned)h1 << 16);
        hiw.y = (unsigned)h2 | ((unsigned)h3 << 16);
        low.x = (unsigned)f2h(f0 - h2f(h0)) | ((unsigned)f2h(f1 - h2f(h1)) << 16);
        low.y = (unsigned)f2h(f2 - h2f(h2)) | ((unsigned)f2h(f3 - h2f(h3)) << 16);
        *reinterpret_cast<uint2*>(&Qh[base + lan15 * 4]) = hiw;
        *reinterpret_cast<uint2*>(&Ql[base + lan15 * 4]) = low;
      } else if (sec == 1) {
        // K: fp16 single, kappa-d layout, packed b64
        uint2 kw;
        kw.x = (unsigned)f2h(f0) | ((unsigned)f2h(f1) << 16);
        kw.y = (unsigned)f2h(f2) | ((unsigned)f2h(f3) << 16);
        *reinterpret_cast<uint2*>(&K16[base + lan15 * 4]) = kw;
      } else {
        // V^T pre-swizzled tile store (scattered u16; L2 absorbs)
        int bb  = row >> 11;
        int nn  = row & 2047;
        int kt_ = nn >> 6, key = nn & 63;
        int ct_ = key >> 4, lg2 = (key >> 2) & 3, rr_ = key & 3;
        int kap = (ct_ >> 1) * 32 + lg2 * 8 + (ct_ & 1) * 4 + rr_;
        size_t tb = (size_t)((bb * HEADS + hh_) * 32 + kt_) * 4096;
        float fs[4] = {f0, f1, f2, f3};
        #pragma unroll
        for (int ni = 0; ni < 4; ++ni) {
          int d = ni * 16 + lan15;
          VT[tb + ((d * 64 + kap) ^ ((d & 7) << 3))] = f2h(fs[ni]);
        }
      }
    }
  }
}

// ---------------------------------------------------------------------------
// Kernel 3: flash attention, swapped QK^T: S^T = mfma(K, Q).  K fp16 single
// + pre-swizzled V^T both staged via global_load_lds (double-buffered, 1
// barrier per tile, loads in flight across a full compute phase).  Q fp16
// hi/lo in regs (exact) -> 2-term QK.  Lane-local softmax (exp2 domain),
// P in-register fp16 B-frag, PV fp16 MFMA -> O^T.
// ---------------------------------------------------------------------------
#define AISSUE(kt, X) do { \
  _Pragma("unroll") for (int cc = 0; cc < 2; ++cc) { \
    int c = t + cc * 256; int fi = c >> 6, lg = (c >> 4) & 3, rr = c & 15; \
    size_t gk = kvbase + (size_t)((kt) * 64 + (fi >> 1) * 16 + rr) * HD \
                + (fi & 1) * 32 + lg * 8; \
    int lo = (w * 64 + cc * 256) * 8; \
    gld16(&K16[gk], &KS##X[lo]); \
    gld16(&VT[vtbase + (size_t)(kt) * 4096 + (size_t)c * 8], &VTS##X[lo]); \
  } } while (0)

__global__ __launch_bounds__(256) void attn_mfma(
    const u16* __restrict__ Qh, const u16* __restrict__ Ql,
    const u16* __restrict__ K16, const u16* __restrict__ VT,
    const float* __restrict__ G, u16* __restrict__ AO16)
{
  __shared__ u16 KS0[4096], KS1[4096];
  __shared__ u16 VTS0[4096], VTS1[4096];   // [d][kappa], fp16, swizzled

  const int t     = threadIdx.x;
  const int w     = t >> 6, l = t & 63;
  const int lan15 = l & 15;
  const int lgrp  = l >> 4;
  // XCD swizzle: block n -> xcd = n%8 owns heads 3*(n%8)..+2
  const int n   = blockIdx.x;          // 0..767
  const int s_  = n >> 3;              // 0..95
  const int bh  = (n & 7) * 3 + (s_ >> 5);
  const int qt  = s_ & 31;
  const int b   = bh / HEADS;
  const int h   = bh % HEADS;
  const size_t kvbase = (size_t)bh * SEQ * HD;
  const size_t vtbase = (size_t)bh * 32 * 4096;
  const float* gp = G + (size_t)bh * SEQ;

  // Q fragments (fp16 hi/lo, kappa-d layout): B-operand, lane's q-row = lan15
  f16x8 qh[2], ql[2];
  {
    size_t qrow = kvbase + (size_t)(qt * 64 + w * 16 + lan15) * HD;
    #pragma unroll
    for (int s = 0; s < 2; ++s) {
      qh[s] = *reinterpret_cast<const f16x8*>(&Qh[qrow + s * 32 + lgrp * 8]);
      ql[s] = *reinterpret_cast<const f16x8*>(&Ql[qrow + s * 32 + lgrp * 8]);
    }
  }

  f32x4 o[4];      // O^T: o[dt] rows d = dt*16 + lgrp*4 + reg, col q = lan15
  #pragma unroll
  for (int dt = 0; dt < 4; ++dt) o[dt] = (f32x4){0.f, 0.f, 0.f, 0.f};
  float mrun  = -INFINITY;
  float lpart = 0.f;   // per-lane partial over this lane's 16 keys/tile

  auto compute_tile = [&](int kt, int buf) {
    const u16* KC = buf ? KS1 : KS0;
    const u16* VC = buf ? VTS1 : VTS0;

    // gate (pre-scaled by SCL2E): lane's 16 keys = ct*16 + lgrp*4 + r
    float4 g4[4];
    #pragma unroll
    for (int ct = 0; ct < 4; ++ct)
      g4[ct] = *reinterpret_cast<const float4*>(&gp[kt * 64 + ct * 16 + lgrp * 4]);

    // ---- S^T = K Q^T (fp16 2-term: Q exact via hi+lo); A=K, B=Q ----
    f32x4 acc[4];
    #pragma unroll
    for (int ct = 0; ct < 4; ++ct) acc[ct] = (f32x4){0.f, 0.f, 0.f, 0.f};
    __builtin_amdgcn_s_setprio(1);
    #pragma unroll
    for (int s = 0; s < 2; ++s) {
      #pragma unroll
      for (int ct = 0; ct < 4; ++ct) {
        int aidx = ((ct * 2 + s) * 64 + l) * 8;
        f16x8 ka = *reinterpret_cast<const f16x8*>(&KC[aidx]);
        acc[ct] = MFMA16F(ka, qh[s], acc[ct]);
        acc[ct] = MFMA16F(ka, ql[s], acc[ct]);
      }
    }
    __builtin_amdgcn_s_setprio(0);

    // ---- gate + online softmax (exp2 domain, lane-local row) ----
    float sv[4][4];
    #pragma unroll
    for (int ct = 0; ct < 4; ++ct) {
      sv[ct][0] = acc[ct][0] * g4[ct].x;
      sv[ct][1] = acc[ct][1] * g4[ct].y;
      sv[ct][2] = acc[ct][2] * g4[ct].z;
      sv[ct][3] = acc[ct][3] * g4[ct].w;
    }
    float tmax = sv[0][0];
    #pragma unroll
    for (int ct = 0; ct < 4; ++ct)
      #pragma unroll
      for (int r = 0; r < 4; ++r) tmax = fmaxf(tmax, sv[ct][r]);
    tmax = fmaxf(tmax, __shfl_xor(tmax, 16));
    tmax = fmaxf(tmax, __shfl_xor(tmax, 32));
    // exact rescale-skip: when no row's max grew, fsc == 1 exactly
    if (__any(tmax > mrun)) {
      float mnew = fmaxf(mrun, tmax);
      float fsc  = exp2f(mrun - mnew);
      mrun = mnew;
      lpart *= fsc;
      #pragma unroll
      for (int dt = 0; dt < 4; ++dt) o[dt] *= fsc;
    }
    float p[4][4];
    float s0 = 0.f;
    #pragma unroll
    for (int ct = 0; ct < 4; ++ct)
      #pragma unroll
      for (int r = 0; r < 4; ++r) {
        p[ct][r] = exp2f(sv[ct][r] - mrun);
        s0 += p[ct][r];
      }
    lpart += s0;

    // ---- P -> fp16 B-frags IN REGISTER (kappa-matched, no LDS) ----
    union { uint4 u; f16x8 h; } pb0, pb1;
    pb0.u.x = cvtpk(p[0][0], p[0][1]); pb0.u.y = cvtpk(p[0][2], p[0][3]);
    pb0.u.z = cvtpk(p[1][0], p[1][1]); pb0.u.w = cvtpk(p[1][2], p[1][3]);
    pb1.u.x = cvtpk(p[2][0], p[2][1]); pb1.u.y = cvtpk(p[2][2], p[2][3]);
    pb1.u.z = cvtpk(p[3][0], p[3][1]); pb1.u.w = cvtpk(p[3][2], p[3][3]);

    // ---- O^T += V^T P^T (single fp16 MFMA per frag); A=V^T, B=P^T ----
    __builtin_amdgcn_s_setprio(1);
    #pragma unroll
    for (int s = 0; s < 2; ++s) {
      #pragma unroll
      for (int dt = 0; dt < 4; ++dt) {
        int brow = dt * 16 + lan15;
        int bidx = (brow * 64 + s * 32 + lgrp * 8) ^ ((brow & 7) << 3);
        f16x8 va = *reinterpret_cast<const f16x8*>(&VC[bidx]);
        o[dt] = MFMA16F(va, s ? pb1.h : pb0.h, o[dt]);
      }
    }
    __builtin_amdgcn_s_setprio(0);
  };

  AISSUE(0, 0);
  for (int kt = 0; kt < SEQ / 64; kt += 2) {
    __syncthreads();                  // drains buf0 loads; buf0 readers done
    AISSUE(kt + 1, 1);                // in flight across compute(kt)
    compute_tile(kt, 0);
    __syncthreads();                  // drains buf1 loads; buf1 readers done
    if (kt + 2 < SEQ / 64) AISSUE(kt + 2, 0);
    compute_tile(kt + 1, 1);
  }

  // ---- epilogue: reduce l, normalize, packed fp16 write (RNE) ----
  lpart += __shfl_xor(lpart, 16);
  lpart += __shfl_xor(lpart, 32);
  float inv = 1.f / lpart;
  const int qrow = qt * 64 + w * 16 + lan15;
  const size_t base = (size_t)(b * SEQ + qrow) * DIM + h * HD;
  #pragma unroll
  for (int dt = 0; dt < 4; ++dt) {
    float f0 = o[dt][0] * inv, f1 = o[dt][1] * inv;
    float f2 = o[dt][2] * inv, f3 = o[dt][3] * inv;
    uint2 ow;
    ow.x = (unsigned)f2h(f0) | ((unsigned)f2h(f1) << 16);
    ow.y = (unsigned)f2h(f2) | ((unsigned)f2h(f3) << 16);
    *reinterpret_cast<uint2*>(&AO16[base + dt * 16 + lgrp * 4]) = ow;
  }
}

// ---------------------------------------------------------------------------
// Kernel 4: out = AO @ Wo + bo.  AO fp16 single (A), Wo fp16 hi/lo (B),
// 2-term fp16 MFMA, global_load_lds staging (32KB dbuf).
// ---------------------------------------------------------------------------
#define OISSUE(kb, X) do { \
  _Pragma("unroll") for (int cc = 0; cc < 2; ++cc) { \
    int c = t + cc * 256; int mf = c >> 6, lg = (c >> 4) & 3, rr = c & 15; \
    size_t ga = (size_t)(row0 + mf * 16 + rr) * DIM + (kb) + lg * 8; \
    int lo = (w * 64 + cc * 256) * 8; \
    gld16(&a16[ga], &AS##X[lo]); } \
  { int c = t; int nf = c >> 6, lg = (c >> 4) & 3, rr = c & 15; \
    size_t gb = (size_t)(col0 + nf * 16 + rr) * DIM + (kb) + lg * 8; \
    int lo = (w * 64) * 8; \
    gld16(&bth[gb], &BH##X[lo]); gld16(&btl[gb], &BL##X[lo]); } } while (0)

__global__ __launch_bounds__(256) void outproj_mfma(
    const u16* __restrict__ a16,
    const u16* __restrict__ bth, const u16* __restrict__ btl,
    const float* __restrict__ bo, float* __restrict__ out)
{
  __shared__ u16 AS0[4096], AS1[4096];
  __shared__ u16 BH0[2048], BL0[2048], BH1[2048], BL1[2048];
  const int t = threadIdx.x;
  const int w = t >> 6, l = t & 63;
  const int lan15 = l & 15, lgrp = l >> 4;
  const int row0 = blockIdx.y * 128, col0 = blockIdx.x * 64;
  const int wrf = (w >> 1) * 4, wcf = (w & 1) * 2;

  f32x4 acc[4][2];
  #pragma unroll
  for (int i = 0; i < 4; ++i)
    #pragma unroll
    for (int j = 0; j < 2; ++j) acc[i][j] = (f32x4){0.f, 0.f, 0.f, 0.f};

  auto ocompute = [&](int buf) {
    const u16* ASc = buf ? AS1 : AS0;
    const u16* BHc = buf ? BH1 : BH0; const u16* BLc = buf ? BL1 : BL0;
    f16x8 a4[4];
    #pragma unroll
    for (int mi = 0; mi < 4; ++mi)
      a4[mi] = *reinterpret_cast<const f16x8*>(&ASc[((wrf + mi) * 64 + l) * 8]);
    __builtin_amdgcn_s_setprio(1);
    #pragma unroll
    for (int ni = 0; ni < 2; ++ni) {
      f16x8 bh = *reinterpret_cast<const f16x8*>(&BHc[((wcf + ni) * 64 + l) * 8]);
      f16x8 bl = *reinterpret_cast<const f16x8*>(&BLc[((wcf + ni) * 64 + l) * 8]);
      #pragma unroll
      for (int mi = 0; mi < 4; ++mi) {
        acc[mi][ni] = MFMA16F(a4[mi], bh, acc[mi][ni]);
        acc[mi][ni] = MFMA16F(a4[mi], bl, acc[mi][ni]);
      }
    }
    __builtin_amdgcn_s_setprio(0);
  };

  OISSUE(0, 0);
  for (int kb = 0; kb < DIM; kb += 64) {
    __syncthreads();
    OISSUE(kb + 32, 1);
    ocompute(0);
    __syncthreads();
    if (kb + 64 < DIM) OISSUE(kb + 64, 0);
    ocompute(1);
  }

  const int wrr = (w >> 1) * 64, wcc = (w & 1) * 32;
  #pragma unroll
  for (int mi = 0; mi < 4; ++mi) {
    #pragma unroll
    for (int reg = 0; reg < 4; ++reg) {
      int row = row0 + wrr + mi * 16 + lgrp * 4 + reg;
      #pragma unroll
      for (int ni = 0; ni < 2; ++ni) {
        int col = col0 + wcc + ni * 16 + lan15;
        out[(size_t)row * DIM + col] = acc[mi][ni][reg] + bo[col];
      }
    }
  }
}

// ---------------------------------------------------------------------------
extern "C" void kernel_launch(void* const* d_in, const int* in_sizes, int n_in,
                              void* d_out, int out_size, void* d_ws, size_t ws_size,
                              hipStream_t stream) {
  const float* x    = (const float*)d_in[0];
  const float* cov  = (const float*)d_in[1];
  const float* Wqkv = (const float*)d_in[2];
  const float* Wo   = (const float*)d_in[3];
  const float* bo   = (const float*)d_in[4];
  const float* Wg1  = (const float*)d_in[5];
  const float* bg1  = (const float*)d_in[6];
  const float* Wg2  = (const float*)d_in[7];
  const float* bg2  = (const float*)d_in[8];
  float* out = (float*)d_out;

  const size_t NX   = (size_t)BN_TOT * DIM;
  const size_t NWQ  = (size_t)DIM * 3 * DIM;
  const size_t NWO  = (size_t)DIM * DIM;
  const size_t NHEA = (size_t)BATCH * HEADS * SEQ * HD;

  float* g   = (float*)d_ws;
  u16* base  = (u16*)(g + (size_t)BATCH * HEADS * SEQ);
  u16* x16   = base;          u16* wth  = x16 + NX;
  u16* wtl   = wth + NWQ;     u16* woth = wtl + NWQ;
  u16* wotl  = woth + NWO;
  u16* Qh    = wotl + NWO;    u16* Ql   = Qh + NHEA;
  u16* K16   = Ql + NHEA;     u16* VT   = K16 + NHEA;
  u16* AO16  = VT + NHEA;

  cvt16_kernel<<<(int)(NX / 1024), 256, 0, stream>>>(x, x16, (int)(NX / 4));
  transpose_split<<<dim3(3 * DIM / 64, DIM / 64), 256, 0, stream>>>(
      Wqkv, wth, wtl, DIM, 3 * DIM);
  transpose_split<<<dim3(DIM / 64, DIM / 64), 256, 0, stream>>>(
      Wo, woth, wotl, DIM, DIM);
  gate_kernel<<<BN_TOT / 256, 256, 0, stream>>>(cov, Wg1, bg1, Wg2, bg2, g);
  qkv_mfma<<<dim3(3 * DIM / 128, BN_TOT / 128), 256, 0, stream>>>(
      x16, wth, wtl, Qh, Ql, K16, VT);
  attn_mfma<<<SEQ / 64 * BATCH * HEADS, 256, 0, stream>>>(
      Qh, Ql, K16, VT, g, AO16);
  outproj_mfma<<<dim3(DIM / 64, BN_TOT / 128), 256, 0, stream>>>(
      AO16, woth, wotl, bo, out);
}

// Round 11
// 203.232 us; speedup vs baseline: 7.5880x; 1.0144x over previous
//
#include <hip/hip_runtime.h>
#include <math.h>

#define DIM 768
#define HEADS 12
#define HD 64
#define GATE_HID 192
#define BATCH 2
#define SEQ 2048
#define BN_TOT (BATCH*SEQ)          // 4096
#define ATT_SCALE 0.125f            // 64^-0.5
#define SCL2E 0.180336879f          // ATT_SCALE * log2(e)

typedef unsigned short u16;
typedef __attribute__((ext_vector_type(8))) _Float16 f16x8;
typedef __attribute__((ext_vector_type(2))) __fp16 fp16v2;
typedef __attribute__((ext_vector_type(4))) float f32x4;

#define MFMA16F(a, b, c) __builtin_amdgcn_mfma_f32_16x16x32_f16(a, b, c, 0, 0, 0)

// global -> LDS direct copy, 16B per lane; lds dest = wave-uniform base + lane*16
__device__ __forceinline__ void gld16(const u16* g, u16* lds) {
  __builtin_amdgcn_global_load_lds(
      (const __attribute__((address_space(1))) void*)g,
      (__attribute__((address_space(3))) void*)lds, 16, 0, 0);
}

__device__ inline u16 f2h(float x) {            // RNE fp32->fp16
  union { _Float16 h; u16 u; } c; c.h = (_Float16)x; return c.u;
}
__device__ inline float h2f(u16 u) {
  union { _Float16 h; u16 u; } c; c.u = u; return (float)c.h;
}
__device__ inline unsigned cvtpk(float a, float b) {   // RTZ packed
  union { fp16v2 h; unsigned u; } c;
  c.h = __builtin_amdgcn_cvt_pkrtz(a, b);
  return c.u;
}

// ---------------------------------------------------------------------------
// Prep A: elementwise fp32 -> fp16 (RNE).
// ---------------------------------------------------------------------------
__global__ __launch_bounds__(256) void cvt16_kernel(
    const float* __restrict__ src, u16* __restrict__ dst, int n4)
{
  int i = blockIdx.x * 256 + threadIdx.x;
  if (i >= n4) return;
  float4 v = reinterpret_cast<const float4*>(src)[i];
  uint2 o;
  o.x = (unsigned)f2h(v.x) | ((unsigned)f2h(v.y) << 16);
  o.y = (unsigned)f2h(v.z) | ((unsigned)f2h(v.w) << 16);
  reinterpret_cast<uint2*>(dst)[i] = o;
}

// ---------------------------------------------------------------------------
// Prep B: transpose + fp16 hi/lo split.  src [R][C] fp32 -> th/tl [C][R].
// ---------------------------------------------------------------------------
__global__ __launch_bounds__(256) void transpose_split(
    const float* __restrict__ src, u16* __restrict__ th, u16* __restrict__ tl,
    int R, int C)
{
  __shared__ float tile[64][65];
  const int t = threadIdx.x;
  const int c = t & 63, r4 = t >> 6;
  const int gr0 = blockIdx.y * 64, gc0 = blockIdx.x * 64;
  #pragma unroll
  for (int i = 0; i < 16; ++i) {
    int row = i * 4 + r4;
    tile[row][c] = src[(size_t)(gr0 + row) * C + gc0 + c];
  }
  __syncthreads();
  #pragma unroll
  for (int i = 0; i < 16; ++i) {
    int rr = i * 4 + r4;
    float v = tile[c][rr];
    u16 hh = f2h(v);
    size_t o = (size_t)(gc0 + rr) * R + gr0 + c;
    th[o] = hh;
    tl[o] = f2h(v - h2f(hh));
  }
}

// ---------------------------------------------------------------------------
// Kernel 1: coverage gate MLP.  Output pre-scaled by SCL2E (exp2-domain fold).
// ---------------------------------------------------------------------------
__global__ __launch_bounds__(256) void gate_kernel(
    const float* __restrict__ cov, const float* __restrict__ Wg1,
    const float* __restrict__ bg1, const float* __restrict__ Wg2,
    const float* __restrict__ bg2, float* __restrict__ g)
{
  int idx = blockIdx.x * 256 + threadIdx.x;   // b*SEQ + n
  if (idx >= BN_TOT) return;
  float c = cov[idx];
  float acc[HEADS];
  #pragma unroll
  for (int t = 0; t < HEADS; ++t) acc[t] = bg2[t];
  for (int j = 0; j < GATE_HID; ++j) {
    float hpre = c * Wg1[j] + bg1[j];
    float s = hpre / (1.f + __expf(-hpre));   // silu
    #pragma unroll
    for (int t = 0; t < HEADS; ++t) acc[t] += s * Wg2[j * HEADS + t];
  }
  int b = idx / SEQ, n = idx % SEQ;
  #pragma unroll
  for (int t = 0; t < HEADS; ++t) {
    float val = SCL2E / (1.f + __expf(-acc[t]));
    g[(size_t)(b * HEADS + t) * SEQ + n] = val;
  }
}

// ---------------------------------------------------------------------------
// Kernel 2: qkv = x @ Wqkv.  x fp16 single (A), W fp16 hi/lo (B) -> 2-term
// fp16 MFMA.  global_load_lds staging, double-buffered LDS (48KB).
// XCD chunk-swizzle: 576 blocks = 8 XCDs x (9x * 8y) -> per-XCD working set
// (x 1.57MB + W 1.77MB) fits 4MB L2.
// Epilogue: Q fp16 hi/lo kappa-d; K fp16 single kappa-d PRE-SCALED by the
// coverage gate (score = q.(k*s*g) algebraic fold); V pre-transposed +
// pre-swizzled flat 8KB tiles for attn's global_load_lds (rule #21).
// ---------------------------------------------------------------------------
#define QISSUE(kb, X) do { \
  _Pragma("unroll") for (int cc = 0; cc < 2; ++cc) { \
    int c = t + cc * 256; int mf = c >> 6, lg = (c >> 4) & 3, rr = c & 15; \
    size_t ga = (size_t)(row0 + mf * 16 + rr) * DIM + (kb) + lg * 8; \
    size_t gb = (size_t)(col0 + mf * 16 + rr) * DIM + (kb) + lg * 8; \
    int lo = (w * 64 + cc * 256) * 8; \
    gld16(&x16[ga], &AS##X[lo]); \
    gld16(&wth[gb], &BH##X[lo]); gld16(&wtl[gb], &BL##X[lo]); \
  } } while (0)

__global__ __launch_bounds__(256) void qkv_mfma(
    const u16* __restrict__ x16,
    const u16* __restrict__ wth, const u16* __restrict__ wtl,
    const float* __restrict__ G,
    u16* __restrict__ Qh, u16* __restrict__ Ql,
    u16* __restrict__ K16, u16* __restrict__ VT)
{
  __shared__ u16 AS0[4096], BH0[4096], BL0[4096];
  __shared__ u16 AS1[4096], BH1[4096], BL1[4096];
  const int t = threadIdx.x;
  const int w = t >> 6, l = t & 63;
  const int lan15 = l & 15, lgrp = l >> 4;
  // XCD chunk swizzle: xcd = id%8 owns a (9x, 8y) chunk (L2-resident)
  const int id  = blockIdx.x;          // 0..575
  const int xcd = id & 7;
  const int j   = id >> 3;             // 0..71
  const int bx  = (xcd & 1) * 9 + (j % 9);
  const int by  = (xcd >> 1) * 8 + (j / 9);
  const int row0 = by * 128, col0 = bx * 128;
  const int wrf = (w >> 1) * 4, wcf = (w & 1) * 4;

  f32x4 acc[4][4];
  #pragma unroll
  for (int i = 0; i < 4; ++i)
    #pragma unroll
    for (int jj = 0; jj < 4; ++jj) acc[i][jj] = (f32x4){0.f, 0.f, 0.f, 0.f};

  auto qcompute = [&](int buf) {
    const u16* ASc = buf ? AS1 : AS0;
    const u16* BHc = buf ? BH1 : BH0; const u16* BLc = buf ? BL1 : BL0;
    f16x8 a4[4];
    #pragma unroll
    for (int mi = 0; mi < 4; ++mi)
      a4[mi] = *reinterpret_cast<const f16x8*>(&ASc[((wrf + mi) * 64 + l) * 8]);
    __builtin_amdgcn_s_setprio(1);
    #pragma unroll
    for (int ni = 0; ni < 4; ++ni) {
      f16x8 bh = *reinterpret_cast<const f16x8*>(&BHc[((wcf + ni) * 64 + l) * 8]);
      f16x8 bl = *reinterpret_cast<const f16x8*>(&BLc[((wcf + ni) * 64 + l) * 8]);
      #pragma unroll
      for (int mi = 0; mi < 4; ++mi) {
        acc[mi][ni] = MFMA16F(a4[mi], bh, acc[mi][ni]);
        acc[mi][ni] = MFMA16F(a4[mi], bl, acc[mi][ni]);
      }
    }
    __builtin_amdgcn_s_setprio(0);
  };

  QISSUE(0, 0);
  for (int kb = 0; kb < DIM; kb += 64) {
    __syncthreads();               // drains buf0 loads (kb); prev readers done
    QISSUE(kb + 32, 1);            // in flight across qcompute(0)
    qcompute(0);
    __syncthreads();               // drains buf1 loads; buf0 readers done
    if (kb + 64 < DIM) QISSUE(kb + 64, 0);
    qcompute(1);
  }

  // epilogue: wave's 64-col block = one head of one section.
  const int gc0 = col0 + (w & 1) * 64;
  const int sec = gc0 / DIM;
  const int hh_ = (gc0 % DIM) / HD;
  const int wrr = (w >> 1) * 64;
  #pragma unroll
  for (int mi = 0; mi < 4; ++mi) {
    #pragma unroll
    for (int reg = 0; reg < 4; ++reg) {
      int row = row0 + wrr + mi * 16 + lgrp * 4 + reg;
      int bb  = row >> 11;
      int nn  = row & 2047;
      size_t base = ((size_t)(bb * HEADS + hh_) * SEQ + nn) * HD;
      float f0 = acc[mi][0][reg], f1 = acc[mi][1][reg];
      float f2 = acc[mi][2][reg], f3 = acc[mi][3][reg];
      if (sec == 0) {
        // Q: fp16 hi/lo, kappa-d layout (kappa = lan15*4 + ni), packed b64
        u16 h0 = f2h(f0), h1 = f2h(f1), h2 = f2h(f2), h3 = f2h(f3);
        uint2 hiw, low;
        hiw.x = (unsigned)h0 | ((unsigned)h1 << 16);
        hiw.y = (unsigned)h2 | ((unsigned)h3 << 16);
        low.x = (unsigned)f2h(f0 - h2f(h0)) | ((unsigned)f2h(f1 - h2f(h1)) << 16);
        low.y = (unsigned)f2h(f2 - h2f(h2)) | ((unsigned)f2h(f3 - h2f(h3)) << 16);
        *reinterpret_cast<uint2*>(&Qh[base + lan15 * 4]) = hiw;
        *reinterpret_cast<uint2*>(&Ql[base + lan15 * 4]) = low;
      } else if (sec == 1) {
        // K: fp16 single, kappa-d layout, PRE-SCALED by gate (s*g*log2e)
        float gv = G[(size_t)(bb * HEADS + hh_) * SEQ + nn];
        uint2 kw;
        kw.x = (unsigned)f2h(f0 * gv) | ((unsigned)f2h(f1 * gv) << 16);
        kw.y = (unsigned)f2h(f2 * gv) | ((unsigned)f2h(f3 * gv) << 16);
        *reinterpret_cast<uint2*>(&K16[base + lan15 * 4]) = kw;
      } else {
        // V^T pre-swizzled tile store (scattered u16; L2 absorbs)
        int kt_ = nn >> 6, key = nn & 63;
        int ct_ = key >> 4, lg2 = (key >> 2) & 3, rr_ = key & 3;
        int kap = (ct_ >> 1) * 32 + lg2 * 8 + (ct_ & 1) * 4 + rr_;
        size_t tb = (size_t)((bb * HEADS + hh_) * 32 + kt_) * 4096;
        float fs[4] = {f0, f1, f2, f3};
        #pragma unroll
        for (int ni = 0; ni < 4; ++ni) {
          int d = ni * 16 + lan15;
          VT[tb + ((d * 64 + kap) ^ ((d & 7) << 3))] = f2h(fs[ni]);
        }
      }
    }
  }
}

// ---------------------------------------------------------------------------
// Kernel 3: flash attention, swapped QK^T: S^T = mfma(K, Q).  K carries the
// gate fold (k*s*g*log2e) so softmax is exp2(acc - m) directly.  K + pre-
// swizzled V^T staged via global_load_lds (dbuf, 1 barrier/tile).  Q fp16
// hi/lo in regs (exact) -> 2-term QK.  Lane-local softmax, P in-register
// fp16 B-frag, PV fp16 MFMA -> O^T.
// ---------------------------------------------------------------------------
#define AISSUE(kt, X) do { \
  _Pragma("unroll") for (int cc = 0; cc < 2; ++cc) { \
    int c = t + cc * 256; int fi = c >> 6, lg = (c >> 4) & 3, rr = c & 15; \
    size_t gk = kvbase + (size_t)((kt) * 64 + (fi >> 1) * 16 + rr) * HD \
                + (fi & 1) * 32 + lg * 8; \
    int lo = (w * 64 + cc * 256) * 8; \
    gld16(&K16[gk], &KS##X[lo]); \
    gld16(&VT[vtbase + (size_t)(kt) * 4096 + (size_t)c * 8], &VTS##X[lo]); \
  } } while (0)

__global__ __launch_bounds__(256) void attn_mfma(
    const u16* __restrict__ Qh, const u16* __restrict__ Ql,
    const u16* __restrict__ K16, const u16* __restrict__ VT,
    u16* __restrict__ AO16)
{
  __shared__ u16 KS0[4096], KS1[4096];
  __shared__ u16 VTS0[4096], VTS1[4096];   // [d][kappa], fp16, swizzled

  const int t     = threadIdx.x;
  const int w     = t >> 6, l = t & 63;
  const int lan15 = l & 15;
  const int lgrp  = l >> 4;
  // XCD swizzle: block n -> xcd = n%8 owns heads 3*(n%8)..+2
  const int n   = blockIdx.x;          // 0..767
  const int s_  = n >> 3;              // 0..95
  const int bh  = (n & 7) * 3 + (s_ >> 5);
  const int qt  = s_ & 31;
  const int b   = bh / HEADS;
  const int h   = bh % HEADS;
  const size_t kvbase = (size_t)bh * SEQ * HD;
  const size_t vtbase = (size_t)bh * 32 * 4096;

  // Q fragments (fp16 hi/lo, kappa-d layout): B-operand, lane's q-row = lan15
  f16x8 qh[2], ql[2];
  {
    size_t qrow = kvbase + (size_t)(qt * 64 + w * 16 + lan15) * HD;
    #pragma unroll
    for (int s = 0; s < 2; ++s) {
      qh[s] = *reinterpret_cast<const f16x8*>(&Qh[qrow + s * 32 + lgrp * 8]);
      ql[s] = *reinterpret_cast<const f16x8*>(&Ql[qrow + s * 32 + lgrp * 8]);
    }
  }

  f32x4 o[4];      // O^T: o[dt] rows d = dt*16 + lgrp*4 + reg, col q = lan15
  #pragma unroll
  for (int dt = 0; dt < 4; ++dt) o[dt] = (f32x4){0.f, 0.f, 0.f, 0.f};
  float mrun  = -INFINITY;
  float lpart = 0.f;   // per-lane partial over this lane's 16 keys/tile

  auto compute_tile = [&](int kt, int buf) {
    const u16* KC = buf ? KS1 : KS0;
    const u16* VC = buf ? VTS1 : VTS0;

    // ---- S^T = K Q^T (fp16 2-term: Q exact via hi+lo); A=K, B=Q ----
    f32x4 acc[4];
    #pragma unroll
    for (int ct = 0; ct < 4; ++ct) acc[ct] = (f32x4){0.f, 0.f, 0.f, 0.f};
    __builtin_amdgcn_s_setprio(1);
    #pragma unroll
    for (int s = 0; s < 2; ++s) {
      #pragma unroll
      for (int ct = 0; ct < 4; ++ct) {
        int aidx = ((ct * 2 + s) * 64 + l) * 8;
        f16x8 ka = *reinterpret_cast<const f16x8*>(&KC[aidx]);
        acc[ct] = MFMA16F(ka, qh[s], acc[ct]);
        acc[ct] = MFMA16F(ka, ql[s], acc[ct]);
      }
    }
    __builtin_amdgcn_s_setprio(0);

    // ---- online softmax (exp2 domain, lane-local row; gate already in K) --
    float tmax = acc[0][0];
    #pragma unroll
    for (int ct = 0; ct < 4; ++ct)
      #pragma unroll
      for (int r = 0; r < 4; ++r) tmax = fmaxf(tmax, acc[ct][r]);
    tmax = fmaxf(tmax, __shfl_xor(tmax, 16));
    tmax = fmaxf(tmax, __shfl_xor(tmax, 32));
    // exact rescale-skip: when no row's max grew, fsc == 1 exactly
    if (__any(tmax > mrun)) {
      float mnew = fmaxf(mrun, tmax);
      float fsc  = exp2f(mrun - mnew);
      mrun = mnew;
      lpart *= fsc;
      #pragma unroll
      for (int dt = 0; dt < 4; ++dt) o[dt] *= fsc;
    }
    float p[4][4];
    float s0 = 0.f;
    #pragma unroll
    for (int ct = 0; ct < 4; ++ct)
      #pragma unroll
      for (int r = 0; r < 4; ++r) {
        p[ct][r] = exp2f(acc[ct][r] - mrun);
        s0 += p[ct][r];
      }
    lpart += s0;

    // ---- P -> fp16 B-frags IN REGISTER (kappa-matched, no LDS) ----
    union { uint4 u; f16x8 h; } pb0, pb1;
    pb0.u.x = cvtpk(p[0][0], p[0][1]); pb0.u.y = cvtpk(p[0][2], p[0][3]);
    pb0.u.z = cvtpk(p[1][0], p[1][1]); pb0.u.w = cvtpk(p[1][2], p[1][3]);
    pb1.u.x = cvtpk(p[2][0], p[2][1]); pb1.u.y = cvtpk(p[2][2], p[2][3]);
    pb1.u.z = cvtpk(p[3][0], p[3][1]); pb1.u.w = cvtpk(p[3][2], p[3][3]);

    // ---- O^T += V^T P^T (single fp16 MFMA per frag); A=V^T, B=P^T ----
    __builtin_amdgcn_s_setprio(1);
    #pragma unroll
    for (int s = 0; s < 2; ++s) {
      #pragma unroll
      for (int dt = 0; dt < 4; ++dt) {
        int brow = dt * 16 + lan15;
        int bidx = (brow * 64 + s * 32 + lgrp * 8) ^ ((brow & 7) << 3);
        f16x8 va = *reinterpret_cast<const f16x8*>(&VC[bidx]);
        o[dt] = MFMA16F(va, s ? pb1.h : pb0.h, o[dt]);
      }
    }
    __builtin_amdgcn_s_setprio(0);
  };

  AISSUE(0, 0);
  for (int kt = 0; kt < SEQ / 64; kt += 2) {
    __syncthreads();                  // drains buf0 loads; buf0 readers done
    AISSUE(kt + 1, 1);                // in flight across compute(kt)
    compute_tile(kt, 0);
    __syncthreads();                  // drains buf1 loads; buf1 readers done
    if (kt + 2 < SEQ / 64) AISSUE(kt + 2, 0);
    compute_tile(kt + 1, 1);
  }

  // ---- epilogue: reduce l, normalize, packed fp16 write (RNE) ----
  lpart += __shfl_xor(lpart, 16);
  lpart += __shfl_xor(lpart, 32);
  float inv = 1.f / lpart;
  const int qrow = qt * 64 + w * 16 + lan15;
  const size_t base = (size_t)(b * SEQ + qrow) * DIM + h * HD;
  #pragma unroll
  for (int dt = 0; dt < 4; ++dt) {
    float f0 = o[dt][0] * inv, f1 = o[dt][1] * inv;
    float f2 = o[dt][2] * inv, f3 = o[dt][3] * inv;
    uint2 ow;
    ow.x = (unsigned)f2h(f0) | ((unsigned)f2h(f1) << 16);
    ow.y = (unsigned)f2h(f2) | ((unsigned)f2h(f3) << 16);
    *reinterpret_cast<uint2*>(&AO16[base + dt * 16 + lgrp * 4]) = ow;
  }
}

// ---------------------------------------------------------------------------
// Kernel 4: out = AO @ Wo + bo.  AO fp16 single (A), Wo fp16 hi/lo (B),
// 2-term fp16 MFMA, gld_lds staging (32KB dbuf).  XCD chunk swizzle:
// 384 blocks = 8 XCDs x (6x * 8y).
// ---------------------------------------------------------------------------
#define OISSUE(kb, X) do { \
  _Pragma("unroll") for (int cc = 0; cc < 2; ++cc) { \
    int c = t + cc * 256; int mf = c >> 6, lg = (c >> 4) & 3, rr = c & 15; \
    size_t ga = (size_t)(row0 + mf * 16 + rr) * DIM + (kb) + lg * 8; \
    int lo = (w * 64 + cc * 256) * 8; \
    gld16(&a16[ga], &AS##X[lo]); } \
  { int c = t; int nf = c >> 6, lg = (c >> 4) & 3, rr = c & 15; \
    size_t gb = (size_t)(col0 + nf * 16 + rr) * DIM + (kb) + lg * 8; \
    int lo = (w * 64) * 8; \
    gld16(&bth[gb], &BH##X[lo]); gld16(&btl[gb], &BL##X[lo]); } } while (0)

__global__ __launch_bounds__(256) void outproj_mfma(
    const u16* __restrict__ a16,
    const u16* __restrict__ bth, const u16* __restrict__ btl,
    const float* __restrict__ bo, float* __restrict__ out)
{
  __shared__ u16 AS0[4096], AS1[4096];
  __shared__ u16 BH0[2048], BL0[2048], BH1[2048], BL1[2048];
  const int t = threadIdx.x;
  const int w = t >> 6, l = t & 63;
  const int lan15 = l & 15, lgrp = l >> 4;
  // XCD chunk swizzle: xcd = id%8 owns a (6x, 8y) chunk
  const int id  = blockIdx.x;          // 0..383
  const int xcd = id & 7;
  const int j   = id >> 3;             // 0..47
  const int bx  = (xcd & 1) * 6 + (j % 6);
  const int by  = (xcd >> 1) * 8 + (j / 6);
  const int row0 = by * 128, col0 = bx * 64;
  const int wrf = (w >> 1) * 4, wcf = (w & 1) * 2;

  f32x4 acc[4][2];
  #pragma unroll
  for (int i = 0; i < 4; ++i)
    #pragma unroll
    for (int jj = 0; jj < 2; ++jj) acc[i][jj] = (f32x4){0.f, 0.f, 0.f, 0.f};

  auto ocompute = [&](int buf) {
    const u16* ASc = buf ? AS1 : AS0;
    const u16* BHc = buf ? BH1 : BH0; const u16* BLc = buf ? BL1 : BL0;
    f16x8 a4[4];
    #pragma unroll
    for (int mi = 0; mi < 4; ++mi)
      a4[mi] = *reinterpret_cast<const f16x8*>(&ASc[((wrf + mi) * 64 + l) * 8]);
    __builtin_amdgcn_s_setprio(1);
    #pragma unroll
    for (int ni = 0; ni < 2; ++ni) {
      f16x8 bh = *reinterpret_cast<const f16x8*>(&BHc[((wcf + ni) * 64 + l) * 8]);
      f16x8 bl = *reinterpret_cast<const f16x8*>(&BLc[((wcf + ni) * 64 + l) * 8]);
      #pragma unroll
      for (int mi = 0; mi < 4; ++mi) {
        acc[mi][ni] = MFMA16F(a4[mi], bh, acc[mi][ni]);
        acc[mi][ni] = MFMA16F(a4[mi], bl, acc[mi][ni]);
      }
    }
    __builtin_amdgcn_s_setprio(0);
  };

  OISSUE(0, 0);
  for (int kb = 0; kb < DIM; kb += 64) {
    __syncthreads();
    OISSUE(kb + 32, 1);
    ocompute(0);
    __syncthreads();
    if (kb + 64 < DIM) OISSUE(kb + 64, 0);
    ocompute(1);
  }

  const int wrr = (w >> 1) * 64, wcc = (w & 1) * 32;
  #pragma unroll
  for (int mi = 0; mi < 4; ++mi) {
    #pragma unroll
    for (int reg = 0; reg < 4; ++reg) {
      int row = row0 + wrr + mi * 16 + lgrp * 4 + reg;
      #pragma unroll
      for (int ni = 0; ni < 2; ++ni) {
        int col = col0 + wcc + ni * 16 + lan15;
        out[(size_t)row * DIM + col] = acc[mi][ni][reg] + bo[col];
      }
    }
  }
}

// ---------------------------------------------------------------------------
extern "C" void kernel_launch(void* const* d_in, const int* in_sizes, int n_in,
                              void* d_out, int out_size, void* d_ws, size_t ws_size,
                              hipStream_t stream) {
  const float* x    = (const float*)d_in[0];
  const float* cov  = (const float*)d_in[1];
  const float* Wqkv = (const float*)d_in[2];
  const float* Wo   = (const float*)d_in[3];
  const float* bo   = (const float*)d_in[4];
  const float* Wg1  = (const float*)d_in[5];
  const float* bg1  = (const float*)d_in[6];
  const float* Wg2  = (const float*)d_in[7];
  const float* bg2  = (const float*)d_in[8];
  float* out = (float*)d_out;

  const size_t NX   = (size_t)BN_TOT * DIM;
  const size_t NWQ  = (size_t)DIM * 3 * DIM;
  const size_t NWO  = (size_t)DIM * DIM;
  const size_t NHEA = (size_t)BATCH * HEADS * SEQ * HD;

  float* g   = (float*)d_ws;
  u16* base  = (u16*)(g + (size_t)BATCH * HEADS * SEQ);
  u16* x16   = base;          u16* wth  = x16 + NX;
  u16* wtl   = wth + NWQ;     u16* woth = wtl + NWQ;
  u16* wotl  = woth + NWO;
  u16* Qh    = wotl + NWO;    u16* Ql   = Qh + NHEA;
  u16* K16   = Ql + NHEA;     u16* VT   = K16 + NHEA;
  u16* AO16  = VT + NHEA;

  cvt16_kernel<<<(int)(NX / 1024), 256, 0, stream>>>(x, x16, (int)(NX / 4));
  transpose_split<<<dim3(3 * DIM / 64, DIM / 64), 256, 0, stream>>>(
      Wqkv, wth, wtl, DIM, 3 * DIM);
  transpose_split<<<dim3(DIM / 64, DIM / 64), 256, 0, stream>>>(
      Wo, woth, wotl, DIM, DIM);
  gate_kernel<<<BN_TOT / 256, 256, 0, stream>>>(cov, Wg1, bg1, Wg2, bg2, g);
  qkv_mfma<<<576, 256, 0, stream>>>(x16, wth, wtl, g, Qh, Ql, K16, VT);
  attn_mfma<<<SEQ / 64 * BATCH * HEADS, 256, 0, stream>>>(
      Qh, Ql, K16, VT, AO16);
  outproj_mfma<<<384, 256, 0, stream>>>(AO16, woth, wotl, bo, out);
}

// Round 12
// 194.273 us; speedup vs baseline: 7.9379x; 1.0461x over previous
//
#include <hip/hip_runtime.h>
#include <math.h>

#define DIM 768
#define HEADS 12
#define HD 64
#define GATE_HID 192
#define BATCH 2
#define SEQ 2048
#define BN_TOT (BATCH*SEQ)          // 4096
#define ATT_SCALE 0.125f            // 64^-0.5
#define SCL2E 0.180336879f          // ATT_SCALE * log2(e)

typedef unsigned short u16;
typedef __attribute__((ext_vector_type(8))) _Float16 f16x8;
typedef __attribute__((ext_vector_type(2))) __fp16 fp16v2;
typedef __attribute__((ext_vector_type(4))) float f32x4;

#define MFMA16F(a, b, c) __builtin_amdgcn_mfma_f32_16x16x32_f16(a, b, c, 0, 0, 0)

// global -> LDS direct copy, 16B per lane; lds dest = wave-uniform base + lane*16
__device__ __forceinline__ void gld16(const u16* g, u16* lds) {
  __builtin_amdgcn_global_load_lds(
      (const __attribute__((address_space(1))) void*)g,
      (__attribute__((address_space(3))) void*)lds, 16, 0, 0);
}

__device__ inline u16 f2h(float x) {            // RNE fp32->fp16
  union { _Float16 h; u16 u; } c; c.h = (_Float16)x; return c.u;
}
__device__ inline float h2f(u16 u) {
  union { _Float16 h; u16 u; } c; c.u = u; return (float)c.h;
}
__device__ inline unsigned cvtpk(float a, float b) {   // RTZ packed
  union { fp16v2 h; unsigned u; } c;
  c.h = __builtin_amdgcn_cvt_pkrtz(a, b);
  return c.u;
}
// raw v_exp_f32 (args <= 0 here; FTZ on tiny args is harmless)
__device__ inline float fexp2(float x) { return __builtin_amdgcn_exp2f(x); }

// ---------------------------------------------------------------------------
// Prep A: elementwise fp32 -> fp16 (RNE).
// ---------------------------------------------------------------------------
__global__ __launch_bounds__(256) void cvt16_kernel(
    const float* __restrict__ src, u16* __restrict__ dst, int n4)
{
  int i = blockIdx.x * 256 + threadIdx.x;
  if (i >= n4) return;
  float4 v = reinterpret_cast<const float4*>(src)[i];
  uint2 o;
  o.x = (unsigned)f2h(v.x) | ((unsigned)f2h(v.y) << 16);
  o.y = (unsigned)f2h(v.z) | ((unsigned)f2h(v.w) << 16);
  reinterpret_cast<uint2*>(dst)[i] = o;
}

// ---------------------------------------------------------------------------
// Prep B: transpose + fp16 hi/lo split.  src [R][C] fp32 -> th/tl [C][R].
// ---------------------------------------------------------------------------
__global__ __launch_bounds__(256) void transpose_split(
    const float* __restrict__ src, u16* __restrict__ th, u16* __restrict__ tl,
    int R, int C)
{
  __shared__ float tile[64][65];
  const int t = threadIdx.x;
  const int c = t & 63, r4 = t >> 6;
  const int gr0 = blockIdx.y * 64, gc0 = blockIdx.x * 64;
  #pragma unroll
  for (int i = 0; i < 16; ++i) {
    int row = i * 4 + r4;
    tile[row][c] = src[(size_t)(gr0 + row) * C + gc0 + c];
  }
  __syncthreads();
  #pragma unroll
  for (int i = 0; i < 16; ++i) {
    int rr = i * 4 + r4;
    float v = tile[c][rr];
    u16 hh = f2h(v);
    size_t o = (size_t)(gc0 + rr) * R + gr0 + c;
    th[o] = hh;
    tl[o] = f2h(v - h2f(hh));
  }
}

// ---------------------------------------------------------------------------
// Kernel 1: coverage gate MLP.  Output pre-scaled by SCL2E (exp2-domain fold).
// ---------------------------------------------------------------------------
__global__ __launch_bounds__(256) void gate_kernel(
    const float* __restrict__ cov, const float* __restrict__ Wg1,
    const float* __restrict__ bg1, const float* __restrict__ Wg2,
    const float* __restrict__ bg2, float* __restrict__ g)
{
  int idx = blockIdx.x * 256 + threadIdx.x;   // b*SEQ + n
  if (idx >= BN_TOT) return;
  float c = cov[idx];
  float acc[HEADS];
  #pragma unroll
  for (int t = 0; t < HEADS; ++t) acc[t] = bg2[t];
  for (int j = 0; j < GATE_HID; ++j) {
    float hpre = c * Wg1[j] + bg1[j];
    float s = hpre / (1.f + __expf(-hpre));   // silu
    #pragma unroll
    for (int t = 0; t < HEADS; ++t) acc[t] += s * Wg2[j * HEADS + t];
  }
  int b = idx / SEQ, n = idx % SEQ;
  #pragma unroll
  for (int t = 0; t < HEADS; ++t) {
    float val = SCL2E / (1.f + __expf(-acc[t]));
    g[(size_t)(b * HEADS + t) * SEQ + n] = val;
  }
}

// ---------------------------------------------------------------------------
// Kernel 2: qkv = x @ Wqkv.  x fp16 single (A), W fp16 hi/lo (B) -> 2-term
// fp16 MFMA.  global_load_lds staging, double-buffered LDS (48KB).
// XCD chunk-swizzle: 576 blocks = 8 XCDs x (9x * 8y).
// Epilogue: Q fp16 hi/lo kappa-d; K fp16 single kappa-d PRE-SCALED by the
// coverage gate; V pre-transposed + pre-swizzled flat 8KB tiles.
// ---------------------------------------------------------------------------
#define QISSUE(kb, X) do { \
  _Pragma("unroll") for (int cc = 0; cc < 2; ++cc) { \
    int c = t + cc * 256; int mf = c >> 6, lg = (c >> 4) & 3, rr = c & 15; \
    size_t ga = (size_t)(row0 + mf * 16 + rr) * DIM + (kb) + lg * 8; \
    size_t gb = (size_t)(col0 + mf * 16 + rr) * DIM + (kb) + lg * 8; \
    int lo = (w * 64 + cc * 256) * 8; \
    gld16(&x16[ga], &AS##X[lo]); \
    gld16(&wth[gb], &BH##X[lo]); gld16(&wtl[gb], &BL##X[lo]); \
  } } while (0)

__global__ __launch_bounds__(256) void qkv_mfma(
    const u16* __restrict__ x16,
    const u16* __restrict__ wth, const u16* __restrict__ wtl,
    const float* __restrict__ G,
    u16* __restrict__ Qh, u16* __restrict__ Ql,
    u16* __restrict__ K16, u16* __restrict__ VT)
{
  __shared__ u16 AS0[4096], BH0[4096], BL0[4096];
  __shared__ u16 AS1[4096], BH1[4096], BL1[4096];
  const int t = threadIdx.x;
  const int w = t >> 6, l = t & 63;
  const int lan15 = l & 15, lgrp = l >> 4;
  // XCD chunk swizzle: xcd = id%8 owns a (9x, 8y) chunk
  const int id  = blockIdx.x;          // 0..575
  const int xcd = id & 7;
  const int j   = id >> 3;             // 0..71
  const int bx  = (xcd & 1) * 9 + (j % 9);
  const int by  = (xcd >> 1) * 8 + (j / 9);
  const int row0 = by * 128, col0 = bx * 128;
  const int wrf = (w >> 1) * 4, wcf = (w & 1) * 4;

  f32x4 acc[4][4];
  #pragma unroll
  for (int i = 0; i < 4; ++i)
    #pragma unroll
    for (int jj = 0; jj < 4; ++jj) acc[i][jj] = (f32x4){0.f, 0.f, 0.f, 0.f};

  auto qcompute = [&](int buf) {
    const u16* ASc = buf ? AS1 : AS0;
    const u16* BHc = buf ? BH1 : BH0; const u16* BLc = buf ? BL1 : BL0;
    f16x8 a4[4];
    #pragma unroll
    for (int mi = 0; mi < 4; ++mi)
      a4[mi] = *reinterpret_cast<const f16x8*>(&ASc[((wrf + mi) * 64 + l) * 8]);
    __builtin_amdgcn_s_setprio(1);
    #pragma unroll
    for (int ni = 0; ni < 4; ++ni) {
      f16x8 bh = *reinterpret_cast<const f16x8*>(&BHc[((wcf + ni) * 64 + l) * 8]);
      f16x8 bl = *reinterpret_cast<const f16x8*>(&BLc[((wcf + ni) * 64 + l) * 8]);
      #pragma unroll
      for (int mi = 0; mi < 4; ++mi) {
        acc[mi][ni] = MFMA16F(a4[mi], bh, acc[mi][ni]);
        acc[mi][ni] = MFMA16F(a4[mi], bl, acc[mi][ni]);
      }
    }
    __builtin_amdgcn_s_setprio(0);
  };

  QISSUE(0, 0);
  for (int kb = 0; kb < DIM; kb += 64) {
    __syncthreads();               // drains buf0 loads (kb); prev readers done
    QISSUE(kb + 32, 1);            // in flight across qcompute(0)
    qcompute(0);
    __syncthreads();               // drains buf1 loads; buf0 readers done
    if (kb + 64 < DIM) QISSUE(kb + 64, 0);
    qcompute(1);
  }

  // epilogue: wave's 64-col block = one head of one section.
  const int gc0 = col0 + (w & 1) * 64;
  const int sec = gc0 / DIM;
  const int hh_ = (gc0 % DIM) / HD;
  const int wrr = (w >> 1) * 64;
  #pragma unroll
  for (int mi = 0; mi < 4; ++mi) {
    #pragma unroll
    for (int reg = 0; reg < 4; ++reg) {
      int row = row0 + wrr + mi * 16 + lgrp * 4 + reg;
      int bb  = row >> 11;
      int nn  = row & 2047;
      size_t base = ((size_t)(bb * HEADS + hh_) * SEQ + nn) * HD;
      float f0 = acc[mi][0][reg], f1 = acc[mi][1][reg];
      float f2 = acc[mi][2][reg], f3 = acc[mi][3][reg];
      if (sec == 0) {
        // Q: fp16 hi/lo, kappa-d layout (kappa = lan15*4 + ni), packed b64
        u16 h0 = f2h(f0), h1 = f2h(f1), h2 = f2h(f2), h3 = f2h(f3);
        uint2 hiw, low;
        hiw.x = (unsigned)h0 | ((unsigned)h1 << 16);
        hiw.y = (unsigned)h2 | ((unsigned)h3 << 16);
        low.x = (unsigned)f2h(f0 - h2f(h0)) | ((unsigned)f2h(f1 - h2f(h1)) << 16);
        low.y = (unsigned)f2h(f2 - h2f(h2)) | ((unsigned)f2h(f3 - h2f(h3)) << 16);
        *reinterpret_cast<uint2*>(&Qh[base + lan15 * 4]) = hiw;
        *reinterpret_cast<uint2*>(&Ql[base + lan15 * 4]) = low;
      } else if (sec == 1) {
        // K: fp16 single, kappa-d layout, PRE-SCALED by gate (s*g*log2e)
        float gv = G[(size_t)(bb * HEADS + hh_) * SEQ + nn];
        uint2 kw;
        kw.x = (unsigned)f2h(f0 * gv) | ((unsigned)f2h(f1 * gv) << 16);
        kw.y = (unsigned)f2h(f2 * gv) | ((unsigned)f2h(f3 * gv) << 16);
        *reinterpret_cast<uint2*>(&K16[base + lan15 * 4]) = kw;
      } else {
        // V^T pre-swizzled tile store (scattered u16; L2 absorbs)
        int kt_ = nn >> 6, key = nn & 63;
        int ct_ = key >> 4, lg2 = (key >> 2) & 3, rr_ = key & 3;
        int kap = (ct_ >> 1) * 32 + lg2 * 8 + (ct_ & 1) * 4 + rr_;
        size_t tb = (size_t)((bb * HEADS + hh_) * 32 + kt_) * 4096;
        float fs[4] = {f0, f1, f2, f3};
        #pragma unroll
        for (int ni = 0; ni < 4; ++ni) {
          int d = ni * 16 + lan15;
          VT[tb + ((d * 64 + kap) ^ ((d & 7) << 3))] = f2h(fs[ni]);
        }
      }
    }
  }
}

// ---------------------------------------------------------------------------
// Kernel 3: flash attention, swapped QK^T: S^T = mfma(K, Q).  Gate folded
// into K.  K + pre-swizzled V^T staged via global_load_lds (dbuf, 1
// barrier/tile).  Q fp16 hi/lo in regs -> 2-term QK.  Lane-local softmax:
// pairwise max3 tree + raw v_exp_f32; P in-register fp16 B-frag; PV fp16
// MFMA -> O^T.
// ---------------------------------------------------------------------------
#define AISSUE(kt, X) do { \
  _Pragma("unroll") for (int cc = 0; cc < 2; ++cc) { \
    int c = t + cc * 256; int fi = c >> 6, lg = (c >> 4) & 3, rr = c & 15; \
    size_t gk = kvbase + (size_t)((kt) * 64 + (fi >> 1) * 16 + rr) * HD \
                + (fi & 1) * 32 + lg * 8; \
    int lo = (w * 64 + cc * 256) * 8; \
    gld16(&K16[gk], &KS##X[lo]); \
    gld16(&VT[vtbase + (size_t)(kt) * 4096 + (size_t)c * 8], &VTS##X[lo]); \
  } } while (0)

__global__ __launch_bounds__(256) void attn_mfma(
    const u16* __restrict__ Qh, const u16* __restrict__ Ql,
    const u16* __restrict__ K16, const u16* __restrict__ VT,
    u16* __restrict__ AO16)
{
  __shared__ u16 KS0[4096], KS1[4096];
  __shared__ u16 VTS0[4096], VTS1[4096];   // [d][kappa], fp16, swizzled

  const int t     = threadIdx.x;
  const int w     = t >> 6, l = t & 63;
  const int lan15 = l & 15;
  const int lgrp  = l >> 4;
  // XCD swizzle: block n -> xcd = n%8 owns heads 3*(n%8)..+2
  const int n   = blockIdx.x;          // 0..767
  const int s_  = n >> 3;              // 0..95
  const int bh  = (n & 7) * 3 + (s_ >> 5);
  const int qt  = s_ & 31;
  const int b   = bh / HEADS;
  const int h   = bh % HEADS;
  const size_t kvbase = (size_t)bh * SEQ * HD;
  const size_t vtbase = (size_t)bh * 32 * 4096;

  // Q fragments (fp16 hi/lo, kappa-d layout): B-operand, lane's q-row = lan15
  f16x8 qh[2], ql[2];
  {
    size_t qrow = kvbase + (size_t)(qt * 64 + w * 16 + lan15) * HD;
    #pragma unroll
    for (int s = 0; s < 2; ++s) {
      qh[s] = *reinterpret_cast<const f16x8*>(&Qh[qrow + s * 32 + lgrp * 8]);
      ql[s] = *reinterpret_cast<const f16x8*>(&Ql[qrow + s * 32 + lgrp * 8]);
    }
  }

  f32x4 o[4];      // O^T: o[dt] rows d = dt*16 + lgrp*4 + reg, col q = lan15
  #pragma unroll
  for (int dt = 0; dt < 4; ++dt) o[dt] = (f32x4){0.f, 0.f, 0.f, 0.f};
  float mrun  = -INFINITY;
  float lpart = 0.f;   // per-lane partial over this lane's 16 keys/tile

  auto compute_tile = [&](int kt, int buf) {
    const u16* KC = buf ? KS1 : KS0;
    const u16* VC = buf ? VTS1 : VTS0;

    // ---- S^T = K Q^T (fp16 2-term: Q exact via hi+lo); A=K, B=Q ----
    f32x4 acc[4];
    #pragma unroll
    for (int ct = 0; ct < 4; ++ct) acc[ct] = (f32x4){0.f, 0.f, 0.f, 0.f};
    __builtin_amdgcn_s_setprio(1);
    #pragma unroll
    for (int s = 0; s < 2; ++s) {
      #pragma unroll
      for (int ct = 0; ct < 4; ++ct) {
        int aidx = ((ct * 2 + s) * 64 + l) * 8;
        f16x8 ka = *reinterpret_cast<const f16x8*>(&KC[aidx]);
        acc[ct] = MFMA16F(ka, qh[s], acc[ct]);
        acc[ct] = MFMA16F(ka, ql[s], acc[ct]);
      }
    }
    __builtin_amdgcn_s_setprio(0);

    // ---- online softmax (exp2 domain, lane-local row; gate already in K) --
    // pairwise max tree (fuses to v_max3), depth 4
    float m0 = fmaxf(fmaxf(acc[0][0], acc[0][1]), fmaxf(acc[0][2], acc[0][3]));
    float m1 = fmaxf(fmaxf(acc[1][0], acc[1][1]), fmaxf(acc[1][2], acc[1][3]));
    float m2 = fmaxf(fmaxf(acc[2][0], acc[2][1]), fmaxf(acc[2][2], acc[2][3]));
    float m3 = fmaxf(fmaxf(acc[3][0], acc[3][1]), fmaxf(acc[3][2], acc[3][3]));
    float tmax = fmaxf(fmaxf(m0, m1), fmaxf(m2, m3));
    tmax = fmaxf(tmax, __shfl_xor(tmax, 16));
    tmax = fmaxf(tmax, __shfl_xor(tmax, 32));
    // exact rescale-skip: when no row's max grew, fsc == 1 exactly
    if (__any(tmax > mrun)) {
      float mnew = fmaxf(mrun, tmax);
      float fsc  = fexp2(mrun - mnew);
      mrun = mnew;
      lpart *= fsc;
      #pragma unroll
      for (int dt = 0; dt < 4; ++dt) o[dt] *= fsc;
    }
    float p[4][4];
    #pragma unroll
    for (int ct = 0; ct < 4; ++ct)
      #pragma unroll
      for (int r = 0; r < 4; ++r)
        p[ct][r] = fexp2(acc[ct][r] - mrun);
    // pairwise sum tree
    float s00 = (p[0][0] + p[0][1]) + (p[0][2] + p[0][3]);
    float s01 = (p[1][0] + p[1][1]) + (p[1][2] + p[1][3]);
    float s10 = (p[2][0] + p[2][1]) + (p[2][2] + p[2][3]);
    float s11 = (p[3][0] + p[3][1]) + (p[3][2] + p[3][3]);
    lpart += (s00 + s01) + (s10 + s11);

    // ---- P -> fp16 B-frags IN REGISTER (kappa-matched, no LDS) ----
    union { uint4 u; f16x8 h; } pb0, pb1;
    pb0.u.x = cvtpk(p[0][0], p[0][1]); pb0.u.y = cvtpk(p[0][2], p[0][3]);
    pb0.u.z = cvtpk(p[1][0], p[1][1]); pb0.u.w = cvtpk(p[1][2], p[1][3]);
    pb1.u.x = cvtpk(p[2][0], p[2][1]); pb1.u.y = cvtpk(p[2][2], p[2][3]);
    pb1.u.z = cvtpk(p[3][0], p[3][1]); pb1.u.w = cvtpk(p[3][2], p[3][3]);

    // ---- O^T += V^T P^T (single fp16 MFMA per frag); A=V^T, B=P^T ----
    __builtin_amdgcn_s_setprio(1);
    #pragma unroll
    for (int s = 0; s < 2; ++s) {
      #pragma unroll
      for (int dt = 0; dt < 4; ++dt) {
        int brow = dt * 16 + lan15;
        int bidx = (brow * 64 + s * 32 + lgrp * 8) ^ ((brow & 7) << 3);
        f16x8 va = *reinterpret_cast<const f16x8*>(&VC[bidx]);
        o[dt] = MFMA16F(va, s ? pb1.h : pb0.h, o[dt]);
      }
    }
    __builtin_amdgcn_s_setprio(0);
  };

  AISSUE(0, 0);
  for (int kt = 0; kt < SEQ / 64; kt += 2) {
    __syncthreads();                  // drains buf0 loads; buf0 readers done
    AISSUE(kt + 1, 1);                // in flight across compute(kt)
    compute_tile(kt, 0);
    __syncthreads();                  // drains buf1 loads; buf1 readers done
    if (kt + 2 < SEQ / 64) AISSUE(kt + 2, 0);
    compute_tile(kt + 1, 1);
  }

  // ---- epilogue: reduce l, normalize, packed fp16 write (RNE) ----
  lpart += __shfl_xor(lpart, 16);
  lpart += __shfl_xor(lpart, 32);
  float inv = 1.f / lpart;
  const int qrow = qt * 64 + w * 16 + lan15;
  const size_t base = (size_t)(b * SEQ + qrow) * DIM + h * HD;
  #pragma unroll
  for (int dt = 0; dt < 4; ++dt) {
    float f0 = o[dt][0] * inv, f1 = o[dt][1] * inv;
    float f2 = o[dt][2] * inv, f3 = o[dt][3] * inv;
    uint2 ow;
    ow.x = (unsigned)f2h(f0) | ((unsigned)f2h(f1) << 16);
    ow.y = (unsigned)f2h(f2) | ((unsigned)f2h(f3) << 16);
    *reinterpret_cast<uint2*>(&AO16[base + dt * 16 + lgrp * 4]) = ow;
  }
}

// ---------------------------------------------------------------------------
// Kernel 4: out = AO @ Wo + bo.  AO fp16 single (A), Wo fp16 hi/lo (B),
// 2-term fp16 MFMA, gld_lds staging (32KB dbuf).  XCD chunk swizzle:
// 384 blocks = 8 XCDs x (6x * 8y).
// ---------------------------------------------------------------------------
#define OISSUE(kb, X) do { \
  _Pragma("unroll") for (int cc = 0; cc < 2; ++cc) { \
    int c = t + cc * 256; int mf = c >> 6, lg = (c >> 4) & 3, rr = c & 15; \
    size_t ga = (size_t)(row0 + mf * 16 + rr) * DIM + (kb) + lg * 8; \
    int lo = (w * 64 + cc * 256) * 8; \
    gld16(&a16[ga], &AS##X[lo]); } \
  { int c = t; int nf = c >> 6, lg = (c >> 4) & 3, rr = c & 15; \
    size_t gb = (size_t)(col0 + nf * 16 + rr) * DIM + (kb) + lg * 8; \
    int lo = (w * 64) * 8; \
    gld16(&bth[gb], &BH##X[lo]); gld16(&btl[gb], &BL##X[lo]); } } while (0)

__global__ __launch_bounds__(256) void outproj_mfma(
    const u16* __restrict__ a16,
    const u16* __restrict__ bth, const u16* __restrict__ btl,
    const float* __restrict__ bo, float* __restrict__ out)
{
  __shared__ u16 AS0[4096], AS1[4096];
  __shared__ u16 BH0[2048], BL0[2048], BH1[2048], BL1[2048];
  const int t = threadIdx.x;
  const int w = t >> 6, l = t & 63;
  const int lan15 = l & 15, lgrp = l >> 4;
  // XCD chunk swizzle: xcd = id%8 owns a (6x, 8y) chunk
  const int id  = blockIdx.x;          // 0..383
  const int xcd = id & 7;
  const int j   = id >> 3;             // 0..47
  const int bx  = (xcd & 1) * 6 + (j % 6);
  const int by  = (xcd >> 1) * 8 + (j / 6);
  const int row0 = by * 128, col0 = bx * 64;
  const int wrf = (w >> 1) * 4, wcf = (w & 1) * 2;

  f32x4 acc[4][2];
  #pragma unroll
  for (int i = 0; i < 4; ++i)
    #pragma unroll
    for (int jj = 0; jj < 2; ++jj) acc[i][jj] = (f32x4){0.f, 0.f, 0.f, 0.f};

  auto ocompute = [&](int buf) {
    const u16* ASc = buf ? AS1 : AS0;
    const u16* BHc = buf ? BH1 : BH0; const u16* BLc = buf ? BL1 : BL0;
    f16x8 a4[4];
    #pragma unroll
    for (int mi = 0; mi < 4; ++mi)
      a4[mi] = *reinterpret_cast<const f16x8*>(&ASc[((wrf + mi) * 64 + l) * 8]);
    __builtin_amdgcn_s_setprio(1);
    #pragma unroll
    for (int ni = 0; ni < 2; ++ni) {
      f16x8 bh = *reinterpret_cast<const f16x8*>(&BHc[((wcf + ni) * 64 + l) * 8]);
      f16x8 bl = *reinterpret_cast<const f16x8*>(&BLc[((wcf + ni) * 64 + l) * 8]);
      #pragma unroll
      for (int mi = 0; mi < 4; ++mi) {
        acc[mi][ni] = MFMA16F(a4[mi], bh, acc[mi][ni]);
        acc[mi][ni] = MFMA16F(a4[mi], bl, acc[mi][ni]);
      }
    }
    __builtin_amdgcn_s_setprio(0);
  };

  OISSUE(0, 0);
  for (int kb = 0; kb < DIM; kb += 64) {
    __syncthreads();
    OISSUE(kb + 32, 1);
    ocompute(0);
    __syncthreads();
    if (kb + 64 < DIM) OISSUE(kb + 64, 0);
    ocompute(1);
  }

  const int wrr = (w >> 1) * 64, wcc = (w & 1) * 32;
  #pragma unroll
  for (int mi = 0; mi < 4; ++mi) {
    #pragma unroll
    for (int reg = 0; reg < 4; ++reg) {
      int row = row0 + wrr + mi * 16 + lgrp * 4 + reg;
      #pragma unroll
      for (int ni = 0; ni < 2; ++ni) {
        int col = col0 + wcc + ni * 16 + lan15;
        out[(size_t)row * DIM + col] = acc[mi][ni][reg] + bo[col];
      }
    }
  }
}

// ---------------------------------------------------------------------------
extern "C" void kernel_launch(void* const* d_in, const int* in_sizes, int n_in,
                              void* d_out, int out_size, void* d_ws, size_t ws_size,
                              hipStream_t stream) {
  const float* x    = (const float*)d_in[0];
  const float* cov  = (const float*)d_in[1];
  const float* Wqkv = (const float*)d_in[2];
  const float* Wo   = (const float*)d_in[3];
  const float* bo   = (const float*)d_in[4];
  const float* Wg1  = (const float*)d_in[5];
  const float* bg1  = (const float*)d_in[6];
  const float* Wg2  = (const float*)d_in[7];
  const float* bg2  = (const float*)d_in[8];
  float* out = (float*)d_out;

  const size_t NX   = (size_t)BN_TOT * DIM;
  const size_t NWQ  = (size_t)DIM * 3 * DIM;
  const size_t NWO  = (size_t)DIM * DIM;
  const size_t NHEA = (size_t)BATCH * HEADS * SEQ * HD;

  float* g   = (float*)d_ws;
  u16* base  = (u16*)(g + (size_t)BATCH * HEADS * SEQ);
  u16* x16   = base;          u16* wth  = x16 + NX;
  u16* wtl   = wth + NWQ;     u16* woth = wtl + NWQ;
  u16* wotl  = woth + NWO;
  u16* Qh    = wotl + NWO;    u16* Ql   = Qh + NHEA;
  u16* K16   = Ql + NHEA;     u16* VT   = K16 + NHEA;
  u16* AO16  = VT + NHEA;

  cvt16_kernel<<<(int)(NX / 1024), 256, 0, stream>>>(x, x16, (int)(NX / 4));
  transpose_split<<<dim3(3 * DIM / 64, DIM / 64), 256, 0, stream>>>(
      Wqkv, wth, wtl, DIM, 3 * DIM);
  transpose_split<<<dim3(DIM / 64, DIM / 64), 256, 0, stream>>>(
      Wo, woth, wotl, DIM, DIM);
  gate_kernel<<<BN_TOT / 256, 256, 0, stream>>>(cov, Wg1, bg1, Wg2, bg2, g);
  qkv_mfma<<<576, 256, 0, stream>>>(x16, wth, wtl, g, Qh, Ql, K16, VT);
  attn_mfma<<<SEQ / 64 * BATCH * HEADS, 256, 0, stream>>>(
      Qh, Ql, K16, VT, AO16);
  outproj_mfma<<<384, 256, 0, stream>>>(AO16, woth, wotl, bo, out);
}